// Round 1
// 249.886 us; speedup vs baseline: 1.0449x; 1.0449x over previous
//
#include <hip/hip_runtime.h>
#include <hip/hip_bf16.h>

// WeisfeilerLehman: labels0 = argmax(x, -1); 3x ordered polynomial hash over edges.
// All arithmetic mod 2^32 (uint32 wrap) == reference int64 truncated to int32.
// R12: occupancy fixes. Fused hist/argmax/zero kernel now 2048 blocks (argmax was
//      8 waves/CU -> latency-bound at 60us); MSD chunks 256->512 so scatter runs
//      at 2 blocks/CU. Everything else identical to R11.
// R13: k_scatter was latency-bound (occ 32%, VALU 27%, HBM 20% - nothing saturated;
//      serial ballot+LDS-RMW+scattered-store chain per batch). NCH 512->1024 puts
//      scatter at exactly 4 blocks/CU (32 waves/CU, the HW cap; LDS 8KB, VGPR 12
//      allow it). SPLIT 2->4 lifts k_prop from ~1.5 to ~3 blocks/CU for the same
//      reason. hist grows to 196*1024 words (+400KB ws, ~28.4MB total).

#define WL_D 128
#define NCH 1024            // MSD chunk count (scatter grid): 4 blocks/CU
#define GRID_F 2048         // fused hist/argmax/zero grid
#define BT 512              // threads per block (8 waves)
#define MSDW 8
#define BBITS 9             // bucket = row >> 9
#define BROWS 512           // rows per bucket
#define NBK 256             // max buckets (N <= 131072)
#define RLSHIFT 23          // buf pack: (rl << 23) | col   (col < 2^23)
#define COLMASK ((1u << RLSHIFT) - 1u)
#define CMAX 20480          // LDS-staged slice cap (80 KB)
#define SPLIT 4             // prop blocks per bucket

__device__ inline unsigned dpow31(unsigned e) {
    unsigned p = 1, b = 31u;
    while (e) { if (e & 1u) p *= b; b *= b; e >>= 1u; }
    return p;
}

// mask of lanes whose low BITS bits of v match mine (inactive lanes use a
// sentinel outside the valid key range so they never match active lanes)
template <int BITS>
__device__ inline unsigned long long match_key(unsigned v) {
    unsigned long long m = ~0ull;
    #pragma unroll
    for (int b = 0; b < BITS; ++b) {
        unsigned long long s = __ballot((v >> b) & 1u);
        m &= ((v >> b) & 1u) ? s : ~s;
    }
    return m;
}

// ---- fused: chunk bucket-histogram (blocks < NCH) + argmax + zero lab1..3 ----
__global__ void __launch_bounds__(BT)
k_hist_argmax(const float* __restrict__ x, const int* __restrict__ ei,
              unsigned* __restrict__ lab0, unsigned* __restrict__ hist,
              unsigned* __restrict__ zero3, int N, int E, int chunk, int nbuckets) {
    __shared__ unsigned h[NBK];
    int b = blockIdx.x, t = threadIdx.x, lane = t & 63, w = t >> 6;
    if (b < NCH) {                      // uniform per-block condition: syncs are safe
        for (int i = t; i < nbuckets; i += BT) h[i] = 0u;
        __syncthreads();
        int base = b * chunk, lim = min(base + chunk, E);
        for (int e = base + t; e < lim; e += BT)
            atomicAdd(&h[((unsigned)ei[e]) >> BBITS], 1u);
        __syncthreads();
        for (int v = t; v < nbuckets; v += BT) hist[(size_t)v * NCH + b] = h[v];
    }
    // zero lab1..lab3 (contiguous 3N words)
    for (int i = b * BT + t; i < 3 * N; i += GRID_F * BT) zero3[i] = 0u;
    // argmax: one wave per row, float2 loads, grid-stride
    for (int r = b * MSDW + w; r < N; r += GRID_F * MSDW) {
        const float2* xr = (const float2*)(x + (size_t)r * WL_D);
        float2 v = xr[lane];
        float bv; int bi;
        if (v.y > v.x) { bv = v.y; bi = 2 * lane + 1; } else { bv = v.x; bi = 2 * lane; }
        #pragma unroll
        for (int off = 32; off > 0; off >>= 1) {
            float ov = __shfl_down(bv, off, 64);
            int   oi = __shfl_down(bi, off, 64);
            if (ov > bv || (ov == bv && oi < bi)) { bv = ov; bi = oi; }
        }
        if (lane == 0) lab0[r] = (unsigned)bi;
    }
}

// ---- scan: tile (1024 elems / block, 2 per thread) + sums ----
__global__ void __launch_bounds__(BT)
k_scan_tile(unsigned* __restrict__ hist, unsigned* __restrict__ bsums, int L) {
    __shared__ unsigned smem[BT];
    int b = blockIdx.x, t = threadIdx.x;
    int i0 = b * 1024;
    unsigned v0 = (i0 + 2 * t     < L) ? hist[i0 + 2 * t]     : 0u;
    unsigned v1 = (i0 + 2 * t + 1 < L) ? hist[i0 + 2 * t + 1] : 0u;
    unsigned s = v0 + v1;
    smem[t] = s;
    __syncthreads();
    for (int o = 1; o < BT; o <<= 1) {
        unsigned u = (t >= o) ? smem[t - o] : 0u;
        __syncthreads();
        smem[t] += u;
        __syncthreads();
    }
    unsigned excl = smem[t] - s;
    if (i0 + 2 * t     < L) hist[i0 + 2 * t]     = excl;
    if (i0 + 2 * t + 1 < L) hist[i0 + 2 * t + 1] = excl + v0;
    if (t == BT - 1) bsums[b] = smem[BT - 1];
}

__global__ void __launch_bounds__(BT)
k_scan_sums(unsigned* __restrict__ bsums, int ntiles) {
    __shared__ unsigned smem[BT];
    int t = threadIdx.x;
    unsigned v = (t < ntiles) ? bsums[t] : 0u;
    smem[t] = v;
    __syncthreads();
    for (int o = 1; o < BT; o <<= 1) {
        unsigned u = (t >= o) ? smem[t - o] : 0u;
        __syncthreads();
        smem[t] += u;
        __syncthreads();
    }
    if (t < ntiles) bsums[t] = smem[t] - v;
}

// ---- stable MSD scatter: per-wave sub-chunks, per-(wave,bucket) LDS cursors ----
__global__ void __launch_bounds__(BT)
k_scatter(const int* __restrict__ ei, const unsigned* __restrict__ hist,
          const unsigned* __restrict__ bsums, unsigned* __restrict__ buf,
          int E, int chunk, int nbuckets) {
    __shared__ unsigned wbase[MSDW * NBK];   // 8 KB
    int b = blockIdx.x, t = threadIdx.x, lane = t & 63, w = t >> 6;
    unsigned long long lmask = (1ull << lane) - 1ull;
    for (int i = t; i < MSDW * NBK; i += BT) wbase[i] = 0u;
    __syncthreads();
    int base = b * chunk, lim = min(base + chunk, E);
    int sub  = (chunk + MSDW - 1) / MSDW;
    int wbeg = base + w * sub;
    int wend = min(wbeg + sub, lim);
    int nbat = (wbeg < wend) ? ((wend - wbeg + 63) >> 6) : 0;
    for (int bt2 = 0; bt2 < nbat; ++bt2) {
        int e = wbeg + bt2 * 64 + lane;
        bool act = (e < wend);
        unsigned v = act ? (((unsigned)ei[e]) >> BBITS) : (NBK - 1u);
        unsigned long long m = match_key<8>(v);
        unsigned before = (unsigned)__popcll(m & lmask);
        unsigned total  = (unsigned)__popcll(m);
        if (act && before == 0u) wbase[w * NBK + v] += total;
    }
    __syncthreads();
    for (int v = t; v < nbuckets; v += BT) {
        size_t idx = (size_t)v * NCH + b;
        unsigned g = hist[idx] + bsums[idx >> 10];
        #pragma unroll
        for (int w2 = 0; w2 < MSDW; ++w2) {
            unsigned cnt = wbase[w2 * NBK + v];
            wbase[w2 * NBK + v] = g;
            g += cnt;
        }
    }
    __syncthreads();
    for (int bt2 = 0; bt2 < nbat; ++bt2) {
        int e = wbeg + bt2 * 64 + lane;
        bool act = (e < wend);
        unsigned r   = act ? (unsigned)ei[e] : 0u;
        unsigned col = act ? (unsigned)ei[(size_t)E + e] : 0u;
        unsigned v = act ? (r >> BBITS) : (NBK - 1u);
        unsigned long long m = match_key<8>(v);
        unsigned before = (unsigned)__popcll(m & lmask);
        unsigned total  = (unsigned)__popcll(m);
        int leader = __ffsll(m) - 1;
        unsigned base0 = 0;
        if (act && before == 0u) { base0 = wbase[w * NBK + v]; wbase[w * NBK + v] = base0 + total; }
        base0 = __shfl(base0, leader, 64);
        if (act) buf[base0 + before] = ((r & (BROWS - 1u)) << RLSHIFT) | col;
    }
}

// ---- per-bucket stable counting sort by rl (slice staged in LDS); emits rs + csr ----
__global__ void __launch_bounds__(BT)
k_bucket(const unsigned* __restrict__ buf, const unsigned* __restrict__ hist,
         const unsigned* __restrict__ bsums, unsigned* __restrict__ csr,
         unsigned* __restrict__ rs_g, int N, int E, int nbuckets) {
    __shared__ unsigned data[CMAX];           // 80 KB
    __shared__ unsigned h2[MSDW * BROWS];     // 16 KB
    __shared__ unsigned offs[BROWS];          // 2 KB
    int bb = blockIdx.x, t = threadIdx.x, lane = t & 63, w = t >> 6;
    unsigned long long lmask = (1ull << lane) - 1ull;
    size_t i0 = (size_t)bb * NCH;
    unsigned start = hist[i0] + bsums[i0 >> 10];
    unsigned end;
    if (bb + 1 < nbuckets) { size_t i1 = (size_t)(bb + 1) * NCH; end = hist[i1] + bsums[i1 >> 10]; }
    else end = (unsigned)E;
    unsigned len = end - start;
    bool lds_ok = (len <= CMAX);
    if (lds_ok) for (unsigned i = t; i < len; i += BT) data[i] = buf[start + i];
    for (int i = t; i < MSDW * BROWS; i += BT) h2[i] = 0u;
    __syncthreads();
    unsigned sub  = (len + MSDW - 1u) / MSDW;
    unsigned wbeg = w * sub;
    unsigned wend = min(wbeg + sub, len);
    int nbat = (wbeg < wend) ? (int)((wend - wbeg + 63u) >> 6) : 0;
    // pass A: per-wave rl counts
    for (int bt2 = 0; bt2 < nbat; ++bt2) {
        unsigned i = wbeg + (unsigned)(bt2 * 64 + lane);
        bool act = (i < wend);
        unsigned v = act ? ((lds_ok ? data[i] : buf[start + i]) >> RLSHIFT) : 1023u;
        unsigned long long m = match_key<10>(v);
        unsigned before = (unsigned)__popcll(m & lmask);
        unsigned total  = (unsigned)__popcll(m);
        if (act && before == 0u) h2[w * BROWS + v] += total;
    }
    __syncthreads();
    // exclusive scan over rl; emit rs; seed per-wave cursors
    unsigned hv = 0;
    #pragma unroll
    for (int w2 = 0; w2 < MSDW; ++w2) hv += h2[w2 * BROWS + t];
    offs[t] = hv;
    __syncthreads();
    for (int o = 1; o < BROWS; o <<= 1) {
        unsigned s = (t >= o) ? offs[t - o] : 0u;
        __syncthreads();
        offs[t] += s;
        __syncthreads();
    }
    {
        unsigned excl = offs[t] - hv;
        int row = bb * BROWS + t;
        if (row < N) rs_g[row] = start + excl;
        unsigned g = start + excl;
        #pragma unroll
        for (int w2 = 0; w2 < MSDW; ++w2) {
            unsigned cnt = h2[w2 * BROWS + t];
            h2[w2 * BROWS + t] = g;
            g += cnt;
        }
    }
    __syncthreads();
    // pass B: stable scatter cols into csr
    for (int bt2 = 0; bt2 < nbat; ++bt2) {
        unsigned i = wbeg + (unsigned)(bt2 * 64 + lane);
        bool act = (i < wend);
        unsigned p = act ? (lds_ok ? data[i] : buf[start + i]) : 0u;
        unsigned v = act ? (p >> RLSHIFT) : 1023u;
        unsigned long long m = match_key<10>(v);
        unsigned before = (unsigned)__popcll(m & lmask);
        unsigned total  = (unsigned)__popcll(m);
        int leader = __ffsll(m) - 1;
        unsigned base0 = 0;
        if (act && before == 0u) { base0 = h2[w * BROWS + v]; h2[w * BROWS + v] = base0 + total; }
        base0 = __shfl(base0, leader, 64);
        if (act) csr[base0 + before] = p & COLMASK;
    }
}

// ---- prop: block per (bucket, quarter); binary-search row, LDS accumulate ----
__global__ void __launch_bounds__(BT)
k_prop(const unsigned* __restrict__ csr, const unsigned* __restrict__ rs,
       const unsigned* __restrict__ hist, const unsigned* __restrict__ bsums,
       const unsigned* __restrict__ lin, unsigned* __restrict__ lout,
       int N, int E, int nbuckets) {
    __shared__ unsigned acc[BROWS];
    __shared__ unsigned offs[BROWS + 1];
    __shared__ unsigned pwt[BROWS];
    int bb = blockIdx.x / SPLIT, pp = blockIdx.x % SPLIT;
    int t = threadIdx.x;
    size_t i0 = (size_t)bb * NCH;
    unsigned start = hist[i0] + bsums[i0 >> 10];
    unsigned end;
    if (bb + 1 < nbuckets) { size_t i1 = (size_t)(bb + 1) * NCH; end = hist[i1] + bsums[i1 >> 10]; }
    else end = (unsigned)E;
    unsigned len = end - start;
    acc[t] = 0u;
    pwt[t] = dpow31((unsigned)t);
    int row = bb * BROWS + t;
    offs[t] = (row < N) ? (rs[row] - start) : len;
    if (t == 0) offs[BROWS] = len;
    __syncthreads();
    unsigned seglen = (len + SPLIT - 1u) / SPLIT;
    unsigned pbeg = pp * seglen;
    unsigned pend = min(pbeg + seglen, len);
    for (unsigned i = pbeg + t; i < pend; i += BT) {
        unsigned col = csr[start + i];
        int lo = 0;
        #pragma unroll
        for (int st = 256; st; st >>= 1) {
            int mid = lo + st;
            if (offs[mid] <= i) lo = mid;
        }
        unsigned ex = offs[lo + 1] - 1u - i;
        unsigned val = lin[col] * ((ex < BROWS) ? pwt[ex] : dpow31(ex));
        atomicAdd(&acc[lo], val);
    }
    __syncthreads();
    if (row < N) atomicAdd(&lout[row], acc[t]);
}

__global__ void __launch_bounds__(BT)
k_out(const unsigned* __restrict__ l0, const unsigned* __restrict__ l1,
      const unsigned* __restrict__ l2, const unsigned* __restrict__ l3,
      int* __restrict__ out, int N) {
    for (int i = blockIdx.x * BT + threadIdx.x; i < N; i += 256 * BT) {
        int a0 = (int)l0[i], a1 = (int)l1[i], a2 = (int)l2[i], a3 = (int)l3[i];
        out[i]         = a3;
        out[N + i]     = a0;
        out[2 * N + i] = a1;
        out[3 * N + i] = a2;
        out[4 * N + i] = a3;
    }
}

extern "C" void kernel_launch(void* const* d_in, const int* in_sizes, int n_in,
                              void* d_out, int out_size, void* d_ws, size_t ws_size,
                              hipStream_t stream) {
    const float* x  = (const float*)d_in[0];
    const int*   ei = (const int*)d_in[1];
    int* out = (int*)d_out;

    int N = in_sizes[0] / WL_D;
    int E = in_sizes[1] / 2;
    int chunk    = (E + NCH - 1) / NCH;        // 3126
    int nbuckets = (N + BROWS - 1) / BROWS;    // 196
    int L        = nbuckets * NCH;             // 200,704
    int ntiles   = (L + 1023) / 1024;          // 197

    // workspace layout (uint32 units) — everything written before read
    unsigned* ws   = (unsigned*)d_ws;
    unsigned* lab0 = ws;               // N
    unsigned* lab1 = lab0 + N;         // N  (zeroed in k_hist_argmax)
    unsigned* lab2 = lab1 + N;         // N  (zeroed)
    unsigned* lab3 = lab2 + N;         // N  (zeroed)
    unsigned* rs   = lab3 + N;         // N
    unsigned* bs   = rs + N;           // 1024
    unsigned* hist = bs + 1024;        // L
    unsigned* buf  = hist + L;         // E
    unsigned* csr  = buf + E;          // E

    k_hist_argmax<<<GRID_F, BT, 0, stream>>>(x, ei, lab0, hist, lab1, N, E, chunk, nbuckets);
    k_scan_tile<<<ntiles, BT, 0, stream>>>(hist, bs, L);
    k_scan_sums<<<1, BT, 0, stream>>>(bs, ntiles);
    k_scatter<<<NCH, BT, 0, stream>>>(ei, hist, bs, buf, E, chunk, nbuckets);
    k_bucket<<<nbuckets, BT, 0, stream>>>(buf, hist, bs, csr, rs, N, E, nbuckets);
    k_prop<<<nbuckets * SPLIT, BT, 0, stream>>>(csr, rs, hist, bs, lab0, lab1, N, E, nbuckets);
    k_prop<<<nbuckets * SPLIT, BT, 0, stream>>>(csr, rs, hist, bs, lab1, lab2, N, E, nbuckets);
    k_prop<<<nbuckets * SPLIT, BT, 0, stream>>>(csr, rs, hist, bs, lab2, lab3, N, E, nbuckets);
    k_out<<<256, BT, 0, stream>>>(lab0, lab1, lab2, lab3, out, N);
}

// Round 2
// 249.010 us; speedup vs baseline: 1.0486x; 1.0035x over previous
//
#include <hip/hip_runtime.h>
#include <hip/hip_bf16.h>

// WeisfeilerLehman: labels0 = argmax(x, -1); 3x ordered polynomial hash over edges.
// All arithmetic mod 2^32 (uint32 wrap) == reference int64 truncated to int32.
// R13: NCH 512->1024 (scatter 4 blocks/CU), SPLIT 2->4.
// R14: k_bucket was the wall (48us, occ 14%, WRITE_SIZE 92MB for 12.8MB useful).
//      (a) BROWS 512->256: nbuckets=391 -> grid no longer < #CUs, per-block work
//          halved, match_key 10->9. (b) Input staging dropped (bucket slice is
//          L2/L3-hot); OUTPUT staged in LDS instead and streamed contiguously ->
//          write amplification 7x -> 1x. LDS 98KB -> 49KB. k_prop: BROWS=256
//          guards, 8-step search, SPLIT back to 2 (grid 782 ~ 3 blocks/CU).

#define WL_D 128
#define NCH 1024            // MSD chunk count (scatter grid): 4 blocks/CU
#define GRID_F 2048         // fused hist/argmax/zero grid
#define BT 512              // threads per block (8 waves)
#define MSDW 8
#define BBITS 8             // bucket = row >> 8
#define BROWS 256           // rows per bucket
#define NBK 512             // max buckets (N <= 131072)
#define RLSHIFT 23          // buf pack: (rl << 23) | col   (col < 2^23)
#define COLMASK ((1u << RLSHIFT) - 1u)
#define CMAX 10240          // LDS-staged output cap (40 KB); mean len 8192, sigma ~90
#define SPLIT 2             // prop blocks per bucket

__device__ inline unsigned dpow31(unsigned e) {
    unsigned p = 1, b = 31u;
    while (e) { if (e & 1u) p *= b; b *= b; e >>= 1u; }
    return p;
}

// mask of lanes whose low BITS bits of v match mine (inactive lanes use a
// sentinel outside the valid key range so they never match active lanes)
template <int BITS>
__device__ inline unsigned long long match_key(unsigned v) {
    unsigned long long m = ~0ull;
    #pragma unroll
    for (int b = 0; b < BITS; ++b) {
        unsigned long long s = __ballot((v >> b) & 1u);
        m &= ((v >> b) & 1u) ? s : ~s;
    }
    return m;
}

// ---- fused: chunk bucket-histogram (blocks < NCH) + argmax + zero lab1..3 ----
__global__ void __launch_bounds__(BT)
k_hist_argmax(const float* __restrict__ x, const int* __restrict__ ei,
              unsigned* __restrict__ lab0, unsigned* __restrict__ hist,
              unsigned* __restrict__ zero3, int N, int E, int chunk, int nbuckets) {
    __shared__ unsigned h[NBK];
    int b = blockIdx.x, t = threadIdx.x, lane = t & 63, w = t >> 6;
    if (b < NCH) {                      // uniform per-block condition: syncs are safe
        for (int i = t; i < nbuckets; i += BT) h[i] = 0u;
        __syncthreads();
        int base = b * chunk, lim = min(base + chunk, E);
        for (int e = base + t; e < lim; e += BT)
            atomicAdd(&h[((unsigned)ei[e]) >> BBITS], 1u);
        __syncthreads();
        for (int v = t; v < nbuckets; v += BT) hist[(size_t)v * NCH + b] = h[v];
    }
    // zero lab1..lab3 (contiguous 3N words)
    for (int i = b * BT + t; i < 3 * N; i += GRID_F * BT) zero3[i] = 0u;
    // argmax: one wave per row, float2 loads, grid-stride
    for (int r = b * MSDW + w; r < N; r += GRID_F * MSDW) {
        const float2* xr = (const float2*)(x + (size_t)r * WL_D);
        float2 v = xr[lane];
        float bv; int bi;
        if (v.y > v.x) { bv = v.y; bi = 2 * lane + 1; } else { bv = v.x; bi = 2 * lane; }
        #pragma unroll
        for (int off = 32; off > 0; off >>= 1) {
            float ov = __shfl_down(bv, off, 64);
            int   oi = __shfl_down(bi, off, 64);
            if (ov > bv || (ov == bv && oi < bi)) { bv = ov; bi = oi; }
        }
        if (lane == 0) lab0[r] = (unsigned)bi;
    }
}

// ---- scan: tile (1024 elems / block, 2 per thread) + sums ----
__global__ void __launch_bounds__(BT)
k_scan_tile(unsigned* __restrict__ hist, unsigned* __restrict__ bsums, int L) {
    __shared__ unsigned smem[BT];
    int b = blockIdx.x, t = threadIdx.x;
    int i0 = b * 1024;
    unsigned v0 = (i0 + 2 * t     < L) ? hist[i0 + 2 * t]     : 0u;
    unsigned v1 = (i0 + 2 * t + 1 < L) ? hist[i0 + 2 * t + 1] : 0u;
    unsigned s = v0 + v1;
    smem[t] = s;
    __syncthreads();
    for (int o = 1; o < BT; o <<= 1) {
        unsigned u = (t >= o) ? smem[t - o] : 0u;
        __syncthreads();
        smem[t] += u;
        __syncthreads();
    }
    unsigned excl = smem[t] - s;
    if (i0 + 2 * t     < L) hist[i0 + 2 * t]     = excl;
    if (i0 + 2 * t + 1 < L) hist[i0 + 2 * t + 1] = excl + v0;
    if (t == BT - 1) bsums[b] = smem[BT - 1];
}

__global__ void __launch_bounds__(BT)
k_scan_sums(unsigned* __restrict__ bsums, int ntiles) {
    __shared__ unsigned smem[BT];
    int t = threadIdx.x;
    unsigned v = (t < ntiles) ? bsums[t] : 0u;
    smem[t] = v;
    __syncthreads();
    for (int o = 1; o < BT; o <<= 1) {
        unsigned u = (t >= o) ? smem[t - o] : 0u;
        __syncthreads();
        smem[t] += u;
        __syncthreads();
    }
    if (t < ntiles) bsums[t] = smem[t] - v;
}

// ---- stable MSD scatter: per-wave sub-chunks, per-(wave,bucket) LDS cursors ----
__global__ void __launch_bounds__(BT)
k_scatter(const int* __restrict__ ei, const unsigned* __restrict__ hist,
          const unsigned* __restrict__ bsums, unsigned* __restrict__ buf,
          int E, int chunk, int nbuckets) {
    __shared__ unsigned wbase[MSDW * NBK];   // 16 KB
    int b = blockIdx.x, t = threadIdx.x, lane = t & 63, w = t >> 6;
    unsigned long long lmask = (1ull << lane) - 1ull;
    for (int i = t; i < MSDW * NBK; i += BT) wbase[i] = 0u;
    __syncthreads();
    int base = b * chunk, lim = min(base + chunk, E);
    int sub  = (chunk + MSDW - 1) / MSDW;
    int wbeg = base + w * sub;
    int wend = min(wbeg + sub, lim);
    int nbat = (wbeg < wend) ? ((wend - wbeg + 63) >> 6) : 0;
    for (int bt2 = 0; bt2 < nbat; ++bt2) {
        int e = wbeg + bt2 * 64 + lane;
        bool act = (e < wend);
        unsigned v = act ? (((unsigned)ei[e]) >> BBITS) : (NBK - 1u);
        unsigned long long m = match_key<9>(v);
        unsigned before = (unsigned)__popcll(m & lmask);
        unsigned total  = (unsigned)__popcll(m);
        if (act && before == 0u) wbase[w * NBK + v] += total;
    }
    __syncthreads();
    for (int v = t; v < nbuckets; v += BT) {
        size_t idx = (size_t)v * NCH + b;
        unsigned g = hist[idx] + bsums[idx >> 10];
        #pragma unroll
        for (int w2 = 0; w2 < MSDW; ++w2) {
            unsigned cnt = wbase[w2 * NBK + v];
            wbase[w2 * NBK + v] = g;
            g += cnt;
        }
    }
    __syncthreads();
    for (int bt2 = 0; bt2 < nbat; ++bt2) {
        int e = wbeg + bt2 * 64 + lane;
        bool act = (e < wend);
        unsigned r   = act ? (unsigned)ei[e] : 0u;
        unsigned col = act ? (unsigned)ei[(size_t)E + e] : 0u;
        unsigned v = act ? (r >> BBITS) : (NBK - 1u);
        unsigned long long m = match_key<9>(v);
        unsigned before = (unsigned)__popcll(m & lmask);
        unsigned total  = (unsigned)__popcll(m);
        int leader = __ffsll(m) - 1;
        unsigned base0 = 0;
        if (act && before == 0u) { base0 = wbase[w * NBK + v]; wbase[w * NBK + v] = base0 + total; }
        base0 = __shfl(base0, leader, 64);
        if (act) buf[base0 + before] = ((r & (BROWS - 1u)) << RLSHIFT) | col;
    }
}

// ---- per-bucket stable counting sort by rl; output staged in LDS, streamed out ----
__global__ void __launch_bounds__(BT)
k_bucket(const unsigned* __restrict__ buf, const unsigned* __restrict__ hist,
         const unsigned* __restrict__ bsums, unsigned* __restrict__ csr,
         unsigned* __restrict__ rs_g, int N, int E, int nbuckets) {
    __shared__ unsigned data2[CMAX];          // 40 KB (sorted output staging)
    __shared__ unsigned h2[MSDW * BROWS];     // 8 KB
    __shared__ unsigned offs[BROWS];          // 1 KB
    int bb = blockIdx.x, t = threadIdx.x, lane = t & 63, w = t >> 6;
    unsigned long long lmask = (1ull << lane) - 1ull;
    size_t i0 = (size_t)bb * NCH;
    unsigned start = hist[i0] + bsums[i0 >> 10];
    unsigned end;
    if (bb + 1 < nbuckets) { size_t i1 = (size_t)(bb + 1) * NCH; end = hist[i1] + bsums[i1 >> 10]; }
    else end = (unsigned)E;
    unsigned len = end - start;
    bool lds_ok = (len <= CMAX);
    for (int i = t; i < MSDW * BROWS; i += BT) h2[i] = 0u;
    __syncthreads();
    unsigned sub  = (len + MSDW - 1u) / MSDW;
    unsigned wbeg = w * sub;
    unsigned wend = min(wbeg + sub, len);
    int nbat = (wbeg < wend) ? (int)((wend - wbeg + 63u) >> 6) : 0;
    // pass A: per-wave rl counts (input read straight from L2/L3-hot buf)
    for (int bt2 = 0; bt2 < nbat; ++bt2) {
        unsigned i = wbeg + (unsigned)(bt2 * 64 + lane);
        bool act = (i < wend);
        unsigned v = act ? (buf[start + i] >> RLSHIFT) : 511u;
        unsigned long long m = match_key<9>(v);
        unsigned before = (unsigned)__popcll(m & lmask);
        unsigned total  = (unsigned)__popcll(m);
        if (act && before == 0u) h2[w * BROWS + v] += total;
    }
    __syncthreads();
    // exclusive scan over rl (256 entries, threads t < BROWS); emit rs; seed cursors
    unsigned hv = 0;
    if (t < BROWS) {
        #pragma unroll
        for (int w2 = 0; w2 < MSDW; ++w2) hv += h2[w2 * BROWS + t];
        offs[t] = hv;
    }
    __syncthreads();
    for (int o = 1; o < BROWS; o <<= 1) {
        unsigned s = (t < BROWS && t >= o) ? offs[t - o] : 0u;
        __syncthreads();
        if (t < BROWS) offs[t] += s;
        __syncthreads();
    }
    if (t < BROWS) {
        unsigned excl = offs[t] - hv;
        int row = bb * BROWS + t;
        if (row < N) rs_g[row] = start + excl;
        unsigned g = lds_ok ? excl : (start + excl);   // bucket-relative if LDS-staged
        #pragma unroll
        for (int w2 = 0; w2 < MSDW; ++w2) {
            unsigned cnt = h2[w2 * BROWS + t];
            h2[w2 * BROWS + t] = g;
            g += cnt;
        }
    }
    __syncthreads();
    // pass B: stable scatter cols into LDS staging (or csr directly on fallback)
    for (int bt2 = 0; bt2 < nbat; ++bt2) {
        unsigned i = wbeg + (unsigned)(bt2 * 64 + lane);
        bool act = (i < wend);
        unsigned p = act ? buf[start + i] : 0u;
        unsigned v = act ? (p >> RLSHIFT) : 511u;
        unsigned long long m = match_key<9>(v);
        unsigned before = (unsigned)__popcll(m & lmask);
        unsigned total  = (unsigned)__popcll(m);
        int leader = __ffsll(m) - 1;
        unsigned base0 = 0;
        if (act && before == 0u) { base0 = h2[w * BROWS + v]; h2[w * BROWS + v] = base0 + total; }
        base0 = __shfl(base0, leader, 64);
        if (act) {
            if (lds_ok) data2[base0 + before] = p & COLMASK;
            else        csr[base0 + before]   = p & COLMASK;
        }
    }
    __syncthreads();
    // stream sorted bucket out contiguously (1x write amplification)
    if (lds_ok) for (unsigned i = t; i < len; i += BT) csr[start + i] = data2[i];
}

// ---- prop: block per (bucket, half); binary-search row, LDS accumulate ----
__global__ void __launch_bounds__(BT)
k_prop(const unsigned* __restrict__ csr, const unsigned* __restrict__ rs,
       const unsigned* __restrict__ hist, const unsigned* __restrict__ bsums,
       const unsigned* __restrict__ lin, unsigned* __restrict__ lout,
       int N, int E, int nbuckets) {
    __shared__ unsigned acc[BROWS];
    __shared__ unsigned offs[BROWS + 1];
    __shared__ unsigned pwt[BROWS];
    int bb = blockIdx.x / SPLIT, pp = blockIdx.x % SPLIT;
    int t = threadIdx.x;
    size_t i0 = (size_t)bb * NCH;
    unsigned start = hist[i0] + bsums[i0 >> 10];
    unsigned end;
    if (bb + 1 < nbuckets) { size_t i1 = (size_t)(bb + 1) * NCH; end = hist[i1] + bsums[i1 >> 10]; }
    else end = (unsigned)E;
    unsigned len = end - start;
    int row = bb * BROWS + t;
    if (t < BROWS) {
        acc[t] = 0u;
        pwt[t] = dpow31((unsigned)t);
        offs[t] = (row < N) ? (rs[row] - start) : len;
    }
    if (t == 0) offs[BROWS] = len;
    __syncthreads();
    unsigned seglen = (len + SPLIT - 1u) / SPLIT;
    unsigned pbeg = pp * seglen;
    unsigned pend = min(pbeg + seglen, len);
    for (unsigned i = pbeg + t; i < pend; i += BT) {
        unsigned col = csr[start + i];
        int lo = 0;
        #pragma unroll
        for (int st = 128; st; st >>= 1) {
            int mid = lo + st;
            if (offs[mid] <= i) lo = mid;
        }
        unsigned ex = offs[lo + 1] - 1u - i;
        unsigned val = lin[col] * ((ex < BROWS) ? pwt[ex] : dpow31(ex));
        atomicAdd(&acc[lo], val);
    }
    __syncthreads();
    if (t < BROWS && row < N) atomicAdd(&lout[row], acc[t]);
}

__global__ void __launch_bounds__(BT)
k_out(const unsigned* __restrict__ l0, const unsigned* __restrict__ l1,
      const unsigned* __restrict__ l2, const unsigned* __restrict__ l3,
      int* __restrict__ out, int N) {
    for (int i = blockIdx.x * BT + threadIdx.x; i < N; i += 256 * BT) {
        int a0 = (int)l0[i], a1 = (int)l1[i], a2 = (int)l2[i], a3 = (int)l3[i];
        out[i]         = a3;
        out[N + i]     = a0;
        out[2 * N + i] = a1;
        out[3 * N + i] = a2;
        out[4 * N + i] = a3;
    }
}

extern "C" void kernel_launch(void* const* d_in, const int* in_sizes, int n_in,
                              void* d_out, int out_size, void* d_ws, size_t ws_size,
                              hipStream_t stream) {
    const float* x  = (const float*)d_in[0];
    const int*   ei = (const int*)d_in[1];
    int* out = (int*)d_out;

    int N = in_sizes[0] / WL_D;
    int E = in_sizes[1] / 2;
    int chunk    = (E + NCH - 1) / NCH;        // 3125
    int nbuckets = (N + BROWS - 1) / BROWS;    // 391
    int L        = nbuckets * NCH;             // 400,384
    int ntiles   = (L + 1023) / 1024;          // 391 (<= 512: single-block sums ok)

    // workspace layout (uint32 units) — everything written before read
    unsigned* ws   = (unsigned*)d_ws;
    unsigned* lab0 = ws;               // N
    unsigned* lab1 = lab0 + N;         // N  (zeroed in k_hist_argmax)
    unsigned* lab2 = lab1 + N;         // N  (zeroed)
    unsigned* lab3 = lab2 + N;         // N  (zeroed)
    unsigned* rs   = lab3 + N;         // N
    unsigned* bs   = rs + N;           // 1024
    unsigned* hist = bs + 1024;        // L
    unsigned* buf  = hist + L;         // E
    unsigned* csr  = buf + E;          // E

    k_hist_argmax<<<GRID_F, BT, 0, stream>>>(x, ei, lab0, hist, lab1, N, E, chunk, nbuckets);
    k_scan_tile<<<ntiles, BT, 0, stream>>>(hist, bs, L);
    k_scan_sums<<<1, BT, 0, stream>>>(bs, ntiles);
    k_scatter<<<NCH, BT, 0, stream>>>(ei, hist, bs, buf, E, chunk, nbuckets);
    k_bucket<<<nbuckets, BT, 0, stream>>>(buf, hist, bs, csr, rs, N, E, nbuckets);
    k_prop<<<nbuckets * SPLIT, BT, 0, stream>>>(csr, rs, hist, bs, lab0, lab1, N, E, nbuckets);
    k_prop<<<nbuckets * SPLIT, BT, 0, stream>>>(csr, rs, hist, bs, lab1, lab2, N, E, nbuckets);
    k_prop<<<nbuckets * SPLIT, BT, 0, stream>>>(csr, rs, hist, bs, lab2, lab3, N, E, nbuckets);
    k_out<<<256, BT, 0, stream>>>(lab0, lab1, lab2, lab3, out, N);
}

// Round 3
// 238.665 us; speedup vs baseline: 1.0940x; 1.0433x over previous
//
#include <hip/hip_runtime.h>
#include <hip/hip_bf16.h>

// WeisfeilerLehman: labels0 = argmax(x, -1); 3x ordered polynomial hash over edges.
// All arithmetic mod 2^32 (uint32 wrap) == reference int64 truncated to int32.
// R14: BROWS 512->256; k_bucket output staged in LDS (write amp 7x->1x).
// R15: (a) k_scatter was latency-bound with VGPR=12 (zero prefetch): batch loads
//      now hoisted into static-indexed reg arrays (7 per pass), rows kept live
//      across the middle phase. (b) hist cursor-bases were a 4KB-strided read
//      (~13MB partial-line fetch): new k_transp tiled-transpose pre-computes
//      histT[b][v] (+bsums) into the csr buffer (free space until k_bucket) so
//      the seed loop is coalesced. (c) k_prop rewritten: csr is stably grouped
//      by row, so label_next[row] is a plain Horner h=h*31+lin[col] over the
//      row segment -- removes the 8-deep LDS binary search per edge, pwt table,
//      LDS+global atomics, and the lab1..3 zeroing. 4 lanes/row (base-31^4
//      partial Horners + 31^T fixup, shfl_xor reduce), grid 782 ~ 3 blocks/CU.

#define WL_D 128
#define NCH 1024            // MSD chunk count (scatter grid): 4 blocks/CU
#define GRID_F 2048         // fused hist/argmax grid
#define BT 512              // threads per block (8 waves)
#define MSDW 8
#define BBITS 8             // bucket = row >> 8
#define BROWS 256           // rows per bucket
#define NBK 512             // max buckets (N <= 131072)
#define RLSHIFT 23          // buf pack: (rl << 23) | col   (col < 2^23)
#define COLMASK ((1u << RLSHIFT) - 1u)
#define CMAX 10240          // LDS-staged output cap (40 KB)
#define NBMAX 7             // unrolled batches per wave in k_scatter (chunk 3125)

// mask of lanes whose low BITS bits of v match mine (inactive lanes use a
// sentinel outside the valid key range so they never match active lanes)
template <int BITS>
__device__ inline unsigned long long match_key(unsigned v) {
    unsigned long long m = ~0ull;
    #pragma unroll
    for (int b = 0; b < BITS; ++b) {
        unsigned long long s = __ballot((v >> b) & 1u);
        m &= ((v >> b) & 1u) ? s : ~s;
    }
    return m;
}

// ---- fused: chunk bucket-histogram (blocks < NCH) + argmax ----
__global__ void __launch_bounds__(BT)
k_hist_argmax(const float* __restrict__ x, const int* __restrict__ ei,
              unsigned* __restrict__ lab0, unsigned* __restrict__ hist,
              int N, int E, int chunk, int nbuckets) {
    __shared__ unsigned h[NBK];
    int b = blockIdx.x, t = threadIdx.x, lane = t & 63, w = t >> 6;
    if (b < NCH) {                      // uniform per-block condition: syncs are safe
        for (int i = t; i < nbuckets; i += BT) h[i] = 0u;
        __syncthreads();
        int base = b * chunk, lim = min(base + chunk, E);
        for (int e = base + t; e < lim; e += BT)
            atomicAdd(&h[((unsigned)ei[e]) >> BBITS], 1u);
        __syncthreads();
        for (int v = t; v < nbuckets; v += BT) hist[(size_t)v * NCH + b] = h[v];
    }
    // argmax: one wave per row, float2 loads, grid-stride
    for (int r = b * MSDW + w; r < N; r += GRID_F * MSDW) {
        const float2* xr = (const float2*)(x + (size_t)r * WL_D);
        float2 v = xr[lane];
        float bv; int bi;
        if (v.y > v.x) { bv = v.y; bi = 2 * lane + 1; } else { bv = v.x; bi = 2 * lane; }
        #pragma unroll
        for (int off = 32; off > 0; off >>= 1) {
            float ov = __shfl_down(bv, off, 64);
            int   oi = __shfl_down(bi, off, 64);
            if (ov > bv || (ov == bv && oi < bi)) { bv = ov; bi = oi; }
        }
        if (lane == 0) lab0[r] = (unsigned)bi;
    }
}

// ---- scan: tile (1024 elems / block, 2 per thread) + sums ----
__global__ void __launch_bounds__(BT)
k_scan_tile(unsigned* __restrict__ hist, unsigned* __restrict__ bsums, int L) {
    __shared__ unsigned smem[BT];
    int b = blockIdx.x, t = threadIdx.x;
    int i0 = b * 1024;
    unsigned v0 = (i0 + 2 * t     < L) ? hist[i0 + 2 * t]     : 0u;
    unsigned v1 = (i0 + 2 * t + 1 < L) ? hist[i0 + 2 * t + 1] : 0u;
    unsigned s = v0 + v1;
    smem[t] = s;
    __syncthreads();
    for (int o = 1; o < BT; o <<= 1) {
        unsigned u = (t >= o) ? smem[t - o] : 0u;
        __syncthreads();
        smem[t] += u;
        __syncthreads();
    }
    unsigned excl = smem[t] - s;
    if (i0 + 2 * t     < L) hist[i0 + 2 * t]     = excl;
    if (i0 + 2 * t + 1 < L) hist[i0 + 2 * t + 1] = excl + v0;
    if (t == BT - 1) bsums[b] = smem[BT - 1];
}

__global__ void __launch_bounds__(BT)
k_scan_sums(unsigned* __restrict__ bsums, int ntiles) {
    __shared__ unsigned smem[BT];
    int t = threadIdx.x;
    unsigned v = (t < ntiles) ? bsums[t] : 0u;
    smem[t] = v;
    __syncthreads();
    for (int o = 1; o < BT; o <<= 1) {
        unsigned u = (t >= o) ? smem[t - o] : 0u;
        __syncthreads();
        smem[t] += u;
        __syncthreads();
    }
    if (t < ntiles) bsums[t] = smem[t] - v;
}

// ---- tiled transpose of scanned hist (+bsums) -> histT[b][v], both sides coalesced ----
__global__ void __launch_bounds__(BT)
k_transp(const unsigned* __restrict__ hist, const unsigned* __restrict__ bsums,
         unsigned* __restrict__ histT, int nbuckets) {
    __shared__ unsigned tl[64][65];
    int vtiles = (nbuckets + 63) / 64;
    int bx = blockIdx.x % vtiles;        // v-tile
    int by = blockIdx.x / vtiles;        // b-tile
    int tx = threadIdx.x & 63, ty = threadIdx.x >> 6;   // 64 x 8
    int v0 = bx * 64, b0 = by * 64;
    #pragma unroll
    for (int r = 0; r < 8; ++r) {
        int row = r * 8 + ty;
        int v = v0 + row;
        size_t idx = (size_t)v * NCH + (b0 + tx);
        tl[row][tx] = (v < nbuckets) ? (hist[idx] + bsums[idx >> 10]) : 0u;
    }
    __syncthreads();
    #pragma unroll
    for (int r = 0; r < 8; ++r) {
        int row = r * 8 + ty;            // b-offset within tile
        int v = v0 + tx;
        if (v < nbuckets) histT[(size_t)(b0 + row) * nbuckets + v] = tl[tx][row];
    }
}

// ---- stable MSD scatter: prefetched batches, per-(wave,bucket) LDS cursors ----
__global__ void __launch_bounds__(BT)
k_scatter(const int* __restrict__ ei, const unsigned* __restrict__ histT,
          unsigned* __restrict__ buf, int E, int chunk, int nbuckets) {
    __shared__ unsigned wbase[MSDW * NBK];   // 16 KB
    int b = blockIdx.x, t = threadIdx.x, lane = t & 63, w = t >> 6;
    unsigned long long lmask = (1ull << lane) - 1ull;
    for (int i = t; i < MSDW * NBK; i += BT) wbase[i] = 0u;
    __syncthreads();
    int base = b * chunk, lim = min(base + chunk, E);
    int sub  = (chunk + MSDW - 1) / MSDW;
    int wbeg = base + w * sub;
    int wend = min(wbeg + sub, lim);
    int nbat = (wbeg < wend) ? ((wend - wbeg + 63) >> 6) : 0;
    // prefetch all row loads (static reg indices; issued before any ballot chain)
    unsigned r_[NBMAX];
    #pragma unroll
    for (int k = 0; k < NBMAX; ++k) {
        int e = wbeg + k * 64 + lane;
        r_[k] = (e < wend) ? (unsigned)ei[e] : 0u;
    }
    // pass A: per-wave bucket counts
    #pragma unroll
    for (int k = 0; k < NBMAX; ++k) {
        if (k >= nbat) break;
        int e = wbeg + k * 64 + lane;
        bool act = (e < wend);
        unsigned v = act ? (r_[k] >> BBITS) : (NBK - 1u);
        unsigned long long m = match_key<9>(v);
        unsigned before = (unsigned)__popcll(m & lmask);
        unsigned total  = (unsigned)__popcll(m);
        if (act && before == 0u) wbase[w * NBK + v] += total;
    }
    for (int k = NBMAX; k < nbat; ++k) {     // dynamic tail (robustness)
        int e = wbeg + k * 64 + lane;
        bool act = (e < wend);
        unsigned v = act ? (((unsigned)ei[e]) >> BBITS) : (NBK - 1u);
        unsigned long long m = match_key<9>(v);
        unsigned before = (unsigned)__popcll(m & lmask);
        unsigned total  = (unsigned)__popcll(m);
        if (act && before == 0u) wbase[w * NBK + v] += total;
    }
    __syncthreads();
    // seed per-wave cursors from transposed bases (coalesced)
    for (int v = t; v < nbuckets; v += BT) {
        unsigned g = histT[(size_t)b * nbuckets + v];
        #pragma unroll
        for (int w2 = 0; w2 < MSDW; ++w2) {
            unsigned cnt = wbase[w2 * NBK + v];
            wbase[w2 * NBK + v] = g;
            g += cnt;
        }
    }
    __syncthreads();
    // pass B: prefetch cols (rows still live in r_), stable scatter
    unsigned c_[NBMAX];
    #pragma unroll
    for (int k = 0; k < NBMAX; ++k) {
        int e = wbeg + k * 64 + lane;
        c_[k] = (e < wend) ? (unsigned)ei[(size_t)E + e] : 0u;
    }
    #pragma unroll
    for (int k = 0; k < NBMAX; ++k) {
        if (k >= nbat) break;
        int e = wbeg + k * 64 + lane;
        bool act = (e < wend);
        unsigned r = r_[k], col = c_[k];
        unsigned v = act ? (r >> BBITS) : (NBK - 1u);
        unsigned long long m = match_key<9>(v);
        unsigned before = (unsigned)__popcll(m & lmask);
        unsigned total  = (unsigned)__popcll(m);
        int leader = __ffsll(m) - 1;
        unsigned base0 = 0;
        if (act && before == 0u) { base0 = wbase[w * NBK + v]; wbase[w * NBK + v] = base0 + total; }
        base0 = __shfl(base0, leader, 64);
        if (act) buf[base0 + before] = ((r & (BROWS - 1u)) << RLSHIFT) | col;
    }
    for (int k = NBMAX; k < nbat; ++k) {     // dynamic tail
        int e = wbeg + k * 64 + lane;
        bool act = (e < wend);
        unsigned r   = act ? (unsigned)ei[e] : 0u;
        unsigned col = act ? (unsigned)ei[(size_t)E + e] : 0u;
        unsigned v = act ? (r >> BBITS) : (NBK - 1u);
        unsigned long long m = match_key<9>(v);
        unsigned before = (unsigned)__popcll(m & lmask);
        unsigned total  = (unsigned)__popcll(m);
        int leader = __ffsll(m) - 1;
        unsigned base0 = 0;
        if (act && before == 0u) { base0 = wbase[w * NBK + v]; wbase[w * NBK + v] = base0 + total; }
        base0 = __shfl(base0, leader, 64);
        if (act) buf[base0 + before] = ((r & (BROWS - 1u)) << RLSHIFT) | col;
    }
}

// ---- per-bucket stable counting sort by rl; output staged in LDS, streamed out ----
__global__ void __launch_bounds__(BT)
k_bucket(const unsigned* __restrict__ buf, const unsigned* __restrict__ hist,
         const unsigned* __restrict__ bsums, unsigned* __restrict__ csr,
         unsigned* __restrict__ rs_g, int N, int E, int nbuckets) {
    __shared__ unsigned data2[CMAX];          // 40 KB (sorted output staging)
    __shared__ unsigned h2[MSDW * BROWS];     // 8 KB
    __shared__ unsigned offs[BROWS];          // 1 KB
    int bb = blockIdx.x, t = threadIdx.x, lane = t & 63, w = t >> 6;
    unsigned long long lmask = (1ull << lane) - 1ull;
    size_t i0 = (size_t)bb * NCH;
    unsigned start = hist[i0] + bsums[i0 >> 10];
    unsigned end;
    if (bb + 1 < nbuckets) { size_t i1 = (size_t)(bb + 1) * NCH; end = hist[i1] + bsums[i1 >> 10]; }
    else end = (unsigned)E;
    unsigned len = end - start;
    bool lds_ok = (len <= CMAX);
    for (int i = t; i < MSDW * BROWS; i += BT) h2[i] = 0u;
    __syncthreads();
    unsigned sub  = (len + MSDW - 1u) / MSDW;
    unsigned wbeg = w * sub;
    unsigned wend = min(wbeg + sub, len);
    int nbat = (wbeg < wend) ? (int)((wend - wbeg + 63u) >> 6) : 0;
    // pass A: per-wave rl counts (input read straight from L2/L3-hot buf)
    for (int bt2 = 0; bt2 < nbat; ++bt2) {
        unsigned i = wbeg + (unsigned)(bt2 * 64 + lane);
        bool act = (i < wend);
        unsigned v = act ? (buf[start + i] >> RLSHIFT) : 511u;
        unsigned long long m = match_key<9>(v);
        unsigned before = (unsigned)__popcll(m & lmask);
        unsigned total  = (unsigned)__popcll(m);
        if (act && before == 0u) h2[w * BROWS + v] += total;
    }
    __syncthreads();
    // exclusive scan over rl (256 entries, threads t < BROWS); emit rs; seed cursors
    unsigned hv = 0;
    if (t < BROWS) {
        #pragma unroll
        for (int w2 = 0; w2 < MSDW; ++w2) hv += h2[w2 * BROWS + t];
        offs[t] = hv;
    }
    __syncthreads();
    for (int o = 1; o < BROWS; o <<= 1) {
        unsigned s = (t < BROWS && t >= o) ? offs[t - o] : 0u;
        __syncthreads();
        if (t < BROWS) offs[t] += s;
        __syncthreads();
    }
    if (t < BROWS) {
        unsigned excl = offs[t] - hv;
        int row = bb * BROWS + t;
        if (row < N) rs_g[row] = start + excl;
        unsigned g = lds_ok ? excl : (start + excl);   // bucket-relative if LDS-staged
        #pragma unroll
        for (int w2 = 0; w2 < MSDW; ++w2) {
            unsigned cnt = h2[w2 * BROWS + t];
            h2[w2 * BROWS + t] = g;
            g += cnt;
        }
    }
    __syncthreads();
    // pass B: stable scatter cols into LDS staging (or csr directly on fallback)
    for (int bt2 = 0; bt2 < nbat; ++bt2) {
        unsigned i = wbeg + (unsigned)(bt2 * 64 + lane);
        bool act = (i < wend);
        unsigned p = act ? buf[start + i] : 0u;
        unsigned v = act ? (p >> RLSHIFT) : 511u;
        unsigned long long m = match_key<9>(v);
        unsigned before = (unsigned)__popcll(m & lmask);
        unsigned total  = (unsigned)__popcll(m);
        int leader = __ffsll(m) - 1;
        unsigned base0 = 0;
        if (act && before == 0u) { base0 = h2[w * BROWS + v]; h2[w * BROWS + v] = base0 + total; }
        base0 = __shfl(base0, leader, 64);
        if (act) {
            if (lds_ok) data2[base0 + before] = p & COLMASK;
            else        csr[base0 + before]   = p & COLMASK;
        }
    }
    __syncthreads();
    // stream sorted bucket out contiguously (1x write amplification)
    if (lds_ok) for (unsigned i = t; i < len; i += BT) csr[start + i] = data2[i];
}

// ---- prop: 4 lanes per row, Horner hash over the row's csr segment ----
// label_next[row] = sum_j lin[col_j] * 31^(d-1-j)  (edge order) == Horner h=h*31+lin.
// Lane l of the 4-group takes j = l, l+4, ... via base-31^4 Horner, then scales by
// 31^T (T in [0,3]) and the group reduces with shfl_xor. Direct store: no atomics,
// no zero-init of the output needed.
__global__ void __launch_bounds__(BT)
k_prop(const unsigned* __restrict__ csr, const unsigned* __restrict__ rs,
       const unsigned* __restrict__ lin, unsigned* __restrict__ lout,
       int N, int E) {
    int g = (blockIdx.x * BT + threadIdx.x) >> 2;   // row
    int l = threadIdx.x & 3;
    if (g >= N) return;
    unsigned s = rs[g];
    unsigned e = (g + 1 < N) ? rs[g + 1] : (unsigned)E;
    unsigned d = e - s;
    unsigned h = 0u;
    unsigned M = (d > (unsigned)l) ? ((d - (unsigned)l + 3u) >> 2) : 0u;
    for (unsigned m = 0; m < M; ++m) {
        unsigned col = csr[s + (unsigned)l + 4u * m];
        h = h * 923521u + lin[col];                 // 31^4
    }
    if (M) {
        unsigned T = d - 1u - (unsigned)l - 4u * (M - 1u);   // in [0,3]
        unsigned p = ((T & 1u) ? 31u : 1u) * ((T & 2u) ? 961u : 1u);
        h *= p;
    }
    h += __shfl_xor(h, 1, 64);
    h += __shfl_xor(h, 2, 64);
    if (l == 0) lout[g] = h;
}

__global__ void __launch_bounds__(BT)
k_out(const unsigned* __restrict__ l0, const unsigned* __restrict__ l1,
      const unsigned* __restrict__ l2, const unsigned* __restrict__ l3,
      int* __restrict__ out, int N) {
    for (int i = blockIdx.x * BT + threadIdx.x; i < N; i += 256 * BT) {
        int a0 = (int)l0[i], a1 = (int)l1[i], a2 = (int)l2[i], a3 = (int)l3[i];
        out[i]         = a3;
        out[N + i]     = a0;
        out[2 * N + i] = a1;
        out[3 * N + i] = a2;
        out[4 * N + i] = a3;
    }
}

extern "C" void kernel_launch(void* const* d_in, const int* in_sizes, int n_in,
                              void* d_out, int out_size, void* d_ws, size_t ws_size,
                              hipStream_t stream) {
    const float* x  = (const float*)d_in[0];
    const int*   ei = (const int*)d_in[1];
    int* out = (int*)d_out;

    int N = in_sizes[0] / WL_D;
    int E = in_sizes[1] / 2;
    int chunk    = (E + NCH - 1) / NCH;        // 3125
    int nbuckets = (N + BROWS - 1) / BROWS;    // 391
    int L        = nbuckets * NCH;             // 400,384
    int ntiles   = (L + 1023) / 1024;          // 391 (<= 512: single-block sums ok)
    int vtiles   = (nbuckets + 63) / 64;       // 7
    int btiles   = NCH / 64;                   // 16
    int pgrid    = (4 * N + BT - 1) / BT;      // 782 (4 lanes per row)

    // workspace layout (uint32 units) — everything written before read
    unsigned* ws   = (unsigned*)d_ws;
    unsigned* lab0 = ws;               // N
    unsigned* lab1 = lab0 + N;         // N
    unsigned* lab2 = lab1 + N;         // N
    unsigned* lab3 = lab2 + N;         // N
    unsigned* rs   = lab3 + N;         // N
    unsigned* bs   = rs + N;           // 1024
    unsigned* hist = bs + 1024;        // L
    unsigned* buf  = hist + L;         // E
    unsigned* csr  = buf + E;          // E
    unsigned* histT = csr;             // transient: csr space is free until k_bucket

    k_hist_argmax<<<GRID_F, BT, 0, stream>>>(x, ei, lab0, hist, N, E, chunk, nbuckets);
    k_scan_tile<<<ntiles, BT, 0, stream>>>(hist, bs, L);
    k_scan_sums<<<1, BT, 0, stream>>>(bs, ntiles);
    k_transp<<<vtiles * btiles, BT, 0, stream>>>(hist, bs, histT, nbuckets);
    k_scatter<<<NCH, BT, 0, stream>>>(ei, histT, buf, E, chunk, nbuckets);
    k_bucket<<<nbuckets, BT, 0, stream>>>(buf, hist, bs, csr, rs, N, E, nbuckets);
    k_prop<<<pgrid, BT, 0, stream>>>(csr, rs, lab0, lab1, N, E);
    k_prop<<<pgrid, BT, 0, stream>>>(csr, rs, lab1, lab2, N, E);
    k_prop<<<pgrid, BT, 0, stream>>>(csr, rs, lab2, lab3, N, E);
    k_out<<<256, BT, 0, stream>>>(lab0, lab1, lab2, lab3, out, N);
}

// Round 4
// 216.590 us; speedup vs baseline: 1.2055x; 1.1019x over previous
//
#include <hip/hip_runtime.h>
#include <hip/hip_bf16.h>

// WeisfeilerLehman: labels0 = argmax(x, -1); 3x ordered polynomial hash over edges.
// All arithmetic mod 2^32 (uint32 wrap) == reference int64 truncated to int32.
// R15: scatter reg-prefetch; histT transposed seed; Horner k_prop (no search).
// R16: (a) NCH 1024->512: per-(chunk,bucket) scatter runs grow 8->16 entries
//      (= one full 64B line) killing the ~2x write amp; prefetch ILP (13 batches
//      in regs) replaces the occupancy that motivated 1024. (b) k_prop 8 lanes/row
//      (base-31^8) halves the dependent-gather chain. (c) argmax 2 rows/wave via
//      float4 + width-32 reduce. (d) k_out folded into k_prop_final (one fewer
//      launch; lab3 never materialized).

#define WL_D 128
#define NCH 512             // MSD chunk count (scatter grid)
#define GRID_F 2048         // fused hist/argmax grid
#define BT 512              // threads per block (8 waves)
#define MSDW 8
#define BBITS 8             // bucket = row >> 8
#define BROWS 256           // rows per bucket
#define NBK 512             // max buckets (N <= 131072)
#define RLSHIFT 23          // buf pack: (rl << 23) | col   (col < 2^23)
#define COLMASK ((1u << RLSHIFT) - 1u)
#define CMAX 10240          // LDS-staged output cap (40 KB)
#define NBMAX 13            // unrolled batches per wave in k_scatter (chunk 6250)
#define HP8 2487512833u     // 31^8 mod 2^32

// mask of lanes whose low BITS bits of v match mine (inactive lanes use a
// sentinel outside the valid key range so they never match active lanes)
template <int BITS>
__device__ inline unsigned long long match_key(unsigned v) {
    unsigned long long m = ~0ull;
    #pragma unroll
    for (int b = 0; b < BITS; ++b) {
        unsigned long long s = __ballot((v >> b) & 1u);
        m &= ((v >> b) & 1u) ? s : ~s;
    }
    return m;
}

// ---- fused: chunk bucket-histogram (blocks < NCH) + argmax ----
__global__ void __launch_bounds__(BT)
k_hist_argmax(const float* __restrict__ x, const int* __restrict__ ei,
              unsigned* __restrict__ lab0, unsigned* __restrict__ hist,
              int N, int E, int chunk, int nbuckets) {
    __shared__ unsigned h[NBK];
    int b = blockIdx.x, t = threadIdx.x, lane = t & 63, w = t >> 6;
    if (b < NCH) {                      // uniform per-block condition: syncs are safe
        for (int i = t; i < nbuckets; i += BT) h[i] = 0u;
        __syncthreads();
        int base = b * chunk, lim = min(base + chunk, E);
        for (int e = base + t; e < lim; e += BT)
            atomicAdd(&h[((unsigned)ei[e]) >> BBITS], 1u);
        __syncthreads();
        for (int v = t; v < nbuckets; v += BT) hist[(size_t)v * NCH + b] = h[v];
    }
    // argmax: 2 rows per wave (float4; lanes 0-31 row 2pr, lanes 32-63 row 2pr+1)
    int half = lane >> 5, li = lane & 31;
    for (int pr = b * MSDW + w; 2 * pr < N; pr += GRID_F * MSDW) {
        int r = 2 * pr + half;
        float bv = -3.4e38f; int bi = 0;
        if (r < N) {
            float4 v = ((const float4*)(x + (size_t)r * WL_D))[li];
            bv = v.x; bi = 4 * li;
            if (v.y > bv) { bv = v.y; bi = 4 * li + 1; }
            if (v.z > bv) { bv = v.z; bi = 4 * li + 2; }
            if (v.w > bv) { bv = v.w; bi = 4 * li + 3; }
        }
        #pragma unroll
        for (int off = 16; off > 0; off >>= 1) {
            float ov = __shfl_down(bv, off, 32);
            int   oi = __shfl_down(bi, off, 32);
            if (ov > bv || (ov == bv && oi < bi)) { bv = ov; bi = oi; }
        }
        if (li == 0 && r < N) lab0[r] = (unsigned)bi;
    }
}

// ---- scan: tile (1024 elems / block, 2 per thread) + sums ----
__global__ void __launch_bounds__(BT)
k_scan_tile(unsigned* __restrict__ hist, unsigned* __restrict__ bsums, int L) {
    __shared__ unsigned smem[BT];
    int b = blockIdx.x, t = threadIdx.x;
    int i0 = b * 1024;
    unsigned v0 = (i0 + 2 * t     < L) ? hist[i0 + 2 * t]     : 0u;
    unsigned v1 = (i0 + 2 * t + 1 < L) ? hist[i0 + 2 * t + 1] : 0u;
    unsigned s = v0 + v1;
    smem[t] = s;
    __syncthreads();
    for (int o = 1; o < BT; o <<= 1) {
        unsigned u = (t >= o) ? smem[t - o] : 0u;
        __syncthreads();
        smem[t] += u;
        __syncthreads();
    }
    unsigned excl = smem[t] - s;
    if (i0 + 2 * t     < L) hist[i0 + 2 * t]     = excl;
    if (i0 + 2 * t + 1 < L) hist[i0 + 2 * t + 1] = excl + v0;
    if (t == BT - 1) bsums[b] = smem[BT - 1];
}

__global__ void __launch_bounds__(BT)
k_scan_sums(unsigned* __restrict__ bsums, int ntiles) {
    __shared__ unsigned smem[BT];
    int t = threadIdx.x;
    unsigned v = (t < ntiles) ? bsums[t] : 0u;
    smem[t] = v;
    __syncthreads();
    for (int o = 1; o < BT; o <<= 1) {
        unsigned u = (t >= o) ? smem[t - o] : 0u;
        __syncthreads();
        smem[t] += u;
        __syncthreads();
    }
    if (t < ntiles) bsums[t] = smem[t] - v;
}

// ---- tiled transpose of scanned hist (+bsums) -> histT[b][v], both sides coalesced ----
__global__ void __launch_bounds__(BT)
k_transp(const unsigned* __restrict__ hist, const unsigned* __restrict__ bsums,
         unsigned* __restrict__ histT, int nbuckets) {
    __shared__ unsigned tl[64][65];
    int vtiles = (nbuckets + 63) / 64;
    int bx = blockIdx.x % vtiles;        // v-tile
    int by = blockIdx.x / vtiles;        // b-tile
    int tx = threadIdx.x & 63, ty = threadIdx.x >> 6;   // 64 x 8
    int v0 = bx * 64, b0 = by * 64;
    #pragma unroll
    for (int r = 0; r < 8; ++r) {
        int row = r * 8 + ty;
        int v = v0 + row;
        size_t idx = (size_t)v * NCH + (b0 + tx);
        tl[row][tx] = (v < nbuckets) ? (hist[idx] + bsums[idx >> 10]) : 0u;
    }
    __syncthreads();
    #pragma unroll
    for (int r = 0; r < 8; ++r) {
        int row = r * 8 + ty;            // b-offset within tile
        int v = v0 + tx;
        if (v < nbuckets) histT[(size_t)(b0 + row) * nbuckets + v] = tl[tx][row];
    }
}

// ---- stable MSD scatter: prefetched batches, per-(wave,bucket) LDS cursors ----
__global__ void __launch_bounds__(BT)
k_scatter(const int* __restrict__ ei, const unsigned* __restrict__ histT,
          unsigned* __restrict__ buf, int E, int chunk, int nbuckets) {
    __shared__ unsigned wbase[MSDW * NBK];   // 16 KB
    int b = blockIdx.x, t = threadIdx.x, lane = t & 63, w = t >> 6;
    unsigned long long lmask = (1ull << lane) - 1ull;
    for (int i = t; i < MSDW * NBK; i += BT) wbase[i] = 0u;
    __syncthreads();
    int base = b * chunk, lim = min(base + chunk, E);
    int sub  = (chunk + MSDW - 1) / MSDW;
    int wbeg = base + w * sub;
    int wend = min(wbeg + sub, lim);
    int nbat = (wbeg < wend) ? ((wend - wbeg + 63) >> 6) : 0;
    // prefetch all row loads (static reg indices; issued before any ballot chain)
    unsigned r_[NBMAX];
    #pragma unroll
    for (int k = 0; k < NBMAX; ++k) {
        int e = wbeg + k * 64 + lane;
        r_[k] = (e < wend) ? (unsigned)ei[e] : 0u;
    }
    // pass A: per-wave bucket counts
    #pragma unroll
    for (int k = 0; k < NBMAX; ++k) {
        if (k >= nbat) break;
        int e = wbeg + k * 64 + lane;
        bool act = (e < wend);
        unsigned v = act ? (r_[k] >> BBITS) : (NBK - 1u);
        unsigned long long m = match_key<9>(v);
        unsigned before = (unsigned)__popcll(m & lmask);
        unsigned total  = (unsigned)__popcll(m);
        if (act && before == 0u) wbase[w * NBK + v] += total;
    }
    for (int k = NBMAX; k < nbat; ++k) {     // dynamic tail (robustness)
        int e = wbeg + k * 64 + lane;
        bool act = (e < wend);
        unsigned v = act ? (((unsigned)ei[e]) >> BBITS) : (NBK - 1u);
        unsigned long long m = match_key<9>(v);
        unsigned before = (unsigned)__popcll(m & lmask);
        unsigned total  = (unsigned)__popcll(m);
        if (act && before == 0u) wbase[w * NBK + v] += total;
    }
    __syncthreads();
    // seed per-wave cursors from transposed bases (coalesced)
    for (int v = t; v < nbuckets; v += BT) {
        unsigned g = histT[(size_t)b * nbuckets + v];
        #pragma unroll
        for (int w2 = 0; w2 < MSDW; ++w2) {
            unsigned cnt = wbase[w2 * NBK + v];
            wbase[w2 * NBK + v] = g;
            g += cnt;
        }
    }
    __syncthreads();
    // pass B: prefetch cols (rows still live in r_), stable scatter
    unsigned c_[NBMAX];
    #pragma unroll
    for (int k = 0; k < NBMAX; ++k) {
        int e = wbeg + k * 64 + lane;
        c_[k] = (e < wend) ? (unsigned)ei[(size_t)E + e] : 0u;
    }
    #pragma unroll
    for (int k = 0; k < NBMAX; ++k) {
        if (k >= nbat) break;
        int e = wbeg + k * 64 + lane;
        bool act = (e < wend);
        unsigned r = r_[k], col = c_[k];
        unsigned v = act ? (r >> BBITS) : (NBK - 1u);
        unsigned long long m = match_key<9>(v);
        unsigned before = (unsigned)__popcll(m & lmask);
        unsigned total  = (unsigned)__popcll(m);
        int leader = __ffsll(m) - 1;
        unsigned base0 = 0;
        if (act && before == 0u) { base0 = wbase[w * NBK + v]; wbase[w * NBK + v] = base0 + total; }
        base0 = __shfl(base0, leader, 64);
        if (act) buf[base0 + before] = ((r & (BROWS - 1u)) << RLSHIFT) | col;
    }
    for (int k = NBMAX; k < nbat; ++k) {     // dynamic tail
        int e = wbeg + k * 64 + lane;
        bool act = (e < wend);
        unsigned r   = act ? (unsigned)ei[e] : 0u;
        unsigned col = act ? (unsigned)ei[(size_t)E + e] : 0u;
        unsigned v = act ? (r >> BBITS) : (NBK - 1u);
        unsigned long long m = match_key<9>(v);
        unsigned before = (unsigned)__popcll(m & lmask);
        unsigned total  = (unsigned)__popcll(m);
        int leader = __ffsll(m) - 1;
        unsigned base0 = 0;
        if (act && before == 0u) { base0 = wbase[w * NBK + v]; wbase[w * NBK + v] = base0 + total; }
        base0 = __shfl(base0, leader, 64);
        if (act) buf[base0 + before] = ((r & (BROWS - 1u)) << RLSHIFT) | col;
    }
}

// ---- per-bucket stable counting sort by rl; output staged in LDS, streamed out ----
__global__ void __launch_bounds__(BT)
k_bucket(const unsigned* __restrict__ buf, const unsigned* __restrict__ hist,
         const unsigned* __restrict__ bsums, unsigned* __restrict__ csr,
         unsigned* __restrict__ rs_g, int N, int E, int nbuckets) {
    __shared__ unsigned data2[CMAX];          // 40 KB (sorted output staging)
    __shared__ unsigned h2[MSDW * BROWS];     // 8 KB
    __shared__ unsigned offs[BROWS];          // 1 KB
    int bb = blockIdx.x, t = threadIdx.x, lane = t & 63, w = t >> 6;
    unsigned long long lmask = (1ull << lane) - 1ull;
    size_t i0 = (size_t)bb * NCH;
    unsigned start = hist[i0] + bsums[i0 >> 10];
    unsigned end;
    if (bb + 1 < nbuckets) { size_t i1 = (size_t)(bb + 1) * NCH; end = hist[i1] + bsums[i1 >> 10]; }
    else end = (unsigned)E;
    unsigned len = end - start;
    bool lds_ok = (len <= CMAX);
    for (int i = t; i < MSDW * BROWS; i += BT) h2[i] = 0u;
    __syncthreads();
    unsigned sub  = (len + MSDW - 1u) / MSDW;
    unsigned wbeg = w * sub;
    unsigned wend = min(wbeg + sub, len);
    int nbat = (wbeg < wend) ? (int)((wend - wbeg + 63u) >> 6) : 0;
    // pass A: per-wave rl counts (input read straight from L2/L3-hot buf)
    for (int bt2 = 0; bt2 < nbat; ++bt2) {
        unsigned i = wbeg + (unsigned)(bt2 * 64 + lane);
        bool act = (i < wend);
        unsigned v = act ? (buf[start + i] >> RLSHIFT) : 511u;
        unsigned long long m = match_key<9>(v);
        unsigned before = (unsigned)__popcll(m & lmask);
        unsigned total  = (unsigned)__popcll(m);
        if (act && before == 0u) h2[w * BROWS + v] += total;
    }
    __syncthreads();
    // exclusive scan over rl (256 entries, threads t < BROWS); emit rs; seed cursors
    unsigned hv = 0;
    if (t < BROWS) {
        #pragma unroll
        for (int w2 = 0; w2 < MSDW; ++w2) hv += h2[w2 * BROWS + t];
        offs[t] = hv;
    }
    __syncthreads();
    for (int o = 1; o < BROWS; o <<= 1) {
        unsigned s = (t < BROWS && t >= o) ? offs[t - o] : 0u;
        __syncthreads();
        if (t < BROWS) offs[t] += s;
        __syncthreads();
    }
    if (t < BROWS) {
        unsigned excl = offs[t] - hv;
        int row = bb * BROWS + t;
        if (row < N) rs_g[row] = start + excl;
        unsigned g = lds_ok ? excl : (start + excl);   // bucket-relative if LDS-staged
        #pragma unroll
        for (int w2 = 0; w2 < MSDW; ++w2) {
            unsigned cnt = h2[w2 * BROWS + t];
            h2[w2 * BROWS + t] = g;
            g += cnt;
        }
    }
    __syncthreads();
    // pass B: stable scatter cols into LDS staging (or csr directly on fallback)
    for (int bt2 = 0; bt2 < nbat; ++bt2) {
        unsigned i = wbeg + (unsigned)(bt2 * 64 + lane);
        bool act = (i < wend);
        unsigned p = act ? buf[start + i] : 0u;
        unsigned v = act ? (p >> RLSHIFT) : 511u;
        unsigned long long m = match_key<9>(v);
        unsigned before = (unsigned)__popcll(m & lmask);
        unsigned total  = (unsigned)__popcll(m);
        int leader = __ffsll(m) - 1;
        unsigned base0 = 0;
        if (act && before == 0u) { base0 = h2[w * BROWS + v]; h2[w * BROWS + v] = base0 + total; }
        base0 = __shfl(base0, leader, 64);
        if (act) {
            if (lds_ok) data2[base0 + before] = p & COLMASK;
            else        csr[base0 + before]   = p & COLMASK;
        }
    }
    __syncthreads();
    // stream sorted bucket out contiguously (1x write amplification)
    if (lds_ok) for (unsigned i = t; i < len; i += BT) csr[start + i] = data2[i];
}

// ---- prop: 8 lanes per row, base-31^8 Horner over the row's csr segment ----
// label_next[row] = sum_j lin[col_j] * 31^(d-1-j). Lane l takes j = l, l+8, ...;
// exponent d-1-l-8m = 8*(M-1-m) + T with T = d-1-l-8(M-1) in [0,7].
__device__ inline unsigned horner8(const unsigned* __restrict__ csr,
                                   const unsigned* __restrict__ rs,
                                   const unsigned* __restrict__ lin,
                                   int g, int l, int N, int E) {
    unsigned s = rs[g];
    unsigned e = (g + 1 < N) ? rs[g + 1] : (unsigned)E;
    unsigned d = e - s;
    unsigned h = 0u;
    unsigned M = (d > (unsigned)l) ? ((d - (unsigned)l + 7u) >> 3) : 0u;
    for (unsigned m = 0; m < M; ++m) {
        unsigned col = csr[s + (unsigned)l + 8u * m];
        h = h * HP8 + lin[col];
    }
    if (M) {
        unsigned T = d - 1u - (unsigned)l - 8u * (M - 1u);   // in [0,7]
        unsigned p = ((T & 1u) ? 31u : 1u) * ((T & 2u) ? 961u : 1u)
                   * ((T & 4u) ? 923521u : 1u);
        h *= p;
    }
    h += __shfl_xor(h, 1, 64);
    h += __shfl_xor(h, 2, 64);
    h += __shfl_xor(h, 4, 64);
    return h;
}

__global__ void __launch_bounds__(BT)
k_prop(const unsigned* __restrict__ csr, const unsigned* __restrict__ rs,
       const unsigned* __restrict__ lin, unsigned* __restrict__ lout,
       int N, int E) {
    int idx = blockIdx.x * BT + threadIdx.x;
    int g = idx >> 3, l = idx & 7;
    if (g >= N) return;
    unsigned h = horner8(csr, rs, lin, g, l, N, E);
    if (l == 0) lout[g] = h;
}

// final prop: writes lab3 straight into out[0..N) and out[4N..5N), plus copies
// lab0..2 into out[N..4N) (k_out folded in; lab3 never materialized)
__global__ void __launch_bounds__(BT)
k_prop_final(const unsigned* __restrict__ csr, const unsigned* __restrict__ rs,
             const unsigned* __restrict__ lin, const unsigned* __restrict__ l0,
             const unsigned* __restrict__ l1, int* __restrict__ out,
             int N, int E, int pgrid) {
    int idx = blockIdx.x * BT + threadIdx.x;
    int g = idx >> 3, l = idx & 7;
    if (g < N) {
        unsigned h = horner8(csr, rs, lin, g, l, N, E);
        if (l == 0) { out[g] = (int)h; out[4 * N + g] = (int)h; }
    }
    for (int i = idx; i < N; i += pgrid * BT) {
        out[N + i]     = (int)l0[i];
        out[2 * N + i] = (int)l1[i];
        out[3 * N + i] = (int)lin[i];    // lin == lab2 on the final pass
    }
}

extern "C" void kernel_launch(void* const* d_in, const int* in_sizes, int n_in,
                              void* d_out, int out_size, void* d_ws, size_t ws_size,
                              hipStream_t stream) {
    const float* x  = (const float*)d_in[0];
    const int*   ei = (const int*)d_in[1];
    int* out = (int*)d_out;

    int N = in_sizes[0] / WL_D;
    int E = in_sizes[1] / 2;
    int chunk    = (E + NCH - 1) / NCH;        // 6250
    int nbuckets = (N + BROWS - 1) / BROWS;    // 391
    int L        = nbuckets * NCH;             // 200,192
    int ntiles   = (L + 1023) / 1024;          // 196 (<= 512: single-block sums ok)
    int vtiles   = (nbuckets + 63) / 64;       // 7
    int btiles   = NCH / 64;                   // 8
    int pgrid    = (8 * N + BT - 1) / BT;      // 1563 (8 lanes per row)

    // workspace layout (uint32 units) — everything written before read
    unsigned* ws   = (unsigned*)d_ws;
    unsigned* lab0 = ws;               // N
    unsigned* lab1 = lab0 + N;         // N
    unsigned* lab2 = lab1 + N;         // N
    unsigned* rs   = lab2 + N;         // N
    unsigned* bs   = rs + N;           // 1024
    unsigned* hist = bs + 1024;        // L
    unsigned* buf  = hist + L;         // E
    unsigned* csr  = buf + E;          // E
    unsigned* histT = csr;             // transient: csr space is free until k_bucket

    k_hist_argmax<<<GRID_F, BT, 0, stream>>>(x, ei, lab0, hist, N, E, chunk, nbuckets);
    k_scan_tile<<<ntiles, BT, 0, stream>>>(hist, bs, L);
    k_scan_sums<<<1, BT, 0, stream>>>(bs, ntiles);
    k_transp<<<vtiles * btiles, BT, 0, stream>>>(hist, bs, histT, nbuckets);
    k_scatter<<<NCH, BT, 0, stream>>>(ei, histT, buf, E, chunk, nbuckets);
    k_bucket<<<nbuckets, BT, 0, stream>>>(buf, hist, bs, csr, rs, N, E, nbuckets);
    k_prop<<<pgrid, BT, 0, stream>>>(csr, rs, lab0, lab1, N, E);
    k_prop<<<pgrid, BT, 0, stream>>>(csr, rs, lab1, lab2, N, E);
    k_prop_final<<<pgrid, BT, 0, stream>>>(csr, rs, lab2, lab0, lab1, out, N, E, pgrid);
}

// Round 5
// 209.086 us; speedup vs baseline: 1.2488x; 1.0359x over previous
//
#include <hip/hip_runtime.h>
#include <hip/hip_bf16.h>

// WeisfeilerLehman: labels0 = argmax(x, -1); 3x ordered polynomial hash over edges.
// All arithmetic mod 2^32 (uint32 wrap) == reference int64 truncated to int32.
// R16: NCH 512 (full-line scatter runs); 8-lane Horner prop; k_out folded.
// R17: (a) first prop fused into k_bucket: sorted cols are already in LDS with
//      row boundaries in offs[] -- computing lab1 there deletes a k_prop launch
//      plus its 13MB csr+rs re-read. (b) k_scan_sums + bucket-start extraction
//      folded into k_transp (per-block redundant 196-elem scan; bstart[v] array
//      replaces strided hist/bsums addressing in k_bucket). (c) k_scatter caches
//      pass-A match masks (m_[13], +26 VGPR) so pass B skips the 9-ballot chain.
//      Launches 9 -> 7.

#define WL_D 128
#define NCH 512             // MSD chunk count (scatter grid)
#define GRID_F 2048         // fused hist/argmax grid
#define BT 512              // threads per block (8 waves)
#define MSDW 8
#define BBITS 8             // bucket = row >> 8
#define BROWS 256           // rows per bucket
#define NBK 512             // max buckets (N <= 131072)
#define RLSHIFT 23          // buf pack: (rl << 23) | col   (col < 2^23)
#define COLMASK ((1u << RLSHIFT) - 1u)
#define CMAX 10240          // LDS-staged output cap (40 KB)
#define NBMAX 13            // unrolled batches per wave in k_scatter (chunk 6250)
#define HP8 2487512833u     // 31^8 mod 2^32

// mask of lanes whose low BITS bits of v match mine (inactive lanes use a
// sentinel outside the valid key range so they never match active lanes)
template <int BITS>
__device__ inline unsigned long long match_key(unsigned v) {
    unsigned long long m = ~0ull;
    #pragma unroll
    for (int b = 0; b < BITS; ++b) {
        unsigned long long s = __ballot((v >> b) & 1u);
        m &= ((v >> b) & 1u) ? s : ~s;
    }
    return m;
}

// ---- fused: chunk bucket-histogram (blocks < NCH) + argmax ----
__global__ void __launch_bounds__(BT)
k_hist_argmax(const float* __restrict__ x, const int* __restrict__ ei,
              unsigned* __restrict__ lab0, unsigned* __restrict__ hist,
              int N, int E, int chunk, int nbuckets) {
    __shared__ unsigned h[NBK];
    int b = blockIdx.x, t = threadIdx.x, lane = t & 63, w = t >> 6;
    if (b < NCH) {                      // uniform per-block condition: syncs are safe
        for (int i = t; i < nbuckets; i += BT) h[i] = 0u;
        __syncthreads();
        int base = b * chunk, lim = min(base + chunk, E);
        for (int e = base + t; e < lim; e += BT)
            atomicAdd(&h[((unsigned)ei[e]) >> BBITS], 1u);
        __syncthreads();
        for (int v = t; v < nbuckets; v += BT) hist[(size_t)v * NCH + b] = h[v];
    }
    // argmax: 2 rows per wave (float4; lanes 0-31 row 2pr, lanes 32-63 row 2pr+1)
    int half = lane >> 5, li = lane & 31;
    for (int pr = b * MSDW + w; 2 * pr < N; pr += GRID_F * MSDW) {
        int r = 2 * pr + half;
        float bv = -3.4e38f; int bi = 0;
        if (r < N) {
            float4 v = ((const float4*)(x + (size_t)r * WL_D))[li];
            bv = v.x; bi = 4 * li;
            if (v.y > bv) { bv = v.y; bi = 4 * li + 1; }
            if (v.z > bv) { bv = v.z; bi = 4 * li + 2; }
            if (v.w > bv) { bv = v.w; bi = 4 * li + 3; }
        }
        #pragma unroll
        for (int off = 16; off > 0; off >>= 1) {
            float ov = __shfl_down(bv, off, 32);
            int   oi = __shfl_down(bi, off, 32);
            if (ov > bv || (ov == bv && oi < bi)) { bv = ov; bi = oi; }
        }
        if (li == 0 && r < N) lab0[r] = (unsigned)bi;
    }
}

// ---- scan: tile (1024 elems / block, 2 per thread) + raw tile totals ----
__global__ void __launch_bounds__(BT)
k_scan_tile(unsigned* __restrict__ hist, unsigned* __restrict__ bsums, int L) {
    __shared__ unsigned smem[BT];
    int b = blockIdx.x, t = threadIdx.x;
    int i0 = b * 1024;
    unsigned v0 = (i0 + 2 * t     < L) ? hist[i0 + 2 * t]     : 0u;
    unsigned v1 = (i0 + 2 * t + 1 < L) ? hist[i0 + 2 * t + 1] : 0u;
    unsigned s = v0 + v1;
    smem[t] = s;
    __syncthreads();
    for (int o = 1; o < BT; o <<= 1) {
        unsigned u = (t >= o) ? smem[t - o] : 0u;
        __syncthreads();
        smem[t] += u;
        __syncthreads();
    }
    unsigned excl = smem[t] - s;
    if (i0 + 2 * t     < L) hist[i0 + 2 * t]     = excl;
    if (i0 + 2 * t + 1 < L) hist[i0 + 2 * t + 1] = excl + v0;
    if (t == BT - 1) bsums[b] = smem[BT - 1];
}

// ---- transpose scanned hist (+bsums scanned in-block) -> histT[b][v]; emit bstart ----
__global__ void __launch_bounds__(BT)
k_transp(const unsigned* __restrict__ hist, const unsigned* __restrict__ bsums,
         unsigned* __restrict__ histT, unsigned* __restrict__ bstart,
         int nbuckets, int ntiles, int E) {
    __shared__ unsigned tl[64][65];
    __shared__ unsigned sb[BT];
    int t = threadIdx.x;
    // replicated exclusive scan of bsums (ntiles <= 512)
    unsigned my = (t < ntiles) ? bsums[t] : 0u;
    sb[t] = my;
    __syncthreads();
    for (int o = 1; o < BT; o <<= 1) {
        unsigned u = (t >= o) ? sb[t - o] : 0u;
        __syncthreads();
        sb[t] += u;
        __syncthreads();
    }
    sb[t] -= my;                         // inclusive -> exclusive
    __syncthreads();
    int vtiles = (nbuckets + 63) / 64;
    int bx = blockIdx.x % vtiles;        // v-tile
    int by = blockIdx.x / vtiles;        // b-tile
    int tx = t & 63, ty = t >> 6;        // 64 x 8
    int vb = bx * 64, b0 = by * 64;
    #pragma unroll
    for (int r = 0; r < 8; ++r) {
        int row = r * 8 + ty;
        int v = vb + row;
        size_t idx = (size_t)v * NCH + (b0 + tx);
        tl[row][tx] = (v < nbuckets) ? (hist[idx] + sb[idx >> 10]) : 0u;
    }
    __syncthreads();
    #pragma unroll
    for (int r = 0; r < 8; ++r) {
        int row = r * 8 + ty;            // b-offset within tile
        int v = vb + tx;
        if (v < nbuckets) histT[(size_t)(b0 + row) * nbuckets + v] = tl[tx][row];
    }
    // bucket starts = chunk-0 column of the scanned hist
    if (by == 0 && t < 64) {
        int v = vb + t;
        if (v < nbuckets) bstart[v] = tl[t][0];
    }
    if (blockIdx.x == 0 && t == 64) bstart[nbuckets] = (unsigned)E;
}

// ---- stable MSD scatter: prefetched batches + cached masks, LDS cursors ----
__global__ void __launch_bounds__(BT)
k_scatter(const int* __restrict__ ei, const unsigned* __restrict__ histT,
          unsigned* __restrict__ buf, int E, int chunk, int nbuckets) {
    __shared__ unsigned wbase[MSDW * NBK];   // 16 KB
    int b = blockIdx.x, t = threadIdx.x, lane = t & 63, w = t >> 6;
    unsigned long long lmask = (1ull << lane) - 1ull;
    for (int i = t; i < MSDW * NBK; i += BT) wbase[i] = 0u;
    __syncthreads();
    int base = b * chunk, lim = min(base + chunk, E);
    int sub  = (chunk + MSDW - 1) / MSDW;
    int wbeg = base + w * sub;
    int wend = min(wbeg + sub, lim);
    int nbat = (wbeg < wend) ? ((wend - wbeg + 63) >> 6) : 0;
    // prefetch all row loads (static reg indices; issued before any ballot chain)
    unsigned r_[NBMAX];
    #pragma unroll
    for (int k = 0; k < NBMAX; ++k) {
        int e = wbeg + k * 64 + lane;
        r_[k] = (e < wend) ? (unsigned)ei[e] : 0u;
    }
    // pass A: per-wave bucket counts; cache the match masks
    unsigned long long m_[NBMAX];
    #pragma unroll
    for (int k = 0; k < NBMAX; ++k) {
        if (k >= nbat) break;
        int e = wbeg + k * 64 + lane;
        bool act = (e < wend);
        unsigned v = act ? (r_[k] >> BBITS) : (NBK - 1u);
        unsigned long long m = match_key<9>(v);
        m_[k] = m;
        unsigned before = (unsigned)__popcll(m & lmask);
        if (act && before == 0u) wbase[w * NBK + v] += (unsigned)__popcll(m);
    }
    for (int k = NBMAX; k < nbat; ++k) {     // dynamic tail (robustness)
        int e = wbeg + k * 64 + lane;
        bool act = (e < wend);
        unsigned v = act ? (((unsigned)ei[e]) >> BBITS) : (NBK - 1u);
        unsigned long long m = match_key<9>(v);
        unsigned before = (unsigned)__popcll(m & lmask);
        if (act && before == 0u) wbase[w * NBK + v] += (unsigned)__popcll(m);
    }
    __syncthreads();
    // seed per-wave cursors from transposed bases (coalesced)
    for (int v = t; v < nbuckets; v += BT) {
        unsigned g = histT[(size_t)b * nbuckets + v];
        #pragma unroll
        for (int w2 = 0; w2 < MSDW; ++w2) {
            unsigned cnt = wbase[w2 * NBK + v];
            wbase[w2 * NBK + v] = g;
            g += cnt;
        }
    }
    __syncthreads();
    // pass B: prefetch cols (rows still live in r_), reuse masks, stable scatter
    unsigned c_[NBMAX];
    #pragma unroll
    for (int k = 0; k < NBMAX; ++k) {
        int e = wbeg + k * 64 + lane;
        c_[k] = (e < wend) ? (unsigned)ei[(size_t)E + e] : 0u;
    }
    #pragma unroll
    for (int k = 0; k < NBMAX; ++k) {
        if (k >= nbat) break;
        int e = wbeg + k * 64 + lane;
        bool act = (e < wend);
        unsigned r = r_[k], col = c_[k];
        unsigned v = r >> BBITS;                 // used only when act
        unsigned long long m = m_[k];
        unsigned before = (unsigned)__popcll(m & lmask);
        int leader = __ffsll(m) - 1;
        unsigned base0 = 0;
        if (act && before == 0u) {
            base0 = wbase[w * NBK + v];
            wbase[w * NBK + v] = base0 + (unsigned)__popcll(m);
        }
        base0 = __shfl(base0, leader, 64);
        if (act) buf[base0 + before] = ((r & (BROWS - 1u)) << RLSHIFT) | col;
    }
    for (int k = NBMAX; k < nbat; ++k) {     // dynamic tail
        int e = wbeg + k * 64 + lane;
        bool act = (e < wend);
        unsigned r   = act ? (unsigned)ei[e] : 0u;
        unsigned col = act ? (unsigned)ei[(size_t)E + e] : 0u;
        unsigned v = act ? (r >> BBITS) : (NBK - 1u);
        unsigned long long m = match_key<9>(v);
        unsigned before = (unsigned)__popcll(m & lmask);
        unsigned total  = (unsigned)__popcll(m);
        int leader = __ffsll(m) - 1;
        unsigned base0 = 0;
        if (act && before == 0u) { base0 = wbase[w * NBK + v]; wbase[w * NBK + v] = base0 + total; }
        base0 = __shfl(base0, leader, 64);
        if (act) buf[base0 + before] = ((r & (BROWS - 1u)) << RLSHIFT) | col;
    }
}

// ---- per-bucket stable counting sort by rl (LDS-staged) + FUSED first prop ----
__global__ void __launch_bounds__(BT)
k_bucket(const unsigned* __restrict__ buf, const unsigned* __restrict__ bstart,
         unsigned* __restrict__ csr, unsigned* __restrict__ rs_g,
         const unsigned* __restrict__ lab0, unsigned* __restrict__ lab1,
         int N, int E, int nbuckets) {
    __shared__ unsigned data2[CMAX];          // 40 KB (sorted output staging)
    __shared__ unsigned h2[MSDW * BROWS];     // 8 KB
    __shared__ unsigned offs[BROWS];          // 1 KB
    int bb = blockIdx.x, t = threadIdx.x, lane = t & 63, w = t >> 6;
    unsigned long long lmask = (1ull << lane) - 1ull;
    unsigned start = bstart[bb];
    unsigned end   = bstart[bb + 1];
    unsigned len = end - start;
    bool lds_ok = (len <= CMAX);
    for (int i = t; i < MSDW * BROWS; i += BT) h2[i] = 0u;
    __syncthreads();
    unsigned sub  = (len + MSDW - 1u) / MSDW;
    unsigned wbeg = w * sub;
    unsigned wend = min(wbeg + sub, len);
    int nbat = (wbeg < wend) ? (int)((wend - wbeg + 63u) >> 6) : 0;
    // pass A: per-wave rl counts (input read straight from L2/L3-hot buf)
    for (int bt2 = 0; bt2 < nbat; ++bt2) {
        unsigned i = wbeg + (unsigned)(bt2 * 64 + lane);
        bool act = (i < wend);
        unsigned v = act ? (buf[start + i] >> RLSHIFT) : 511u;
        unsigned long long m = match_key<9>(v);
        unsigned before = (unsigned)__popcll(m & lmask);
        unsigned total  = (unsigned)__popcll(m);
        if (act && before == 0u) h2[w * BROWS + v] += total;
    }
    __syncthreads();
    // exclusive scan over rl (256 entries, threads t < BROWS); emit rs; seed cursors
    unsigned hv = 0;
    if (t < BROWS) {
        #pragma unroll
        for (int w2 = 0; w2 < MSDW; ++w2) hv += h2[w2 * BROWS + t];
        offs[t] = hv;
    }
    __syncthreads();
    for (int o = 1; o < BROWS; o <<= 1) {
        unsigned s = (t < BROWS && t >= o) ? offs[t - o] : 0u;
        __syncthreads();
        if (t < BROWS) offs[t] += s;
        __syncthreads();
    }
    if (t < BROWS) {
        unsigned excl = offs[t] - hv;
        int row = bb * BROWS + t;
        if (row < N) rs_g[row] = start + excl;
        unsigned g = lds_ok ? excl : (start + excl);   // bucket-relative if LDS-staged
        #pragma unroll
        for (int w2 = 0; w2 < MSDW; ++w2) {
            unsigned cnt = h2[w2 * BROWS + t];
            h2[w2 * BROWS + t] = g;
            g += cnt;
        }
    }
    __syncthreads();
    // pass B: stable scatter cols into LDS staging (or csr directly on fallback)
    for (int bt2 = 0; bt2 < nbat; ++bt2) {
        unsigned i = wbeg + (unsigned)(bt2 * 64 + lane);
        bool act = (i < wend);
        unsigned p = act ? buf[start + i] : 0u;
        unsigned v = act ? (p >> RLSHIFT) : 511u;
        unsigned long long m = match_key<9>(v);
        unsigned before = (unsigned)__popcll(m & lmask);
        unsigned total  = (unsigned)__popcll(m);
        int leader = __ffsll(m) - 1;
        unsigned base0 = 0;
        if (act && before == 0u) { base0 = h2[w * BROWS + v]; h2[w * BROWS + v] = base0 + total; }
        base0 = __shfl(base0, leader, 64);
        if (act) {
            if (lds_ok) data2[base0 + before] = p & COLMASK;
            else        csr[base0 + before]   = p & COLMASK;
        }
    }
    __syncthreads();
    // FUSED first prop: lab1 for this bucket's rows, 8 lanes/row, cols from LDS.
    // offs[r] is the inclusive row-end (bucket-relative); row start = offs[r-1].
    const unsigned* srcp = lds_ok ? (const unsigned*)data2 : (csr + start);
    int l = t & 7;
    for (int r0 = t >> 3; r0 < BROWS; r0 += BT / 8) {
        unsigned beg = r0 ? offs[r0 - 1] : 0u;
        unsigned d   = offs[r0] - beg;
        unsigned h = 0u;
        unsigned M = (d > (unsigned)l) ? ((d - (unsigned)l + 7u) >> 3) : 0u;
        for (unsigned m = 0; m < M; ++m) {
            unsigned col = srcp[beg + (unsigned)l + 8u * m];
            h = h * HP8 + lab0[col];
        }
        if (M) {
            unsigned T = d - 1u - (unsigned)l - 8u * (M - 1u);   // in [0,7]
            unsigned p = ((T & 1u) ? 31u : 1u) * ((T & 2u) ? 961u : 1u)
                       * ((T & 4u) ? 923521u : 1u);
            h *= p;
        }
        h += __shfl_xor(h, 1, 64);
        h += __shfl_xor(h, 2, 64);
        h += __shfl_xor(h, 4, 64);
        int row = bb * BROWS + r0;
        if (l == 0 && row < N) lab1[row] = h;
    }
    // stream sorted bucket out contiguously (1x write amplification)
    if (lds_ok) for (unsigned i = t; i < len; i += BT) csr[start + i] = data2[i];
}

// ---- prop: 8 lanes per row, base-31^8 Horner over the row's csr segment ----
__device__ inline unsigned horner8(const unsigned* __restrict__ csr,
                                   const unsigned* __restrict__ rs,
                                   const unsigned* __restrict__ lin,
                                   int g, int l, int N, int E) {
    unsigned s = rs[g];
    unsigned e = (g + 1 < N) ? rs[g + 1] : (unsigned)E;
    unsigned d = e - s;
    unsigned h = 0u;
    unsigned M = (d > (unsigned)l) ? ((d - (unsigned)l + 7u) >> 3) : 0u;
    for (unsigned m = 0; m < M; ++m) {
        unsigned col = csr[s + (unsigned)l + 8u * m];
        h = h * HP8 + lin[col];
    }
    if (M) {
        unsigned T = d - 1u - (unsigned)l - 8u * (M - 1u);   // in [0,7]
        unsigned p = ((T & 1u) ? 31u : 1u) * ((T & 2u) ? 961u : 1u)
                   * ((T & 4u) ? 923521u : 1u);
        h *= p;
    }
    h += __shfl_xor(h, 1, 64);
    h += __shfl_xor(h, 2, 64);
    h += __shfl_xor(h, 4, 64);
    return h;
}

__global__ void __launch_bounds__(BT)
k_prop(const unsigned* __restrict__ csr, const unsigned* __restrict__ rs,
       const unsigned* __restrict__ lin, unsigned* __restrict__ lout,
       int N, int E) {
    int idx = blockIdx.x * BT + threadIdx.x;
    int g = idx >> 3, l = idx & 7;
    if (g >= N) return;
    unsigned h = horner8(csr, rs, lin, g, l, N, E);
    if (l == 0) lout[g] = h;
}

// final prop: writes lab3 straight into out[0..N) and out[4N..5N), plus copies
// lab0..2 into out[N..4N)
__global__ void __launch_bounds__(BT)
k_prop_final(const unsigned* __restrict__ csr, const unsigned* __restrict__ rs,
             const unsigned* __restrict__ lin, const unsigned* __restrict__ l0,
             const unsigned* __restrict__ l1, int* __restrict__ out,
             int N, int E, int pgrid) {
    int idx = blockIdx.x * BT + threadIdx.x;
    int g = idx >> 3, l = idx & 7;
    if (g < N) {
        unsigned h = horner8(csr, rs, lin, g, l, N, E);
        if (l == 0) { out[g] = (int)h; out[4 * N + g] = (int)h; }
    }
    for (int i = idx; i < N; i += pgrid * BT) {
        out[N + i]     = (int)l0[i];
        out[2 * N + i] = (int)l1[i];
        out[3 * N + i] = (int)lin[i];    // lin == lab2 on the final pass
    }
}

extern "C" void kernel_launch(void* const* d_in, const int* in_sizes, int n_in,
                              void* d_out, int out_size, void* d_ws, size_t ws_size,
                              hipStream_t stream) {
    const float* x  = (const float*)d_in[0];
    const int*   ei = (const int*)d_in[1];
    int* out = (int*)d_out;

    int N = in_sizes[0] / WL_D;
    int E = in_sizes[1] / 2;
    int chunk    = (E + NCH - 1) / NCH;        // 6250
    int nbuckets = (N + BROWS - 1) / BROWS;    // 391
    int L        = nbuckets * NCH;             // 200,192
    int ntiles   = (L + 1023) / 1024;          // 196 (<= 512: in-block scan ok)
    int vtiles   = (nbuckets + 63) / 64;       // 7
    int btiles   = NCH / 64;                   // 8
    int pgrid    = (8 * N + BT - 1) / BT;      // 1563 (8 lanes per row)

    // workspace layout (uint32 units) — everything written before read
    unsigned* ws    = (unsigned*)d_ws;
    unsigned* lab0  = ws;               // N
    unsigned* lab1  = lab0 + N;         // N
    unsigned* lab2  = lab1 + N;         // N
    unsigned* rs    = lab2 + N;         // N
    unsigned* bs    = rs + N;           // 1024
    unsigned* bstart= bs + 1024;        // 1024 (nbuckets+1 used)
    unsigned* hist  = bstart + 1024;    // L
    unsigned* buf   = hist + L;         // E
    unsigned* csr   = buf + E;          // E
    unsigned* histT = csr;              // transient: csr space is free until k_bucket

    k_hist_argmax<<<GRID_F, BT, 0, stream>>>(x, ei, lab0, hist, N, E, chunk, nbuckets);
    k_scan_tile<<<ntiles, BT, 0, stream>>>(hist, bs, L);
    k_transp<<<vtiles * btiles, BT, 0, stream>>>(hist, bs, histT, bstart, nbuckets, ntiles, E);
    k_scatter<<<NCH, BT, 0, stream>>>(ei, histT, buf, E, chunk, nbuckets);
    k_bucket<<<nbuckets, BT, 0, stream>>>(buf, bstart, csr, rs, lab0, lab1, N, E, nbuckets);
    k_prop<<<pgrid, BT, 0, stream>>>(csr, rs, lab1, lab2, N, E);
    k_prop_final<<<pgrid, BT, 0, stream>>>(csr, rs, lab2, lab0, lab1, out, N, E, pgrid);
}

// Round 6
// 203.914 us; speedup vs baseline: 1.2805x; 1.0254x over previous
//
#include <hip/hip_runtime.h>
#include <hip/hip_bf16.h>

// WeisfeilerLehman: labels0 = argmax(x, -1); 3x ordered polynomial hash over edges.
// All arithmetic mod 2^32 (uint32 wrap) == reference int64 truncated to int32.
// R17: first prop fused into k_bucket; scan_sums+bstart folded into k_transp;
//      scatter caches pass-A match masks. Launches 9 -> 7.
// R18: latency-chain round. (a) horner reassociated 4-wide (h*H4+l0*H3+l1*H2+
//      l2*H+l3): the 4 csr loads and then the 4 lin gathers issue independently,
//      cutting dependent round-trips per row ~8 -> ~2 (applies to k_prop,
//      k_prop_final, and the fused prop in k_bucket). (b) k_bucket prefetches
//      the whole bucket slice into regs (d_[20], scatter-style): pass A overlaps
//      loads with ballots, pass B does zero buf reads (-12.8 MB L2 traffic).
//      VGPR ~88->~112 stays inside the 2-blocks/CU quantum -- free.

#define WL_D 128
#define NCH 512             // MSD chunk count (scatter grid)
#define GRID_F 2048         // fused hist/argmax grid
#define BT 512              // threads per block (8 waves)
#define MSDW 8
#define BBITS 8             // bucket = row >> 8
#define BROWS 256           // rows per bucket
#define NBK 512             // max buckets (N <= 131072)
#define RLSHIFT 23          // buf pack: (rl << 23) | col   (col < 2^23)
#define COLMASK ((1u << RLSHIFT) - 1u)
#define CMAX 10240          // LDS-staged output cap (40 KB)
#define NBMAX 13            // unrolled batches per wave in k_scatter (chunk 6250)
#define KBMAX 20            // unrolled batches per wave in k_bucket (len <= CMAX)
#define HP8 2487512833u     // 31^8 mod 2^32

// mask of lanes whose low BITS bits of v match mine (inactive lanes use a
// sentinel outside the valid key range so they never match active lanes)
template <int BITS>
__device__ inline unsigned long long match_key(unsigned v) {
    unsigned long long m = ~0ull;
    #pragma unroll
    for (int b = 0; b < BITS; ++b) {
        unsigned long long s = __ballot((v >> b) & 1u);
        m &= ((v >> b) & 1u) ? s : ~s;
    }
    return m;
}

// ---- fused: chunk bucket-histogram (blocks < NCH) + argmax ----
__global__ void __launch_bounds__(BT)
k_hist_argmax(const float* __restrict__ x, const int* __restrict__ ei,
              unsigned* __restrict__ lab0, unsigned* __restrict__ hist,
              int N, int E, int chunk, int nbuckets) {
    __shared__ unsigned h[NBK];
    int b = blockIdx.x, t = threadIdx.x, lane = t & 63, w = t >> 6;
    if (b < NCH) {                      // uniform per-block condition: syncs are safe
        for (int i = t; i < nbuckets; i += BT) h[i] = 0u;
        __syncthreads();
        int base = b * chunk, lim = min(base + chunk, E);
        for (int e = base + t; e < lim; e += BT)
            atomicAdd(&h[((unsigned)ei[e]) >> BBITS], 1u);
        __syncthreads();
        for (int v = t; v < nbuckets; v += BT) hist[(size_t)v * NCH + b] = h[v];
    }
    // argmax: 2 rows per wave (float4; lanes 0-31 row 2pr, lanes 32-63 row 2pr+1)
    int half = lane >> 5, li = lane & 31;
    for (int pr = b * MSDW + w; 2 * pr < N; pr += GRID_F * MSDW) {
        int r = 2 * pr + half;
        float bv = -3.4e38f; int bi = 0;
        if (r < N) {
            float4 v = ((const float4*)(x + (size_t)r * WL_D))[li];
            bv = v.x; bi = 4 * li;
            if (v.y > bv) { bv = v.y; bi = 4 * li + 1; }
            if (v.z > bv) { bv = v.z; bi = 4 * li + 2; }
            if (v.w > bv) { bv = v.w; bi = 4 * li + 3; }
        }
        #pragma unroll
        for (int off = 16; off > 0; off >>= 1) {
            float ov = __shfl_down(bv, off, 32);
            int   oi = __shfl_down(bi, off, 32);
            if (ov > bv || (ov == bv && oi < bi)) { bv = ov; bi = oi; }
        }
        if (li == 0 && r < N) lab0[r] = (unsigned)bi;
    }
}

// ---- scan: tile (1024 elems / block, 2 per thread) + raw tile totals ----
__global__ void __launch_bounds__(BT)
k_scan_tile(unsigned* __restrict__ hist, unsigned* __restrict__ bsums, int L) {
    __shared__ unsigned smem[BT];
    int b = blockIdx.x, t = threadIdx.x;
    int i0 = b * 1024;
    unsigned v0 = (i0 + 2 * t     < L) ? hist[i0 + 2 * t]     : 0u;
    unsigned v1 = (i0 + 2 * t + 1 < L) ? hist[i0 + 2 * t + 1] : 0u;
    unsigned s = v0 + v1;
    smem[t] = s;
    __syncthreads();
    for (int o = 1; o < BT; o <<= 1) {
        unsigned u = (t >= o) ? smem[t - o] : 0u;
        __syncthreads();
        smem[t] += u;
        __syncthreads();
    }
    unsigned excl = smem[t] - s;
    if (i0 + 2 * t     < L) hist[i0 + 2 * t]     = excl;
    if (i0 + 2 * t + 1 < L) hist[i0 + 2 * t + 1] = excl + v0;
    if (t == BT - 1) bsums[b] = smem[BT - 1];
}

// ---- transpose scanned hist (+bsums scanned in-block) -> histT[b][v]; emit bstart ----
__global__ void __launch_bounds__(BT)
k_transp(const unsigned* __restrict__ hist, const unsigned* __restrict__ bsums,
         unsigned* __restrict__ histT, unsigned* __restrict__ bstart,
         int nbuckets, int ntiles, int E) {
    __shared__ unsigned tl[64][65];
    __shared__ unsigned sb[BT];
    int t = threadIdx.x;
    // replicated exclusive scan of bsums (ntiles <= 512)
    unsigned my = (t < ntiles) ? bsums[t] : 0u;
    sb[t] = my;
    __syncthreads();
    for (int o = 1; o < BT; o <<= 1) {
        unsigned u = (t >= o) ? sb[t - o] : 0u;
        __syncthreads();
        sb[t] += u;
        __syncthreads();
    }
    sb[t] -= my;                         // inclusive -> exclusive
    __syncthreads();
    int vtiles = (nbuckets + 63) / 64;
    int bx = blockIdx.x % vtiles;        // v-tile
    int by = blockIdx.x / vtiles;        // b-tile
    int tx = t & 63, ty = t >> 6;        // 64 x 8
    int vb = bx * 64, b0 = by * 64;
    #pragma unroll
    for (int r = 0; r < 8; ++r) {
        int row = r * 8 + ty;
        int v = vb + row;
        size_t idx = (size_t)v * NCH + (b0 + tx);
        tl[row][tx] = (v < nbuckets) ? (hist[idx] + sb[idx >> 10]) : 0u;
    }
    __syncthreads();
    #pragma unroll
    for (int r = 0; r < 8; ++r) {
        int row = r * 8 + ty;            // b-offset within tile
        int v = vb + tx;
        if (v < nbuckets) histT[(size_t)(b0 + row) * nbuckets + v] = tl[tx][row];
    }
    // bucket starts = chunk-0 column of the scanned hist
    if (by == 0 && t < 64) {
        int v = vb + t;
        if (v < nbuckets) bstart[v] = tl[t][0];
    }
    if (blockIdx.x == 0 && t == 64) bstart[nbuckets] = (unsigned)E;
}

// ---- stable MSD scatter: prefetched batches + cached masks, LDS cursors ----
__global__ void __launch_bounds__(BT)
k_scatter(const int* __restrict__ ei, const unsigned* __restrict__ histT,
          unsigned* __restrict__ buf, int E, int chunk, int nbuckets) {
    __shared__ unsigned wbase[MSDW * NBK];   // 16 KB
    int b = blockIdx.x, t = threadIdx.x, lane = t & 63, w = t >> 6;
    unsigned long long lmask = (1ull << lane) - 1ull;
    for (int i = t; i < MSDW * NBK; i += BT) wbase[i] = 0u;
    __syncthreads();
    int base = b * chunk, lim = min(base + chunk, E);
    int sub  = (chunk + MSDW - 1) / MSDW;
    int wbeg = base + w * sub;
    int wend = min(wbeg + sub, lim);
    int nbat = (wbeg < wend) ? ((wend - wbeg + 63) >> 6) : 0;
    // prefetch all row loads (static reg indices; issued before any ballot chain)
    unsigned r_[NBMAX];
    #pragma unroll
    for (int k = 0; k < NBMAX; ++k) {
        int e = wbeg + k * 64 + lane;
        r_[k] = (e < wend) ? (unsigned)ei[e] : 0u;
    }
    // pass A: per-wave bucket counts; cache the match masks
    unsigned long long m_[NBMAX];
    #pragma unroll
    for (int k = 0; k < NBMAX; ++k) {
        if (k >= nbat) break;
        int e = wbeg + k * 64 + lane;
        bool act = (e < wend);
        unsigned v = act ? (r_[k] >> BBITS) : (NBK - 1u);
        unsigned long long m = match_key<9>(v);
        m_[k] = m;
        unsigned before = (unsigned)__popcll(m & lmask);
        if (act && before == 0u) wbase[w * NBK + v] += (unsigned)__popcll(m);
    }
    for (int k = NBMAX; k < nbat; ++k) {     // dynamic tail (robustness)
        int e = wbeg + k * 64 + lane;
        bool act = (e < wend);
        unsigned v = act ? (((unsigned)ei[e]) >> BBITS) : (NBK - 1u);
        unsigned long long m = match_key<9>(v);
        unsigned before = (unsigned)__popcll(m & lmask);
        if (act && before == 0u) wbase[w * NBK + v] += (unsigned)__popcll(m);
    }
    __syncthreads();
    // seed per-wave cursors from transposed bases (coalesced)
    for (int v = t; v < nbuckets; v += BT) {
        unsigned g = histT[(size_t)b * nbuckets + v];
        #pragma unroll
        for (int w2 = 0; w2 < MSDW; ++w2) {
            unsigned cnt = wbase[w2 * NBK + v];
            wbase[w2 * NBK + v] = g;
            g += cnt;
        }
    }
    __syncthreads();
    // pass B: prefetch cols (rows still live in r_), reuse masks, stable scatter
    unsigned c_[NBMAX];
    #pragma unroll
    for (int k = 0; k < NBMAX; ++k) {
        int e = wbeg + k * 64 + lane;
        c_[k] = (e < wend) ? (unsigned)ei[(size_t)E + e] : 0u;
    }
    #pragma unroll
    for (int k = 0; k < NBMAX; ++k) {
        if (k >= nbat) break;
        int e = wbeg + k * 64 + lane;
        bool act = (e < wend);
        unsigned r = r_[k], col = c_[k];
        unsigned v = r >> BBITS;                 // used only when act
        unsigned long long m = m_[k];
        unsigned before = (unsigned)__popcll(m & lmask);
        int leader = __ffsll(m) - 1;
        unsigned base0 = 0;
        if (act && before == 0u) {
            base0 = wbase[w * NBK + v];
            wbase[w * NBK + v] = base0 + (unsigned)__popcll(m);
        }
        base0 = __shfl(base0, leader, 64);
        if (act) buf[base0 + before] = ((r & (BROWS - 1u)) << RLSHIFT) | col;
    }
    for (int k = NBMAX; k < nbat; ++k) {     // dynamic tail
        int e = wbeg + k * 64 + lane;
        bool act = (e < wend);
        unsigned r   = act ? (unsigned)ei[e] : 0u;
        unsigned col = act ? (unsigned)ei[(size_t)E + e] : 0u;
        unsigned v = act ? (r >> BBITS) : (NBK - 1u);
        unsigned long long m = match_key<9>(v);
        unsigned before = (unsigned)__popcll(m & lmask);
        unsigned total  = (unsigned)__popcll(m);
        int leader = __ffsll(m) - 1;
        unsigned base0 = 0;
        if (act && before == 0u) { base0 = wbase[w * NBK + v]; wbase[w * NBK + v] = base0 + total; }
        base0 = __shfl(base0, leader, 64);
        if (act) buf[base0 + before] = ((r & (BROWS - 1u)) << RLSHIFT) | col;
    }
}

// ---- per-bucket stable counting sort by rl (reg-prefetched, LDS-staged out)
//      + FUSED first prop ----
__global__ void __launch_bounds__(BT)
k_bucket(const unsigned* __restrict__ buf, const unsigned* __restrict__ bstart,
         unsigned* __restrict__ csr, unsigned* __restrict__ rs_g,
         const unsigned* __restrict__ lab0, unsigned* __restrict__ lab1,
         int N, int E, int nbuckets) {
    __shared__ unsigned data2[CMAX];          // 40 KB (sorted output staging)
    __shared__ unsigned h2[MSDW * BROWS];     // 8 KB
    __shared__ unsigned offs[BROWS];          // 1 KB
    int bb = blockIdx.x, t = threadIdx.x, lane = t & 63, w = t >> 6;
    unsigned long long lmask = (1ull << lane) - 1ull;
    unsigned start = bstart[bb];
    unsigned end   = bstart[bb + 1];
    unsigned len = end - start;
    bool lds_ok = (len <= CMAX);
    for (int i = t; i < MSDW * BROWS; i += BT) h2[i] = 0u;
    __syncthreads();
    unsigned sub  = (len + MSDW - 1u) / MSDW;
    unsigned wbeg = w * sub;
    unsigned wend = min(wbeg + sub, len);
    int nbat = (wbeg < wend) ? (int)((wend - wbeg + 63u) >> 6) : 0;
    // prefetch the wave's whole slice into regs (i >= wend iff k >= nbat covers OOB)
    unsigned d_[KBMAX];
    #pragma unroll
    for (int k = 0; k < KBMAX; ++k) {
        unsigned i = wbeg + (unsigned)(k * 64 + lane);
        d_[k] = (i < wend) ? buf[start + i] : 0u;
    }
    // pass A: per-wave rl counts (ballots overlap the prefetch)
    #pragma unroll
    for (int k = 0; k < KBMAX; ++k) {
        if (k >= nbat) break;
        unsigned i = wbeg + (unsigned)(k * 64 + lane);
        bool act = (i < wend);
        unsigned v = act ? (d_[k] >> RLSHIFT) : 511u;
        unsigned long long m = match_key<9>(v);
        unsigned before = (unsigned)__popcll(m & lmask);
        unsigned total  = (unsigned)__popcll(m);
        if (act && before == 0u) h2[w * BROWS + v] += total;
    }
    for (int k = KBMAX; k < nbat; ++k) {     // dynamic tail (giant-bucket fallback)
        unsigned i = wbeg + (unsigned)(k * 64 + lane);
        bool act = (i < wend);
        unsigned v = act ? (buf[start + i] >> RLSHIFT) : 511u;
        unsigned long long m = match_key<9>(v);
        unsigned before = (unsigned)__popcll(m & lmask);
        unsigned total  = (unsigned)__popcll(m);
        if (act && before == 0u) h2[w * BROWS + v] += total;
    }
    __syncthreads();
    // exclusive scan over rl (256 entries, threads t < BROWS); emit rs; seed cursors
    unsigned hv = 0;
    if (t < BROWS) {
        #pragma unroll
        for (int w2 = 0; w2 < MSDW; ++w2) hv += h2[w2 * BROWS + t];
        offs[t] = hv;
    }
    __syncthreads();
    for (int o = 1; o < BROWS; o <<= 1) {
        unsigned s = (t < BROWS && t >= o) ? offs[t - o] : 0u;
        __syncthreads();
        if (t < BROWS) offs[t] += s;
        __syncthreads();
    }
    if (t < BROWS) {
        unsigned excl = offs[t] - hv;
        int row = bb * BROWS + t;
        if (row < N) rs_g[row] = start + excl;
        unsigned g = lds_ok ? excl : (start + excl);   // bucket-relative if LDS-staged
        #pragma unroll
        for (int w2 = 0; w2 < MSDW; ++w2) {
            unsigned cnt = h2[w2 * BROWS + t];
            h2[w2 * BROWS + t] = g;
            g += cnt;
        }
    }
    __syncthreads();
    // pass B: stable scatter cols (from regs) into LDS staging / csr fallback
    #pragma unroll
    for (int k = 0; k < KBMAX; ++k) {
        if (k >= nbat) break;
        unsigned i = wbeg + (unsigned)(k * 64 + lane);
        bool act = (i < wend);
        unsigned p = d_[k];
        unsigned v = act ? (p >> RLSHIFT) : 511u;
        unsigned long long m = match_key<9>(v);
        unsigned before = (unsigned)__popcll(m & lmask);
        unsigned total  = (unsigned)__popcll(m);
        int leader = __ffsll(m) - 1;
        unsigned base0 = 0;
        if (act && before == 0u) { base0 = h2[w * BROWS + v]; h2[w * BROWS + v] = base0 + total; }
        base0 = __shfl(base0, leader, 64);
        if (act) {
            if (lds_ok) data2[base0 + before] = p & COLMASK;
            else        csr[base0 + before]   = p & COLMASK;
        }
    }
    for (int k = KBMAX; k < nbat; ++k) {     // dynamic tail
        unsigned i = wbeg + (unsigned)(k * 64 + lane);
        bool act = (i < wend);
        unsigned p = act ? buf[start + i] : 0u;
        unsigned v = act ? (p >> RLSHIFT) : 511u;
        unsigned long long m = match_key<9>(v);
        unsigned before = (unsigned)__popcll(m & lmask);
        unsigned total  = (unsigned)__popcll(m);
        int leader = __ffsll(m) - 1;
        unsigned base0 = 0;
        if (act && before == 0u) { base0 = h2[w * BROWS + v]; h2[w * BROWS + v] = base0 + total; }
        base0 = __shfl(base0, leader, 64);
        if (act) {
            if (lds_ok) data2[base0 + before] = p & COLMASK;
            else        csr[base0 + before]   = p & COLMASK;
        }
    }
    __syncthreads();
    // FUSED first prop: lab1 for this bucket's rows, 8 lanes/row, cols from LDS.
    // 4-wide reassociated Horner: independent col loads, then independent gathers.
    const unsigned H1 = HP8, H2 = HP8 * HP8, H3 = H2 * HP8, H4 = H3 * HP8;
    const unsigned* srcp = lds_ok ? (const unsigned*)data2 : (csr + start);
    int l = t & 7;
    for (int r0 = t >> 3; r0 < BROWS; r0 += BT / 8) {
        unsigned beg = r0 ? offs[r0 - 1] : 0u;
        unsigned d   = offs[r0] - beg;
        unsigned h = 0u;
        unsigned M = (d > (unsigned)l) ? ((d - (unsigned)l + 7u) >> 3) : 0u;
        unsigned bidx = beg + (unsigned)l;
        unsigned m = 0;
        for (; m + 4u <= M; m += 4u) {
            unsigned c0 = srcp[bidx + 8u * m];
            unsigned c1 = srcp[bidx + 8u * m + 8u];
            unsigned c2 = srcp[bidx + 8u * m + 16u];
            unsigned c3 = srcp[bidx + 8u * m + 24u];
            unsigned l0 = lab0[c0], l1 = lab0[c1], l2 = lab0[c2], l3 = lab0[c3];
            h = h * H4 + l0 * H3 + l1 * H2 + l2 * H1 + l3;
        }
        for (; m < M; ++m) h = h * H1 + lab0[srcp[bidx + 8u * m]];
        if (M) {
            unsigned T = d - 1u - (unsigned)l - 8u * (M - 1u);   // in [0,7]
            unsigned p = ((T & 1u) ? 31u : 1u) * ((T & 2u) ? 961u : 1u)
                       * ((T & 4u) ? 923521u : 1u);
            h *= p;
        }
        h += __shfl_xor(h, 1, 64);
        h += __shfl_xor(h, 2, 64);
        h += __shfl_xor(h, 4, 64);
        int row = bb * BROWS + r0;
        if (l == 0 && row < N) lab1[row] = h;
    }
    // stream sorted bucket out contiguously (1x write amplification)
    if (lds_ok) for (unsigned i = t; i < len; i += BT) csr[start + i] = data2[i];
}

// ---- prop: 8 lanes per row, 4-wide reassociated base-31^8 Horner ----
__device__ inline unsigned horner8(const unsigned* __restrict__ csr,
                                   const unsigned* __restrict__ rs,
                                   const unsigned* __restrict__ lin,
                                   int g, int l, int N, int E) {
    const unsigned H1 = HP8, H2 = HP8 * HP8, H3 = H2 * HP8, H4 = H3 * HP8;
    unsigned s = rs[g];
    unsigned e = (g + 1 < N) ? rs[g + 1] : (unsigned)E;
    unsigned d = e - s;
    unsigned h = 0u;
    unsigned M = (d > (unsigned)l) ? ((d - (unsigned)l + 7u) >> 3) : 0u;
    unsigned bidx = s + (unsigned)l;
    unsigned m = 0;
    for (; m + 4u <= M; m += 4u) {
        unsigned c0 = csr[bidx + 8u * m];
        unsigned c1 = csr[bidx + 8u * m + 8u];
        unsigned c2 = csr[bidx + 8u * m + 16u];
        unsigned c3 = csr[bidx + 8u * m + 24u];
        unsigned l0 = lin[c0], l1 = lin[c1], l2 = lin[c2], l3 = lin[c3];
        h = h * H4 + l0 * H3 + l1 * H2 + l2 * H1 + l3;
    }
    for (; m < M; ++m) h = h * H1 + lin[csr[bidx + 8u * m]];
    if (M) {
        unsigned T = d - 1u - (unsigned)l - 8u * (M - 1u);   // in [0,7]
        unsigned p = ((T & 1u) ? 31u : 1u) * ((T & 2u) ? 961u : 1u)
                   * ((T & 4u) ? 923521u : 1u);
        h *= p;
    }
    h += __shfl_xor(h, 1, 64);
    h += __shfl_xor(h, 2, 64);
    h += __shfl_xor(h, 4, 64);
    return h;
}

__global__ void __launch_bounds__(BT)
k_prop(const unsigned* __restrict__ csr, const unsigned* __restrict__ rs,
       const unsigned* __restrict__ lin, unsigned* __restrict__ lout,
       int N, int E) {
    int idx = blockIdx.x * BT + threadIdx.x;
    int g = idx >> 3, l = idx & 7;
    if (g >= N) return;
    unsigned h = horner8(csr, rs, lin, g, l, N, E);
    if (l == 0) lout[g] = h;
}

// final prop: writes lab3 straight into out[0..N) and out[4N..5N), plus copies
// lab0..2 into out[N..4N)
__global__ void __launch_bounds__(BT)
k_prop_final(const unsigned* __restrict__ csr, const unsigned* __restrict__ rs,
             const unsigned* __restrict__ lin, const unsigned* __restrict__ l0,
             const unsigned* __restrict__ l1, int* __restrict__ out,
             int N, int E, int pgrid) {
    int idx = blockIdx.x * BT + threadIdx.x;
    int g = idx >> 3, l = idx & 7;
    if (g < N) {
        unsigned h = horner8(csr, rs, lin, g, l, N, E);
        if (l == 0) { out[g] = (int)h; out[4 * N + g] = (int)h; }
    }
    for (int i = idx; i < N; i += pgrid * BT) {
        out[N + i]     = (int)l0[i];
        out[2 * N + i] = (int)l1[i];
        out[3 * N + i] = (int)lin[i];    // lin == lab2 on the final pass
    }
}

extern "C" void kernel_launch(void* const* d_in, const int* in_sizes, int n_in,
                              void* d_out, int out_size, void* d_ws, size_t ws_size,
                              hipStream_t stream) {
    const float* x  = (const float*)d_in[0];
    const int*   ei = (const int*)d_in[1];
    int* out = (int*)d_out;

    int N = in_sizes[0] / WL_D;
    int E = in_sizes[1] / 2;
    int chunk    = (E + NCH - 1) / NCH;        // 6250
    int nbuckets = (N + BROWS - 1) / BROWS;    // 391
    int L        = nbuckets * NCH;             // 200,192
    int ntiles   = (L + 1023) / 1024;          // 196 (<= 512: in-block scan ok)
    int vtiles   = (nbuckets + 63) / 64;       // 7
    int btiles   = NCH / 64;                   // 8
    int pgrid    = (8 * N + BT - 1) / BT;      // 1563 (8 lanes per row)

    // workspace layout (uint32 units) — everything written before read
    unsigned* ws    = (unsigned*)d_ws;
    unsigned* lab0  = ws;               // N
    unsigned* lab1  = lab0 + N;         // N
    unsigned* lab2  = lab1 + N;         // N
    unsigned* rs    = lab2 + N;         // N
    unsigned* bs    = rs + N;           // 1024
    unsigned* bstart= bs + 1024;        // 1024 (nbuckets+1 used)
    unsigned* hist  = bstart + 1024;    // L
    unsigned* buf   = hist + L;         // E
    unsigned* csr   = buf + E;          // E
    unsigned* histT = csr;              // transient: csr space is free until k_bucket

    k_hist_argmax<<<GRID_F, BT, 0, stream>>>(x, ei, lab0, hist, N, E, chunk, nbuckets);
    k_scan_tile<<<ntiles, BT, 0, stream>>>(hist, bs, L);
    k_transp<<<vtiles * btiles, BT, 0, stream>>>(hist, bs, histT, bstart, nbuckets, ntiles, E);
    k_scatter<<<NCH, BT, 0, stream>>>(ei, histT, buf, E, chunk, nbuckets);
    k_bucket<<<nbuckets, BT, 0, stream>>>(buf, bstart, csr, rs, lab0, lab1, N, E, nbuckets);
    k_prop<<<pgrid, BT, 0, stream>>>(csr, rs, lab1, lab2, N, E);
    k_prop_final<<<pgrid, BT, 0, stream>>>(csr, rs, lab2, lab0, lab1, out, N, E, pgrid);
}

// Round 7
// 201.942 us; speedup vs baseline: 1.2930x; 1.0098x over previous
//
#include <hip/hip_runtime.h>
#include <hip/hip_bf16.h>

// WeisfeilerLehman: labels0 = argmax(x, -1); 3x ordered polynomial hash over edges.
// All arithmetic mod 2^32 (uint32 wrap) == reference int64 truncated to int32.
// R18: 4-wide reassociated Horner; k_bucket reg-prefetch (pass B reads regs).
// R19: write-locality round. (a) XCD-chunked swizzle chunk=(bid%8)*64+bid/8 in
//      k_hist_argmax + k_scatter: each XCD owns 64 CONSECUTIVE chunks, so its
//      per-bucket writes form contiguous ~4KB spans and the per-XCD dirty set
//      is 1.6MB < 4MB L2 -> scatter's ~4.5x partial-line write amp (58MB for
//      12.8MB useful, R2 counters) collapses to ~1x. Same for hist's strided
//      4B stores. Logical chunk order unchanged -> stability preserved.
//      (b) k_bucket: csr write-back issued BEFORE the fused prop so the 32KB
//      stream drains under the prop's gathers.

#define WL_D 128
#define NCH 512             // MSD chunk count (scatter grid)
#define GRID_F 2048         // fused hist/argmax grid
#define BT 512              // threads per block (8 waves)
#define MSDW 8
#define BBITS 8             // bucket = row >> 8
#define BROWS 256           // rows per bucket
#define NBK 512             // max buckets (N <= 131072)
#define RLSHIFT 23          // buf pack: (rl << 23) | col   (col < 2^23)
#define COLMASK ((1u << RLSHIFT) - 1u)
#define CMAX 10240          // LDS-staged output cap (40 KB)
#define NBMAX 13            // unrolled batches per wave in k_scatter (chunk 6250)
#define KBMAX 20            // unrolled batches per wave in k_bucket (len <= CMAX)
#define HP8 2487512833u     // 31^8 mod 2^32

// XCD-chunked chunk assignment: blockIdx -> chunk such that each XCD (bid % 8
// under round-robin dispatch) owns NCH/8 consecutive chunks. Bijective on [0,NCH).
__device__ inline int xcd_chunk(int bid) { return ((bid & 7) << 6) | (bid >> 3); }

// mask of lanes whose low BITS bits of v match mine (inactive lanes use a
// sentinel outside the valid key range so they never match active lanes)
template <int BITS>
__device__ inline unsigned long long match_key(unsigned v) {
    unsigned long long m = ~0ull;
    #pragma unroll
    for (int b = 0; b < BITS; ++b) {
        unsigned long long s = __ballot((v >> b) & 1u);
        m &= ((v >> b) & 1u) ? s : ~s;
    }
    return m;
}

// ---- fused: chunk bucket-histogram (blocks < NCH) + argmax ----
__global__ void __launch_bounds__(BT)
k_hist_argmax(const float* __restrict__ x, const int* __restrict__ ei,
              unsigned* __restrict__ lab0, unsigned* __restrict__ hist,
              int N, int E, int chunk, int nbuckets) {
    __shared__ unsigned h[NBK];
    int bid = blockIdx.x, t = threadIdx.x, lane = t & 63, w = t >> 6;
    if (bid < NCH) {                    // uniform per-block condition: syncs are safe
        int b = xcd_chunk(bid);         // swizzled chunk id (bijective on [0,NCH))
        for (int i = t; i < nbuckets; i += BT) h[i] = 0u;
        __syncthreads();
        int base = b * chunk, lim = min(base + chunk, E);
        for (int e = base + t; e < lim; e += BT)
            atomicAdd(&h[((unsigned)ei[e]) >> BBITS], 1u);
        __syncthreads();
        for (int v = t; v < nbuckets; v += BT) hist[(size_t)v * NCH + b] = h[v];
    }
    // argmax: 2 rows per wave (float4; lanes 0-31 row 2pr, lanes 32-63 row 2pr+1)
    int half = lane >> 5, li = lane & 31;
    for (int pr = bid * MSDW + w; 2 * pr < N; pr += GRID_F * MSDW) {
        int r = 2 * pr + half;
        float bv = -3.4e38f; int bi = 0;
        if (r < N) {
            float4 v = ((const float4*)(x + (size_t)r * WL_D))[li];
            bv = v.x; bi = 4 * li;
            if (v.y > bv) { bv = v.y; bi = 4 * li + 1; }
            if (v.z > bv) { bv = v.z; bi = 4 * li + 2; }
            if (v.w > bv) { bv = v.w; bi = 4 * li + 3; }
        }
        #pragma unroll
        for (int off = 16; off > 0; off >>= 1) {
            float ov = __shfl_down(bv, off, 32);
            int   oi = __shfl_down(bi, off, 32);
            if (ov > bv || (ov == bv && oi < bi)) { bv = ov; bi = oi; }
        }
        if (li == 0 && r < N) lab0[r] = (unsigned)bi;
    }
}

// ---- scan: tile (1024 elems / block, 2 per thread) + raw tile totals ----
__global__ void __launch_bounds__(BT)
k_scan_tile(unsigned* __restrict__ hist, unsigned* __restrict__ bsums, int L) {
    __shared__ unsigned smem[BT];
    int b = blockIdx.x, t = threadIdx.x;
    int i0 = b * 1024;
    unsigned v0 = (i0 + 2 * t     < L) ? hist[i0 + 2 * t]     : 0u;
    unsigned v1 = (i0 + 2 * t + 1 < L) ? hist[i0 + 2 * t + 1] : 0u;
    unsigned s = v0 + v1;
    smem[t] = s;
    __syncthreads();
    for (int o = 1; o < BT; o <<= 1) {
        unsigned u = (t >= o) ? smem[t - o] : 0u;
        __syncthreads();
        smem[t] += u;
        __syncthreads();
    }
    unsigned excl = smem[t] - s;
    if (i0 + 2 * t     < L) hist[i0 + 2 * t]     = excl;
    if (i0 + 2 * t + 1 < L) hist[i0 + 2 * t + 1] = excl + v0;
    if (t == BT - 1) bsums[b] = smem[BT - 1];
}

// ---- transpose scanned hist (+bsums scanned in-block) -> histT[b][v]; emit bstart ----
__global__ void __launch_bounds__(BT)
k_transp(const unsigned* __restrict__ hist, const unsigned* __restrict__ bsums,
         unsigned* __restrict__ histT, unsigned* __restrict__ bstart,
         int nbuckets, int ntiles, int E) {
    __shared__ unsigned tl[64][65];
    __shared__ unsigned sb[BT];
    int t = threadIdx.x;
    // replicated exclusive scan of bsums (ntiles <= 512)
    unsigned my = (t < ntiles) ? bsums[t] : 0u;
    sb[t] = my;
    __syncthreads();
    for (int o = 1; o < BT; o <<= 1) {
        unsigned u = (t >= o) ? sb[t - o] : 0u;
        __syncthreads();
        sb[t] += u;
        __syncthreads();
    }
    sb[t] -= my;                         // inclusive -> exclusive
    __syncthreads();
    int vtiles = (nbuckets + 63) / 64;
    int bx = blockIdx.x % vtiles;        // v-tile
    int by = blockIdx.x / vtiles;        // b-tile
    int tx = t & 63, ty = t >> 6;        // 64 x 8
    int vb = bx * 64, b0 = by * 64;
    #pragma unroll
    for (int r = 0; r < 8; ++r) {
        int row = r * 8 + ty;
        int v = vb + row;
        size_t idx = (size_t)v * NCH + (b0 + tx);
        tl[row][tx] = (v < nbuckets) ? (hist[idx] + sb[idx >> 10]) : 0u;
    }
    __syncthreads();
    #pragma unroll
    for (int r = 0; r < 8; ++r) {
        int row = r * 8 + ty;            // b-offset within tile
        int v = vb + tx;
        if (v < nbuckets) histT[(size_t)(b0 + row) * nbuckets + v] = tl[tx][row];
    }
    // bucket starts = chunk-0 column of the scanned hist
    if (by == 0 && t < 64) {
        int v = vb + t;
        if (v < nbuckets) bstart[v] = tl[t][0];
    }
    if (blockIdx.x == 0 && t == 64) bstart[nbuckets] = (unsigned)E;
}

// ---- stable MSD scatter: prefetched batches + cached masks, LDS cursors ----
__global__ void __launch_bounds__(BT)
k_scatter(const int* __restrict__ ei, const unsigned* __restrict__ histT,
          unsigned* __restrict__ buf, int E, int chunk, int nbuckets) {
    __shared__ unsigned wbase[MSDW * NBK];   // 16 KB
    int b = xcd_chunk(blockIdx.x);           // swizzled chunk id
    int t = threadIdx.x, lane = t & 63, w = t >> 6;
    unsigned long long lmask = (1ull << lane) - 1ull;
    for (int i = t; i < MSDW * NBK; i += BT) wbase[i] = 0u;
    __syncthreads();
    int base = b * chunk, lim = min(base + chunk, E);
    int sub  = (chunk + MSDW - 1) / MSDW;
    int wbeg = base + w * sub;
    int wend = min(wbeg + sub, lim);
    int nbat = (wbeg < wend) ? ((wend - wbeg + 63) >> 6) : 0;
    // prefetch all row loads (static reg indices; issued before any ballot chain)
    unsigned r_[NBMAX];
    #pragma unroll
    for (int k = 0; k < NBMAX; ++k) {
        int e = wbeg + k * 64 + lane;
        r_[k] = (e < wend) ? (unsigned)ei[e] : 0u;
    }
    // pass A: per-wave bucket counts; cache the match masks
    unsigned long long m_[NBMAX];
    #pragma unroll
    for (int k = 0; k < NBMAX; ++k) {
        if (k >= nbat) break;
        int e = wbeg + k * 64 + lane;
        bool act = (e < wend);
        unsigned v = act ? (r_[k] >> BBITS) : (NBK - 1u);
        unsigned long long m = match_key<9>(v);
        m_[k] = m;
        unsigned before = (unsigned)__popcll(m & lmask);
        if (act && before == 0u) wbase[w * NBK + v] += (unsigned)__popcll(m);
    }
    for (int k = NBMAX; k < nbat; ++k) {     // dynamic tail (robustness)
        int e = wbeg + k * 64 + lane;
        bool act = (e < wend);
        unsigned v = act ? (((unsigned)ei[e]) >> BBITS) : (NBK - 1u);
        unsigned long long m = match_key<9>(v);
        unsigned before = (unsigned)__popcll(m & lmask);
        if (act && before == 0u) wbase[w * NBK + v] += (unsigned)__popcll(m);
    }
    __syncthreads();
    // seed per-wave cursors from transposed bases (coalesced)
    for (int v = t; v < nbuckets; v += BT) {
        unsigned g = histT[(size_t)b * nbuckets + v];
        #pragma unroll
        for (int w2 = 0; w2 < MSDW; ++w2) {
            unsigned cnt = wbase[w2 * NBK + v];
            wbase[w2 * NBK + v] = g;
            g += cnt;
        }
    }
    __syncthreads();
    // pass B: prefetch cols (rows still live in r_), reuse masks, stable scatter
    unsigned c_[NBMAX];
    #pragma unroll
    for (int k = 0; k < NBMAX; ++k) {
        int e = wbeg + k * 64 + lane;
        c_[k] = (e < wend) ? (unsigned)ei[(size_t)E + e] : 0u;
    }
    #pragma unroll
    for (int k = 0; k < NBMAX; ++k) {
        if (k >= nbat) break;
        int e = wbeg + k * 64 + lane;
        bool act = (e < wend);
        unsigned r = r_[k], col = c_[k];
        unsigned v = r >> BBITS;                 // used only when act
        unsigned long long m = m_[k];
        unsigned before = (unsigned)__popcll(m & lmask);
        int leader = __ffsll(m) - 1;
        unsigned base0 = 0;
        if (act && before == 0u) {
            base0 = wbase[w * NBK + v];
            wbase[w * NBK + v] = base0 + (unsigned)__popcll(m);
        }
        base0 = __shfl(base0, leader, 64);
        if (act) buf[base0 + before] = ((r & (BROWS - 1u)) << RLSHIFT) | col;
    }
    for (int k = NBMAX; k < nbat; ++k) {     // dynamic tail
        int e = wbeg + k * 64 + lane;
        bool act = (e < wend);
        unsigned r   = act ? (unsigned)ei[e] : 0u;
        unsigned col = act ? (unsigned)ei[(size_t)E + e] : 0u;
        unsigned v = act ? (r >> BBITS) : (NBK - 1u);
        unsigned long long m = match_key<9>(v);
        unsigned before = (unsigned)__popcll(m & lmask);
        unsigned total  = (unsigned)__popcll(m);
        int leader = __ffsll(m) - 1;
        unsigned base0 = 0;
        if (act && before == 0u) { base0 = wbase[w * NBK + v]; wbase[w * NBK + v] = base0 + total; }
        base0 = __shfl(base0, leader, 64);
        if (act) buf[base0 + before] = ((r & (BROWS - 1u)) << RLSHIFT) | col;
    }
}

// ---- per-bucket stable counting sort by rl (reg-prefetched, LDS-staged out)
//      + FUSED first prop ----
__global__ void __launch_bounds__(BT)
k_bucket(const unsigned* __restrict__ buf, const unsigned* __restrict__ bstart,
         unsigned* __restrict__ csr, unsigned* __restrict__ rs_g,
         const unsigned* __restrict__ lab0, unsigned* __restrict__ lab1,
         int N, int E, int nbuckets) {
    __shared__ unsigned data2[CMAX];          // 40 KB (sorted output staging)
    __shared__ unsigned h2[MSDW * BROWS];     // 8 KB
    __shared__ unsigned offs[BROWS];          // 1 KB
    int bb = blockIdx.x, t = threadIdx.x, lane = t & 63, w = t >> 6;
    unsigned long long lmask = (1ull << lane) - 1ull;
    unsigned start = bstart[bb];
    unsigned end   = bstart[bb + 1];
    unsigned len = end - start;
    bool lds_ok = (len <= CMAX);
    for (int i = t; i < MSDW * BROWS; i += BT) h2[i] = 0u;
    __syncthreads();
    unsigned sub  = (len + MSDW - 1u) / MSDW;
    unsigned wbeg = w * sub;
    unsigned wend = min(wbeg + sub, len);
    int nbat = (wbeg < wend) ? (int)((wend - wbeg + 63u) >> 6) : 0;
    // prefetch the wave's whole slice into regs (i >= wend iff k >= nbat covers OOB)
    unsigned d_[KBMAX];
    #pragma unroll
    for (int k = 0; k < KBMAX; ++k) {
        unsigned i = wbeg + (unsigned)(k * 64 + lane);
        d_[k] = (i < wend) ? buf[start + i] : 0u;
    }
    // pass A: per-wave rl counts (ballots overlap the prefetch)
    #pragma unroll
    for (int k = 0; k < KBMAX; ++k) {
        if (k >= nbat) break;
        unsigned i = wbeg + (unsigned)(k * 64 + lane);
        bool act = (i < wend);
        unsigned v = act ? (d_[k] >> RLSHIFT) : 511u;
        unsigned long long m = match_key<9>(v);
        unsigned before = (unsigned)__popcll(m & lmask);
        unsigned total  = (unsigned)__popcll(m);
        if (act && before == 0u) h2[w * BROWS + v] += total;
    }
    for (int k = KBMAX; k < nbat; ++k) {     // dynamic tail (giant-bucket fallback)
        unsigned i = wbeg + (unsigned)(k * 64 + lane);
        bool act = (i < wend);
        unsigned v = act ? (buf[start + i] >> RLSHIFT) : 511u;
        unsigned long long m = match_key<9>(v);
        unsigned before = (unsigned)__popcll(m & lmask);
        unsigned total  = (unsigned)__popcll(m);
        if (act && before == 0u) h2[w * BROWS + v] += total;
    }
    __syncthreads();
    // exclusive scan over rl (256 entries, threads t < BROWS); emit rs; seed cursors
    unsigned hv = 0;
    if (t < BROWS) {
        #pragma unroll
        for (int w2 = 0; w2 < MSDW; ++w2) hv += h2[w2 * BROWS + t];
        offs[t] = hv;
    }
    __syncthreads();
    for (int o = 1; o < BROWS; o <<= 1) {
        unsigned s = (t < BROWS && t >= o) ? offs[t - o] : 0u;
        __syncthreads();
        if (t < BROWS) offs[t] += s;
        __syncthreads();
    }
    if (t < BROWS) {
        unsigned excl = offs[t] - hv;
        int row = bb * BROWS + t;
        if (row < N) rs_g[row] = start + excl;
        unsigned g = lds_ok ? excl : (start + excl);   // bucket-relative if LDS-staged
        #pragma unroll
        for (int w2 = 0; w2 < MSDW; ++w2) {
            unsigned cnt = h2[w2 * BROWS + t];
            h2[w2 * BROWS + t] = g;
            g += cnt;
        }
    }
    __syncthreads();
    // pass B: stable scatter cols (from regs) into LDS staging / csr fallback
    #pragma unroll
    for (int k = 0; k < KBMAX; ++k) {
        if (k >= nbat) break;
        unsigned i = wbeg + (unsigned)(k * 64 + lane);
        bool act = (i < wend);
        unsigned p = d_[k];
        unsigned v = act ? (p >> RLSHIFT) : 511u;
        unsigned long long m = match_key<9>(v);
        unsigned before = (unsigned)__popcll(m & lmask);
        unsigned total  = (unsigned)__popcll(m);
        int leader = __ffsll(m) - 1;
        unsigned base0 = 0;
        if (act && before == 0u) { base0 = h2[w * BROWS + v]; h2[w * BROWS + v] = base0 + total; }
        base0 = __shfl(base0, leader, 64);
        if (act) {
            if (lds_ok) data2[base0 + before] = p & COLMASK;
            else        csr[base0 + before]   = p & COLMASK;
        }
    }
    for (int k = KBMAX; k < nbat; ++k) {     // dynamic tail
        unsigned i = wbeg + (unsigned)(k * 64 + lane);
        bool act = (i < wend);
        unsigned p = act ? buf[start + i] : 0u;
        unsigned v = act ? (p >> RLSHIFT) : 511u;
        unsigned long long m = match_key<9>(v);
        unsigned before = (unsigned)__popcll(m & lmask);
        unsigned total  = (unsigned)__popcll(m);
        int leader = __ffsll(m) - 1;
        unsigned base0 = 0;
        if (act && before == 0u) { base0 = h2[w * BROWS + v]; h2[w * BROWS + v] = base0 + total; }
        base0 = __shfl(base0, leader, 64);
        if (act) {
            if (lds_ok) data2[base0 + before] = p & COLMASK;
            else        csr[base0 + before]   = p & COLMASK;
        }
    }
    __syncthreads();
    // stream sorted bucket out FIRST: the 32KB of stores drain underneath the
    // fused prop's gather/compute phase (fire-and-forget until kernel end)
    if (lds_ok) for (unsigned i = t; i < len; i += BT) csr[start + i] = data2[i];
    // FUSED first prop: lab1 for this bucket's rows, 8 lanes/row, cols from LDS.
    // 4-wide reassociated Horner: independent col loads, then independent gathers.
    const unsigned H1 = HP8, H2 = HP8 * HP8, H3 = H2 * HP8, H4 = H3 * HP8;
    const unsigned* srcp = lds_ok ? (const unsigned*)data2 : (csr + start);
    int l = t & 7;
    for (int r0 = t >> 3; r0 < BROWS; r0 += BT / 8) {
        unsigned beg = r0 ? offs[r0 - 1] : 0u;
        unsigned d   = offs[r0] - beg;
        unsigned h = 0u;
        unsigned M = (d > (unsigned)l) ? ((d - (unsigned)l + 7u) >> 3) : 0u;
        unsigned bidx = beg + (unsigned)l;
        unsigned m = 0;
        for (; m + 4u <= M; m += 4u) {
            unsigned c0 = srcp[bidx + 8u * m];
            unsigned c1 = srcp[bidx + 8u * m + 8u];
            unsigned c2 = srcp[bidx + 8u * m + 16u];
            unsigned c3 = srcp[bidx + 8u * m + 24u];
            unsigned l0 = lab0[c0], l1 = lab0[c1], l2 = lab0[c2], l3 = lab0[c3];
            h = h * H4 + l0 * H3 + l1 * H2 + l2 * H1 + l3;
        }
        for (; m < M; ++m) h = h * H1 + lab0[srcp[bidx + 8u * m]];
        if (M) {
            unsigned T = d - 1u - (unsigned)l - 8u * (M - 1u);   // in [0,7]
            unsigned p = ((T & 1u) ? 31u : 1u) * ((T & 2u) ? 961u : 1u)
                       * ((T & 4u) ? 923521u : 1u);
            h *= p;
        }
        h += __shfl_xor(h, 1, 64);
        h += __shfl_xor(h, 2, 64);
        h += __shfl_xor(h, 4, 64);
        int row = bb * BROWS + r0;
        if (l == 0 && row < N) lab1[row] = h;
    }
}

// ---- prop: 8 lanes per row, 4-wide reassociated base-31^8 Horner ----
__device__ inline unsigned horner8(const unsigned* __restrict__ csr,
                                   const unsigned* __restrict__ rs,
                                   const unsigned* __restrict__ lin,
                                   int g, int l, int N, int E) {
    const unsigned H1 = HP8, H2 = HP8 * HP8, H3 = H2 * HP8, H4 = H3 * HP8;
    unsigned s = rs[g];
    unsigned e = (g + 1 < N) ? rs[g + 1] : (unsigned)E;
    unsigned d = e - s;
    unsigned h = 0u;
    unsigned M = (d > (unsigned)l) ? ((d - (unsigned)l + 7u) >> 3) : 0u;
    unsigned bidx = s + (unsigned)l;
    unsigned m = 0;
    for (; m + 4u <= M; m += 4u) {
        unsigned c0 = csr[bidx + 8u * m];
        unsigned c1 = csr[bidx + 8u * m + 8u];
        unsigned c2 = csr[bidx + 8u * m + 16u];
        unsigned c3 = csr[bidx + 8u * m + 24u];
        unsigned l0 = lin[c0], l1 = lin[c1], l2 = lin[c2], l3 = lin[c3];
        h = h * H4 + l0 * H3 + l1 * H2 + l2 * H1 + l3;
    }
    for (; m < M; ++m) h = h * H1 + lin[csr[bidx + 8u * m]];
    if (M) {
        unsigned T = d - 1u - (unsigned)l - 8u * (M - 1u);   // in [0,7]
        unsigned p = ((T & 1u) ? 31u : 1u) * ((T & 2u) ? 961u : 1u)
                   * ((T & 4u) ? 923521u : 1u);
        h *= p;
    }
    h += __shfl_xor(h, 1, 64);
    h += __shfl_xor(h, 2, 64);
    h += __shfl_xor(h, 4, 64);
    return h;
}

__global__ void __launch_bounds__(BT)
k_prop(const unsigned* __restrict__ csr, const unsigned* __restrict__ rs,
       const unsigned* __restrict__ lin, unsigned* __restrict__ lout,
       int N, int E) {
    int idx = blockIdx.x * BT + threadIdx.x;
    int g = idx >> 3, l = idx & 7;
    if (g >= N) return;
    unsigned h = horner8(csr, rs, lin, g, l, N, E);
    if (l == 0) lout[g] = h;
}

// final prop: writes lab3 straight into out[0..N) and out[4N..5N), plus copies
// lab0..2 into out[N..4N)
__global__ void __launch_bounds__(BT)
k_prop_final(const unsigned* __restrict__ csr, const unsigned* __restrict__ rs,
             const unsigned* __restrict__ lin, const unsigned* __restrict__ l0,
             const unsigned* __restrict__ l1, int* __restrict__ out,
             int N, int E, int pgrid) {
    int idx = blockIdx.x * BT + threadIdx.x;
    int g = idx >> 3, l = idx & 7;
    if (g < N) {
        unsigned h = horner8(csr, rs, lin, g, l, N, E);
        if (l == 0) { out[g] = (int)h; out[4 * N + g] = (int)h; }
    }
    for (int i = idx; i < N; i += pgrid * BT) {
        out[N + i]     = (int)l0[i];
        out[2 * N + i] = (int)l1[i];
        out[3 * N + i] = (int)lin[i];    // lin == lab2 on the final pass
    }
}

extern "C" void kernel_launch(void* const* d_in, const int* in_sizes, int n_in,
                              void* d_out, int out_size, void* d_ws, size_t ws_size,
                              hipStream_t stream) {
    const float* x  = (const float*)d_in[0];
    const int*   ei = (const int*)d_in[1];
    int* out = (int*)d_out;

    int N = in_sizes[0] / WL_D;
    int E = in_sizes[1] / 2;
    int chunk    = (E + NCH - 1) / NCH;        // 6250
    int nbuckets = (N + BROWS - 1) / BROWS;    // 391
    int L        = nbuckets * NCH;             // 200,192
    int ntiles   = (L + 1023) / 1024;          // 196 (<= 512: in-block scan ok)
    int vtiles   = (nbuckets + 63) / 64;       // 7
    int btiles   = NCH / 64;                   // 8
    int pgrid    = (8 * N + BT - 1) / BT;      // 1563 (8 lanes per row)

    // workspace layout (uint32 units) — everything written before read
    unsigned* ws    = (unsigned*)d_ws;
    unsigned* lab0  = ws;               // N
    unsigned* lab1  = lab0 + N;         // N
    unsigned* lab2  = lab1 + N;         // N
    unsigned* rs    = lab2 + N;         // N
    unsigned* bs    = rs + N;           // 1024
    unsigned* bstart= bs + 1024;        // 1024 (nbuckets+1 used)
    unsigned* hist  = bstart + 1024;    // L
    unsigned* buf   = hist + L;         // E
    unsigned* csr   = buf + E;          // E
    unsigned* histT = csr;              // transient: csr space is free until k_bucket

    k_hist_argmax<<<GRID_F, BT, 0, stream>>>(x, ei, lab0, hist, N, E, chunk, nbuckets);
    k_scan_tile<<<ntiles, BT, 0, stream>>>(hist, bs, L);
    k_transp<<<vtiles * btiles, BT, 0, stream>>>(hist, bs, histT, bstart, nbuckets, ntiles, E);
    k_scatter<<<NCH, BT, 0, stream>>>(ei, histT, buf, E, chunk, nbuckets);
    k_bucket<<<nbuckets, BT, 0, stream>>>(buf, bstart, csr, rs, lab0, lab1, N, E, nbuckets);
    k_prop<<<pgrid, BT, 0, stream>>>(csr, rs, lab1, lab2, N, E);
    k_prop_final<<<pgrid, BT, 0, stream>>>(csr, rs, lab2, lab0, lab1, out, N, E, pgrid);
}

// Round 8
// 198.604 us; speedup vs baseline: 1.3147x; 1.0168x over previous
//
#include <hip/hip_runtime.h>
#include <hip/hip_bf16.h>

// WeisfeilerLehman: labels0 = argmax(x, -1); 3x ordered polynomial hash over edges.
// All arithmetic mod 2^32 (uint32 wrap) == reference int64 truncated to int32.
// R19: XCD-chunked swizzle for hist/scatter writes; csr writeback before prop.
// R20: k_bucket was the top controllable kernel (40us, occ 24%, nothing
//      saturated -> latency + round-imbalance at 391 blocks / 256 CUs).
//      BROWS 256->128: grid 782 ~ 3 blocks/CU (round tail 1/2 machine -> 1/4
//      round), per-block work halved, LDS 49KB -> 25KB so 3+ blocks co-reside.
//      Ripple: BBITS=7, NBK=1024 (scatter match_key<10>, wbase 32KB -- still
//      2 blocks/CU at grid 512), bucket match_key<8> sentinel 255, CMAX 5120,
//      KBMAX 10, scan L=400K (ntiles 391 <= 512 ok), transp vtiles 13.

#define WL_D 128
#define NCH 512             // MSD chunk count (scatter grid)
#define GRID_F 2048         // fused hist/argmax grid
#define BT 512              // threads per block (8 waves)
#define MSDW 8
#define BBITS 7             // bucket = row >> 7
#define BROWS 128           // rows per bucket
#define NBK 1024            // max buckets (N <= 131072)
#define RLSHIFT 23          // buf pack: (rl << 23) | col   (col < 2^23)
#define COLMASK ((1u << RLSHIFT) - 1u)
#define CMAX 5120           // LDS-staged output cap (20 KB); mean len 4096 + 16 sigma
#define NBMAX 13            // unrolled batches per wave in k_scatter (chunk 6250)
#define KBMAX 10            // unrolled batches per wave in k_bucket (len <= CMAX)
#define HP8 2487512833u     // 31^8 mod 2^32

// XCD-chunked chunk assignment: blockIdx -> chunk such that each XCD (bid % 8
// under round-robin dispatch) owns NCH/8 consecutive chunks. Bijective on [0,NCH).
__device__ inline int xcd_chunk(int bid) { return ((bid & 7) << 6) | (bid >> 3); }

// mask of lanes whose low BITS bits of v match mine (inactive lanes use a
// sentinel outside the valid key range so they never match active lanes)
template <int BITS>
__device__ inline unsigned long long match_key(unsigned v) {
    unsigned long long m = ~0ull;
    #pragma unroll
    for (int b = 0; b < BITS; ++b) {
        unsigned long long s = __ballot((v >> b) & 1u);
        m &= ((v >> b) & 1u) ? s : ~s;
    }
    return m;
}

// ---- fused: chunk bucket-histogram (blocks < NCH) + argmax ----
__global__ void __launch_bounds__(BT)
k_hist_argmax(const float* __restrict__ x, const int* __restrict__ ei,
              unsigned* __restrict__ lab0, unsigned* __restrict__ hist,
              int N, int E, int chunk, int nbuckets) {
    __shared__ unsigned h[NBK];
    int bid = blockIdx.x, t = threadIdx.x, lane = t & 63, w = t >> 6;
    if (bid < NCH) {                    // uniform per-block condition: syncs are safe
        int b = xcd_chunk(bid);         // swizzled chunk id (bijective on [0,NCH))
        for (int i = t; i < nbuckets; i += BT) h[i] = 0u;
        __syncthreads();
        int base = b * chunk, lim = min(base + chunk, E);
        for (int e = base + t; e < lim; e += BT)
            atomicAdd(&h[((unsigned)ei[e]) >> BBITS], 1u);
        __syncthreads();
        for (int v = t; v < nbuckets; v += BT) hist[(size_t)v * NCH + b] = h[v];
    }
    // argmax: 2 rows per wave (float4; lanes 0-31 row 2pr, lanes 32-63 row 2pr+1)
    int half = lane >> 5, li = lane & 31;
    for (int pr = bid * MSDW + w; 2 * pr < N; pr += GRID_F * MSDW) {
        int r = 2 * pr + half;
        float bv = -3.4e38f; int bi = 0;
        if (r < N) {
            float4 v = ((const float4*)(x + (size_t)r * WL_D))[li];
            bv = v.x; bi = 4 * li;
            if (v.y > bv) { bv = v.y; bi = 4 * li + 1; }
            if (v.z > bv) { bv = v.z; bi = 4 * li + 2; }
            if (v.w > bv) { bv = v.w; bi = 4 * li + 3; }
        }
        #pragma unroll
        for (int off = 16; off > 0; off >>= 1) {
            float ov = __shfl_down(bv, off, 32);
            int   oi = __shfl_down(bi, off, 32);
            if (ov > bv || (ov == bv && oi < bi)) { bv = ov; bi = oi; }
        }
        if (li == 0 && r < N) lab0[r] = (unsigned)bi;
    }
}

// ---- scan: tile (1024 elems / block, 2 per thread) + raw tile totals ----
__global__ void __launch_bounds__(BT)
k_scan_tile(unsigned* __restrict__ hist, unsigned* __restrict__ bsums, int L) {
    __shared__ unsigned smem[BT];
    int b = blockIdx.x, t = threadIdx.x;
    int i0 = b * 1024;
    unsigned v0 = (i0 + 2 * t     < L) ? hist[i0 + 2 * t]     : 0u;
    unsigned v1 = (i0 + 2 * t + 1 < L) ? hist[i0 + 2 * t + 1] : 0u;
    unsigned s = v0 + v1;
    smem[t] = s;
    __syncthreads();
    for (int o = 1; o < BT; o <<= 1) {
        unsigned u = (t >= o) ? smem[t - o] : 0u;
        __syncthreads();
        smem[t] += u;
        __syncthreads();
    }
    unsigned excl = smem[t] - s;
    if (i0 + 2 * t     < L) hist[i0 + 2 * t]     = excl;
    if (i0 + 2 * t + 1 < L) hist[i0 + 2 * t + 1] = excl + v0;
    if (t == BT - 1) bsums[b] = smem[BT - 1];
}

// ---- transpose scanned hist (+bsums scanned in-block) -> histT[b][v]; emit bstart ----
__global__ void __launch_bounds__(BT)
k_transp(const unsigned* __restrict__ hist, const unsigned* __restrict__ bsums,
         unsigned* __restrict__ histT, unsigned* __restrict__ bstart,
         int nbuckets, int ntiles, int E) {
    __shared__ unsigned tl[64][65];
    __shared__ unsigned sb[BT];
    int t = threadIdx.x;
    // replicated exclusive scan of bsums (ntiles <= 512)
    unsigned my = (t < ntiles) ? bsums[t] : 0u;
    sb[t] = my;
    __syncthreads();
    for (int o = 1; o < BT; o <<= 1) {
        unsigned u = (t >= o) ? sb[t - o] : 0u;
        __syncthreads();
        sb[t] += u;
        __syncthreads();
    }
    sb[t] -= my;                         // inclusive -> exclusive
    __syncthreads();
    int vtiles = (nbuckets + 63) / 64;
    int bx = blockIdx.x % vtiles;        // v-tile
    int by = blockIdx.x / vtiles;        // b-tile
    int tx = t & 63, ty = t >> 6;        // 64 x 8
    int vb = bx * 64, b0 = by * 64;
    #pragma unroll
    for (int r = 0; r < 8; ++r) {
        int row = r * 8 + ty;
        int v = vb + row;
        size_t idx = (size_t)v * NCH + (b0 + tx);
        tl[row][tx] = (v < nbuckets) ? (hist[idx] + sb[idx >> 10]) : 0u;
    }
    __syncthreads();
    #pragma unroll
    for (int r = 0; r < 8; ++r) {
        int row = r * 8 + ty;            // b-offset within tile
        int v = vb + tx;
        if (v < nbuckets) histT[(size_t)(b0 + row) * nbuckets + v] = tl[tx][row];
    }
    // bucket starts = chunk-0 column of the scanned hist
    if (by == 0 && t < 64) {
        int v = vb + t;
        if (v < nbuckets) bstart[v] = tl[t][0];
    }
    if (blockIdx.x == 0 && t == 64) bstart[nbuckets] = (unsigned)E;
}

// ---- stable MSD scatter: prefetched batches + cached masks, LDS cursors ----
__global__ void __launch_bounds__(BT)
k_scatter(const int* __restrict__ ei, const unsigned* __restrict__ histT,
          unsigned* __restrict__ buf, int E, int chunk, int nbuckets) {
    __shared__ unsigned wbase[MSDW * NBK];   // 32 KB
    int b = xcd_chunk(blockIdx.x);           // swizzled chunk id
    int t = threadIdx.x, lane = t & 63, w = t >> 6;
    unsigned long long lmask = (1ull << lane) - 1ull;
    for (int i = t; i < MSDW * NBK; i += BT) wbase[i] = 0u;
    __syncthreads();
    int base = b * chunk, lim = min(base + chunk, E);
    int sub  = (chunk + MSDW - 1) / MSDW;
    int wbeg = base + w * sub;
    int wend = min(wbeg + sub, lim);
    int nbat = (wbeg < wend) ? ((wend - wbeg + 63) >> 6) : 0;
    // prefetch all row loads (static reg indices; issued before any ballot chain)
    unsigned r_[NBMAX];
    #pragma unroll
    for (int k = 0; k < NBMAX; ++k) {
        int e = wbeg + k * 64 + lane;
        r_[k] = (e < wend) ? (unsigned)ei[e] : 0u;
    }
    // pass A: per-wave bucket counts; cache the match masks
    unsigned long long m_[NBMAX];
    #pragma unroll
    for (int k = 0; k < NBMAX; ++k) {
        if (k >= nbat) break;
        int e = wbeg + k * 64 + lane;
        bool act = (e < wend);
        unsigned v = act ? (r_[k] >> BBITS) : (NBK - 1u);
        unsigned long long m = match_key<10>(v);
        m_[k] = m;
        unsigned before = (unsigned)__popcll(m & lmask);
        if (act && before == 0u) wbase[w * NBK + v] += (unsigned)__popcll(m);
    }
    for (int k = NBMAX; k < nbat; ++k) {     // dynamic tail (robustness)
        int e = wbeg + k * 64 + lane;
        bool act = (e < wend);
        unsigned v = act ? (((unsigned)ei[e]) >> BBITS) : (NBK - 1u);
        unsigned long long m = match_key<10>(v);
        unsigned before = (unsigned)__popcll(m & lmask);
        if (act && before == 0u) wbase[w * NBK + v] += (unsigned)__popcll(m);
    }
    __syncthreads();
    // seed per-wave cursors from transposed bases (coalesced)
    for (int v = t; v < nbuckets; v += BT) {
        unsigned g = histT[(size_t)b * nbuckets + v];
        #pragma unroll
        for (int w2 = 0; w2 < MSDW; ++w2) {
            unsigned cnt = wbase[w2 * NBK + v];
            wbase[w2 * NBK + v] = g;
            g += cnt;
        }
    }
    __syncthreads();
    // pass B: prefetch cols (rows still live in r_), reuse masks, stable scatter
    unsigned c_[NBMAX];
    #pragma unroll
    for (int k = 0; k < NBMAX; ++k) {
        int e = wbeg + k * 64 + lane;
        c_[k] = (e < wend) ? (unsigned)ei[(size_t)E + e] : 0u;
    }
    #pragma unroll
    for (int k = 0; k < NBMAX; ++k) {
        if (k >= nbat) break;
        int e = wbeg + k * 64 + lane;
        bool act = (e < wend);
        unsigned r = r_[k], col = c_[k];
        unsigned v = r >> BBITS;                 // used only when act
        unsigned long long m = m_[k];
        unsigned before = (unsigned)__popcll(m & lmask);
        int leader = __ffsll(m) - 1;
        unsigned base0 = 0;
        if (act && before == 0u) {
            base0 = wbase[w * NBK + v];
            wbase[w * NBK + v] = base0 + (unsigned)__popcll(m);
        }
        base0 = __shfl(base0, leader, 64);
        if (act) buf[base0 + before] = ((r & (BROWS - 1u)) << RLSHIFT) | col;
    }
    for (int k = NBMAX; k < nbat; ++k) {     // dynamic tail
        int e = wbeg + k * 64 + lane;
        bool act = (e < wend);
        unsigned r   = act ? (unsigned)ei[e] : 0u;
        unsigned col = act ? (unsigned)ei[(size_t)E + e] : 0u;
        unsigned v = act ? (r >> BBITS) : (NBK - 1u);
        unsigned long long m = match_key<10>(v);
        unsigned before = (unsigned)__popcll(m & lmask);
        unsigned total  = (unsigned)__popcll(m);
        int leader = __ffsll(m) - 1;
        unsigned base0 = 0;
        if (act && before == 0u) { base0 = wbase[w * NBK + v]; wbase[w * NBK + v] = base0 + total; }
        base0 = __shfl(base0, leader, 64);
        if (act) buf[base0 + before] = ((r & (BROWS - 1u)) << RLSHIFT) | col;
    }
}

// ---- per-bucket stable counting sort by rl (reg-prefetched, LDS-staged out)
//      + FUSED first prop ----
__global__ void __launch_bounds__(BT)
k_bucket(const unsigned* __restrict__ buf, const unsigned* __restrict__ bstart,
         unsigned* __restrict__ csr, unsigned* __restrict__ rs_g,
         const unsigned* __restrict__ lab0, unsigned* __restrict__ lab1,
         int N, int E, int nbuckets) {
    __shared__ unsigned data2[CMAX];          // 20 KB (sorted output staging)
    __shared__ unsigned h2[MSDW * BROWS];     // 4 KB
    __shared__ unsigned offs[BROWS];          // 0.5 KB
    int bb = blockIdx.x, t = threadIdx.x, lane = t & 63, w = t >> 6;
    unsigned long long lmask = (1ull << lane) - 1ull;
    unsigned start = bstart[bb];
    unsigned end   = bstart[bb + 1];
    unsigned len = end - start;
    bool lds_ok = (len <= CMAX);
    for (int i = t; i < MSDW * BROWS; i += BT) h2[i] = 0u;
    __syncthreads();
    unsigned sub  = (len + MSDW - 1u) / MSDW;
    unsigned wbeg = w * sub;
    unsigned wend = min(wbeg + sub, len);
    int nbat = (wbeg < wend) ? (int)((wend - wbeg + 63u) >> 6) : 0;
    // prefetch the wave's whole slice into regs (i >= wend iff k >= nbat covers OOB)
    unsigned d_[KBMAX];
    #pragma unroll
    for (int k = 0; k < KBMAX; ++k) {
        unsigned i = wbeg + (unsigned)(k * 64 + lane);
        d_[k] = (i < wend) ? buf[start + i] : 0u;
    }
    // pass A: per-wave rl counts (ballots overlap the prefetch)
    #pragma unroll
    for (int k = 0; k < KBMAX; ++k) {
        if (k >= nbat) break;
        unsigned i = wbeg + (unsigned)(k * 64 + lane);
        bool act = (i < wend);
        unsigned v = act ? (d_[k] >> RLSHIFT) : 255u;
        unsigned long long m = match_key<8>(v);
        unsigned before = (unsigned)__popcll(m & lmask);
        unsigned total  = (unsigned)__popcll(m);
        if (act && before == 0u) h2[w * BROWS + v] += total;
    }
    for (int k = KBMAX; k < nbat; ++k) {     // dynamic tail (giant-bucket fallback)
        unsigned i = wbeg + (unsigned)(k * 64 + lane);
        bool act = (i < wend);
        unsigned v = act ? (buf[start + i] >> RLSHIFT) : 255u;
        unsigned long long m = match_key<8>(v);
        unsigned before = (unsigned)__popcll(m & lmask);
        unsigned total  = (unsigned)__popcll(m);
        if (act && before == 0u) h2[w * BROWS + v] += total;
    }
    __syncthreads();
    // exclusive scan over rl (128 entries, threads t < BROWS); emit rs; seed cursors
    unsigned hv = 0;
    if (t < BROWS) {
        #pragma unroll
        for (int w2 = 0; w2 < MSDW; ++w2) hv += h2[w2 * BROWS + t];
        offs[t] = hv;
    }
    __syncthreads();
    for (int o = 1; o < BROWS; o <<= 1) {
        unsigned s = (t < BROWS && t >= o) ? offs[t - o] : 0u;
        __syncthreads();
        if (t < BROWS) offs[t] += s;
        __syncthreads();
    }
    if (t < BROWS) {
        unsigned excl = offs[t] - hv;
        int row = bb * BROWS + t;
        if (row < N) rs_g[row] = start + excl;
        unsigned g = lds_ok ? excl : (start + excl);   // bucket-relative if LDS-staged
        #pragma unroll
        for (int w2 = 0; w2 < MSDW; ++w2) {
            unsigned cnt = h2[w2 * BROWS + t];
            h2[w2 * BROWS + t] = g;
            g += cnt;
        }
    }
    __syncthreads();
    // pass B: stable scatter cols (from regs) into LDS staging / csr fallback
    #pragma unroll
    for (int k = 0; k < KBMAX; ++k) {
        if (k >= nbat) break;
        unsigned i = wbeg + (unsigned)(k * 64 + lane);
        bool act = (i < wend);
        unsigned p = d_[k];
        unsigned v = act ? (p >> RLSHIFT) : 255u;
        unsigned long long m = match_key<8>(v);
        unsigned before = (unsigned)__popcll(m & lmask);
        unsigned total  = (unsigned)__popcll(m);
        int leader = __ffsll(m) - 1;
        unsigned base0 = 0;
        if (act && before == 0u) { base0 = h2[w * BROWS + v]; h2[w * BROWS + v] = base0 + total; }
        base0 = __shfl(base0, leader, 64);
        if (act) {
            if (lds_ok) data2[base0 + before] = p & COLMASK;
            else        csr[base0 + before]   = p & COLMASK;
        }
    }
    for (int k = KBMAX; k < nbat; ++k) {     // dynamic tail
        unsigned i = wbeg + (unsigned)(k * 64 + lane);
        bool act = (i < wend);
        unsigned p = act ? buf[start + i] : 0u;
        unsigned v = act ? (p >> RLSHIFT) : 255u;
        unsigned long long m = match_key<8>(v);
        unsigned before = (unsigned)__popcll(m & lmask);
        unsigned total  = (unsigned)__popcll(m);
        int leader = __ffsll(m) - 1;
        unsigned base0 = 0;
        if (act && before == 0u) { base0 = h2[w * BROWS + v]; h2[w * BROWS + v] = base0 + total; }
        base0 = __shfl(base0, leader, 64);
        if (act) {
            if (lds_ok) data2[base0 + before] = p & COLMASK;
            else        csr[base0 + before]   = p & COLMASK;
        }
    }
    __syncthreads();
    // stream sorted bucket out FIRST: the stores drain underneath the fused prop
    if (lds_ok) for (unsigned i = t; i < len; i += BT) csr[start + i] = data2[i];
    // FUSED first prop: lab1 for this bucket's rows, 8 lanes/row, cols from LDS.
    // 4-wide reassociated Horner: independent col loads, then independent gathers.
    const unsigned H1 = HP8, H2 = HP8 * HP8, H3 = H2 * HP8, H4 = H3 * HP8;
    const unsigned* srcp = lds_ok ? (const unsigned*)data2 : (csr + start);
    int l = t & 7;
    for (int r0 = t >> 3; r0 < BROWS; r0 += BT / 8) {
        unsigned beg = r0 ? offs[r0 - 1] : 0u;
        unsigned d   = offs[r0] - beg;
        unsigned h = 0u;
        unsigned M = (d > (unsigned)l) ? ((d - (unsigned)l + 7u) >> 3) : 0u;
        unsigned bidx = beg + (unsigned)l;
        unsigned m = 0;
        for (; m + 4u <= M; m += 4u) {
            unsigned c0 = srcp[bidx + 8u * m];
            unsigned c1 = srcp[bidx + 8u * m + 8u];
            unsigned c2 = srcp[bidx + 8u * m + 16u];
            unsigned c3 = srcp[bidx + 8u * m + 24u];
            unsigned l0 = lab0[c0], l1 = lab0[c1], l2 = lab0[c2], l3 = lab0[c3];
            h = h * H4 + l0 * H3 + l1 * H2 + l2 * H1 + l3;
        }
        for (; m < M; ++m) h = h * H1 + lab0[srcp[bidx + 8u * m]];
        if (M) {
            unsigned T = d - 1u - (unsigned)l - 8u * (M - 1u);   // in [0,7]
            unsigned p = ((T & 1u) ? 31u : 1u) * ((T & 2u) ? 961u : 1u)
                       * ((T & 4u) ? 923521u : 1u);
            h *= p;
        }
        h += __shfl_xor(h, 1, 64);
        h += __shfl_xor(h, 2, 64);
        h += __shfl_xor(h, 4, 64);
        int row = bb * BROWS + r0;
        if (l == 0 && row < N) lab1[row] = h;
    }
}

// ---- prop: 8 lanes per row, 4-wide reassociated base-31^8 Horner ----
__device__ inline unsigned horner8(const unsigned* __restrict__ csr,
                                   const unsigned* __restrict__ rs,
                                   const unsigned* __restrict__ lin,
                                   int g, int l, int N, int E) {
    const unsigned H1 = HP8, H2 = HP8 * HP8, H3 = H2 * HP8, H4 = H3 * HP8;
    unsigned s = rs[g];
    unsigned e = (g + 1 < N) ? rs[g + 1] : (unsigned)E;
    unsigned d = e - s;
    unsigned h = 0u;
    unsigned M = (d > (unsigned)l) ? ((d - (unsigned)l + 7u) >> 3) : 0u;
    unsigned bidx = s + (unsigned)l;
    unsigned m = 0;
    for (; m + 4u <= M; m += 4u) {
        unsigned c0 = csr[bidx + 8u * m];
        unsigned c1 = csr[bidx + 8u * m + 8u];
        unsigned c2 = csr[bidx + 8u * m + 16u];
        unsigned c3 = csr[bidx + 8u * m + 24u];
        unsigned l0 = lin[c0], l1 = lin[c1], l2 = lin[c2], l3 = lin[c3];
        h = h * H4 + l0 * H3 + l1 * H2 + l2 * H1 + l3;
    }
    for (; m < M; ++m) h = h * H1 + lin[csr[bidx + 8u * m]];
    if (M) {
        unsigned T = d - 1u - (unsigned)l - 8u * (M - 1u);   // in [0,7]
        unsigned p = ((T & 1u) ? 31u : 1u) * ((T & 2u) ? 961u : 1u)
                   * ((T & 4u) ? 923521u : 1u);
        h *= p;
    }
    h += __shfl_xor(h, 1, 64);
    h += __shfl_xor(h, 2, 64);
    h += __shfl_xor(h, 4, 64);
    return h;
}

__global__ void __launch_bounds__(BT)
k_prop(const unsigned* __restrict__ csr, const unsigned* __restrict__ rs,
       const unsigned* __restrict__ lin, unsigned* __restrict__ lout,
       int N, int E) {
    int idx = blockIdx.x * BT + threadIdx.x;
    int g = idx >> 3, l = idx & 7;
    if (g >= N) return;
    unsigned h = horner8(csr, rs, lin, g, l, N, E);
    if (l == 0) lout[g] = h;
}

// final prop: writes lab3 straight into out[0..N) and out[4N..5N), plus copies
// lab0..2 into out[N..4N)
__global__ void __launch_bounds__(BT)
k_prop_final(const unsigned* __restrict__ csr, const unsigned* __restrict__ rs,
             const unsigned* __restrict__ lin, const unsigned* __restrict__ l0,
             const unsigned* __restrict__ l1, int* __restrict__ out,
             int N, int E, int pgrid) {
    int idx = blockIdx.x * BT + threadIdx.x;
    int g = idx >> 3, l = idx & 7;
    if (g < N) {
        unsigned h = horner8(csr, rs, lin, g, l, N, E);
        if (l == 0) { out[g] = (int)h; out[4 * N + g] = (int)h; }
    }
    for (int i = idx; i < N; i += pgrid * BT) {
        out[N + i]     = (int)l0[i];
        out[2 * N + i] = (int)l1[i];
        out[3 * N + i] = (int)lin[i];    // lin == lab2 on the final pass
    }
}

extern "C" void kernel_launch(void* const* d_in, const int* in_sizes, int n_in,
                              void* d_out, int out_size, void* d_ws, size_t ws_size,
                              hipStream_t stream) {
    const float* x  = (const float*)d_in[0];
    const int*   ei = (const int*)d_in[1];
    int* out = (int*)d_out;

    int N = in_sizes[0] / WL_D;
    int E = in_sizes[1] / 2;
    int chunk    = (E + NCH - 1) / NCH;        // 6250
    int nbuckets = (N + BROWS - 1) / BROWS;    // 782
    int L        = nbuckets * NCH;             // 400,384
    int ntiles   = (L + 1023) / 1024;          // 391 (<= 512: in-block scan ok)
    int vtiles   = (nbuckets + 63) / 64;       // 13
    int btiles   = NCH / 64;                   // 8
    int pgrid    = (8 * N + BT - 1) / BT;      // 1563 (8 lanes per row)

    // workspace layout (uint32 units) — everything written before read
    unsigned* ws    = (unsigned*)d_ws;
    unsigned* lab0  = ws;               // N
    unsigned* lab1  = lab0 + N;         // N
    unsigned* lab2  = lab1 + N;         // N
    unsigned* rs    = lab2 + N;         // N
    unsigned* bs    = rs + N;           // 1024
    unsigned* bstart= bs + 1024;        // 1024 (nbuckets+1 used)
    unsigned* hist  = bstart + 1024;    // L
    unsigned* buf   = hist + L;         // E
    unsigned* csr   = buf + E;          // E
    unsigned* histT = csr;              // transient: csr space is free until k_bucket

    k_hist_argmax<<<GRID_F, BT, 0, stream>>>(x, ei, lab0, hist, N, E, chunk, nbuckets);
    k_scan_tile<<<ntiles, BT, 0, stream>>>(hist, bs, L);
    k_transp<<<vtiles * btiles, BT, 0, stream>>>(hist, bs, histT, bstart, nbuckets, ntiles, E);
    k_scatter<<<NCH, BT, 0, stream>>>(ei, histT, buf, E, chunk, nbuckets);
    k_bucket<<<nbuckets, BT, 0, stream>>>(buf, bstart, csr, rs, lab0, lab1, N, E, nbuckets);
    k_prop<<<pgrid, BT, 0, stream>>>(csr, rs, lab1, lab2, N, E);
    k_prop_final<<<pgrid, BT, 0, stream>>>(csr, rs, lab2, lab0, lab1, out, N, E, pgrid);
}

// Round 9
// 197.714 us; speedup vs baseline: 1.3206x; 1.0045x over previous
//
#include <hip/hip_runtime.h>
#include <hip/hip_bf16.h>

// WeisfeilerLehman: labels0 = argmax(x, -1); 3x ordered polynomial hash over edges.
// All arithmetic mod 2^32 (uint32 wrap) == reference int64 truncated to int32.
// R20: BROWS 128 (bucket grid 782 ~ 3 blocks/CU, LDS 25KB).
// R21: (a) hist/argmax ROLE SPLIT: blocks < NCH do hist only (int4-vectorized ei
//      reads); blocks >= NCH do all the argmax -- removes the hist blocks' tail.
//      (b) k_scatter: mask cache dropped (saves 26 VGPR; ballots are throughput
//      work the extra waves hide) + __launch_bounds__(BT,6) -> VGPR<=85,
//      3 blocks/CU (was 2). (c) k_bucket: 128-entry scan via wave-0 shfl_up
//      (2 barriers, was 16). (d) horner: 2-wide reassociated residual step.

#define WL_D 128
#define NCH 512             // MSD chunk count (scatter grid)
#define GRID_F 2048         // fused hist/argmax grid
#define BT 512              // threads per block (8 waves)
#define MSDW 8
#define BBITS 7             // bucket = row >> 7
#define BROWS 128           // rows per bucket
#define NBK 1024            // max buckets (N <= 131072)
#define RLSHIFT 23          // buf pack: (rl << 23) | col   (col < 2^23)
#define COLMASK ((1u << RLSHIFT) - 1u)
#define CMAX 5120           // LDS-staged output cap (20 KB)
#define NBMAX 13            // unrolled batches per wave in k_scatter (chunk 6250)
#define KBMAX 10            // unrolled batches per wave in k_bucket (len <= CMAX)
#define HP8 2487512833u     // 31^8 mod 2^32

// XCD-chunked chunk assignment: blockIdx -> chunk such that each XCD (bid % 8
// under round-robin dispatch) owns NCH/8 consecutive chunks. Bijective on [0,NCH).
__device__ inline int xcd_chunk(int bid) { return ((bid & 7) << 6) | (bid >> 3); }

// mask of lanes whose low BITS bits of v match mine (inactive lanes use a
// sentinel outside the valid key range so they never match active lanes)
template <int BITS>
__device__ inline unsigned long long match_key(unsigned v) {
    unsigned long long m = ~0ull;
    #pragma unroll
    for (int b = 0; b < BITS; ++b) {
        unsigned long long s = __ballot((v >> b) & 1u);
        m &= ((v >> b) & 1u) ? s : ~s;
    }
    return m;
}

// ---- fused: chunk bucket-histogram (blocks < NCH) OR argmax (blocks >= NCH) ----
__global__ void __launch_bounds__(BT)
k_hist_argmax(const float* __restrict__ x, const int* __restrict__ ei,
              unsigned* __restrict__ lab0, unsigned* __restrict__ hist,
              int N, int E, int chunk, int nbuckets) {
    __shared__ unsigned h[NBK];
    int bid = blockIdx.x, t = threadIdx.x, lane = t & 63, w = t >> 6;
    if (bid < NCH) {                    // hist-only blocks (uniform condition)
        int b = xcd_chunk(bid);         // swizzled chunk id (bijective on [0,NCH))
        for (int i = t; i < nbuckets; i += BT) h[i] = 0u;
        __syncthreads();
        int base = b * chunk, lim = min(base + chunk, E);
        int vbeg = (base + 3) & ~3; if (vbeg > lim) vbeg = lim;
        int vend = lim & ~3;        if (vend < vbeg) vend = vbeg;
        for (int e = base + t; e < vbeg; e += BT)
            atomicAdd(&h[((unsigned)ei[e]) >> BBITS], 1u);
        for (int i = vbeg + 4 * t; i < vend; i += 4 * BT) {
            int4 v4 = *(const int4*)(ei + i);
            atomicAdd(&h[((unsigned)v4.x) >> BBITS], 1u);
            atomicAdd(&h[((unsigned)v4.y) >> BBITS], 1u);
            atomicAdd(&h[((unsigned)v4.z) >> BBITS], 1u);
            atomicAdd(&h[((unsigned)v4.w) >> BBITS], 1u);
        }
        for (int e = vend + t; e < lim; e += BT)
            atomicAdd(&h[((unsigned)ei[e]) >> BBITS], 1u);
        __syncthreads();
        for (int v = t; v < nbuckets; v += BT) hist[(size_t)v * NCH + b] = h[v];
    } else {
        // argmax blocks: 2 rows per wave (float4; half-waves of 32 lanes)
        int ab = bid - NCH;
        int half = lane >> 5, li = lane & 31;
        for (int pr = ab * MSDW + w; 2 * pr < N; pr += (GRID_F - NCH) * MSDW) {
            int r = 2 * pr + half;
            float bv = -3.4e38f; int bi = 0;
            if (r < N) {
                float4 v = ((const float4*)(x + (size_t)r * WL_D))[li];
                bv = v.x; bi = 4 * li;
                if (v.y > bv) { bv = v.y; bi = 4 * li + 1; }
                if (v.z > bv) { bv = v.z; bi = 4 * li + 2; }
                if (v.w > bv) { bv = v.w; bi = 4 * li + 3; }
            }
            #pragma unroll
            for (int off = 16; off > 0; off >>= 1) {
                float ov = __shfl_down(bv, off, 32);
                int   oi = __shfl_down(bi, off, 32);
                if (ov > bv || (ov == bv && oi < bi)) { bv = ov; bi = oi; }
            }
            if (li == 0 && r < N) lab0[r] = (unsigned)bi;
        }
    }
}

// ---- scan: tile (1024 elems / block, 2 per thread) + raw tile totals ----
__global__ void __launch_bounds__(BT)
k_scan_tile(unsigned* __restrict__ hist, unsigned* __restrict__ bsums, int L) {
    __shared__ unsigned smem[BT];
    int b = blockIdx.x, t = threadIdx.x;
    int i0 = b * 1024;
    unsigned v0 = (i0 + 2 * t     < L) ? hist[i0 + 2 * t]     : 0u;
    unsigned v1 = (i0 + 2 * t + 1 < L) ? hist[i0 + 2 * t + 1] : 0u;
    unsigned s = v0 + v1;
    smem[t] = s;
    __syncthreads();
    for (int o = 1; o < BT; o <<= 1) {
        unsigned u = (t >= o) ? smem[t - o] : 0u;
        __syncthreads();
        smem[t] += u;
        __syncthreads();
    }
    unsigned excl = smem[t] - s;
    if (i0 + 2 * t     < L) hist[i0 + 2 * t]     = excl;
    if (i0 + 2 * t + 1 < L) hist[i0 + 2 * t + 1] = excl + v0;
    if (t == BT - 1) bsums[b] = smem[BT - 1];
}

// ---- transpose scanned hist (+bsums scanned in-block) -> histT[b][v]; emit bstart ----
__global__ void __launch_bounds__(BT)
k_transp(const unsigned* __restrict__ hist, const unsigned* __restrict__ bsums,
         unsigned* __restrict__ histT, unsigned* __restrict__ bstart,
         int nbuckets, int ntiles, int E) {
    __shared__ unsigned tl[64][65];
    __shared__ unsigned sb[BT];
    int t = threadIdx.x;
    // replicated exclusive scan of bsums (ntiles <= 512)
    unsigned my = (t < ntiles) ? bsums[t] : 0u;
    sb[t] = my;
    __syncthreads();
    for (int o = 1; o < BT; o <<= 1) {
        unsigned u = (t >= o) ? sb[t - o] : 0u;
        __syncthreads();
        sb[t] += u;
        __syncthreads();
    }
    sb[t] -= my;                         // inclusive -> exclusive
    __syncthreads();
    int vtiles = (nbuckets + 63) / 64;
    int bx = blockIdx.x % vtiles;        // v-tile
    int by = blockIdx.x / vtiles;        // b-tile
    int tx = t & 63, ty = t >> 6;        // 64 x 8
    int vb = bx * 64, b0 = by * 64;
    #pragma unroll
    for (int r = 0; r < 8; ++r) {
        int row = r * 8 + ty;
        int v = vb + row;
        size_t idx = (size_t)v * NCH + (b0 + tx);
        tl[row][tx] = (v < nbuckets) ? (hist[idx] + sb[idx >> 10]) : 0u;
    }
    __syncthreads();
    #pragma unroll
    for (int r = 0; r < 8; ++r) {
        int row = r * 8 + ty;            // b-offset within tile
        int v = vb + tx;
        if (v < nbuckets) histT[(size_t)(b0 + row) * nbuckets + v] = tl[tx][row];
    }
    // bucket starts = chunk-0 column of the scanned hist
    if (by == 0 && t < 64) {
        int v = vb + t;
        if (v < nbuckets) bstart[v] = tl[t][0];
    }
    if (blockIdx.x == 0 && t == 64) bstart[nbuckets] = (unsigned)E;
}

// ---- stable MSD scatter: prefetched batches, LDS cursors; 3 blocks/CU ----
__global__ void __launch_bounds__(BT, 6)
k_scatter(const int* __restrict__ ei, const unsigned* __restrict__ histT,
          unsigned* __restrict__ buf, int E, int chunk, int nbuckets) {
    __shared__ unsigned wbase[MSDW * NBK];   // 32 KB
    int b = xcd_chunk(blockIdx.x);           // swizzled chunk id
    int t = threadIdx.x, lane = t & 63, w = t >> 6;
    unsigned long long lmask = (1ull << lane) - 1ull;
    for (int i = t; i < MSDW * NBK; i += BT) wbase[i] = 0u;
    __syncthreads();
    int base = b * chunk, lim = min(base + chunk, E);
    int sub  = (chunk + MSDW - 1) / MSDW;
    int wbeg = base + w * sub;
    int wend = min(wbeg + sub, lim);
    int nbat = (wbeg < wend) ? ((wend - wbeg + 63) >> 6) : 0;
    // prefetch all row loads (static reg indices; issued before any ballot chain)
    unsigned r_[NBMAX];
    #pragma unroll
    for (int k = 0; k < NBMAX; ++k) {
        int e = wbeg + k * 64 + lane;
        r_[k] = (e < wend) ? (unsigned)ei[e] : 0u;
    }
    // pass A: per-wave bucket counts
    #pragma unroll
    for (int k = 0; k < NBMAX; ++k) {
        if (k >= nbat) break;
        int e = wbeg + k * 64 + lane;
        bool act = (e < wend);
        unsigned v = act ? (r_[k] >> BBITS) : (NBK - 1u);
        unsigned long long m = match_key<10>(v);
        unsigned before = (unsigned)__popcll(m & lmask);
        if (act && before == 0u) wbase[w * NBK + v] += (unsigned)__popcll(m);
    }
    for (int k = NBMAX; k < nbat; ++k) {     // dynamic tail (robustness)
        int e = wbeg + k * 64 + lane;
        bool act = (e < wend);
        unsigned v = act ? (((unsigned)ei[e]) >> BBITS) : (NBK - 1u);
        unsigned long long m = match_key<10>(v);
        unsigned before = (unsigned)__popcll(m & lmask);
        if (act && before == 0u) wbase[w * NBK + v] += (unsigned)__popcll(m);
    }
    __syncthreads();
    // seed per-wave cursors from transposed bases (coalesced)
    for (int v = t; v < nbuckets; v += BT) {
        unsigned g = histT[(size_t)b * nbuckets + v];
        #pragma unroll
        for (int w2 = 0; w2 < MSDW; ++w2) {
            unsigned cnt = wbase[w2 * NBK + v];
            wbase[w2 * NBK + v] = g;
            g += cnt;
        }
    }
    __syncthreads();
    // pass B: prefetch cols (rows still live in r_), recompute masks, stable scatter
    unsigned c_[NBMAX];
    #pragma unroll
    for (int k = 0; k < NBMAX; ++k) {
        int e = wbeg + k * 64 + lane;
        c_[k] = (e < wend) ? (unsigned)ei[(size_t)E + e] : 0u;
    }
    #pragma unroll
    for (int k = 0; k < NBMAX; ++k) {
        if (k >= nbat) break;
        int e = wbeg + k * 64 + lane;
        bool act = (e < wend);
        unsigned r = r_[k], col = c_[k];
        unsigned v = act ? (r >> BBITS) : (NBK - 1u);
        unsigned long long m = match_key<10>(v);
        unsigned before = (unsigned)__popcll(m & lmask);
        int leader = __ffsll(m) - 1;
        unsigned base0 = 0;
        if (act && before == 0u) {
            base0 = wbase[w * NBK + v];
            wbase[w * NBK + v] = base0 + (unsigned)__popcll(m);
        }
        base0 = __shfl(base0, leader, 64);
        if (act) buf[base0 + before] = ((r & (BROWS - 1u)) << RLSHIFT) | col;
    }
    for (int k = NBMAX; k < nbat; ++k) {     // dynamic tail
        int e = wbeg + k * 64 + lane;
        bool act = (e < wend);
        unsigned r   = act ? (unsigned)ei[e] : 0u;
        unsigned col = act ? (unsigned)ei[(size_t)E + e] : 0u;
        unsigned v = act ? (r >> BBITS) : (NBK - 1u);
        unsigned long long m = match_key<10>(v);
        unsigned before = (unsigned)__popcll(m & lmask);
        unsigned total  = (unsigned)__popcll(m);
        int leader = __ffsll(m) - 1;
        unsigned base0 = 0;
        if (act && before == 0u) { base0 = wbase[w * NBK + v]; wbase[w * NBK + v] = base0 + total; }
        base0 = __shfl(base0, leader, 64);
        if (act) buf[base0 + before] = ((r & (BROWS - 1u)) << RLSHIFT) | col;
    }
}

// ---- per-bucket stable counting sort by rl (reg-prefetched, LDS-staged out)
//      + FUSED first prop ----
__global__ void __launch_bounds__(BT)
k_bucket(const unsigned* __restrict__ buf, const unsigned* __restrict__ bstart,
         unsigned* __restrict__ csr, unsigned* __restrict__ rs_g,
         const unsigned* __restrict__ lab0, unsigned* __restrict__ lab1,
         int N, int E, int nbuckets) {
    __shared__ unsigned data2[CMAX];          // 20 KB (sorted output staging)
    __shared__ unsigned h2[MSDW * BROWS];     // 4 KB
    __shared__ unsigned offs[BROWS];          // 0.5 KB
    int bb = blockIdx.x, t = threadIdx.x, lane = t & 63, w = t >> 6;
    unsigned long long lmask = (1ull << lane) - 1ull;
    unsigned start = bstart[bb];
    unsigned end   = bstart[bb + 1];
    unsigned len = end - start;
    bool lds_ok = (len <= CMAX);
    for (int i = t; i < MSDW * BROWS; i += BT) h2[i] = 0u;
    __syncthreads();
    unsigned sub  = (len + MSDW - 1u) / MSDW;
    unsigned wbeg = w * sub;
    unsigned wend = min(wbeg + sub, len);
    int nbat = (wbeg < wend) ? (int)((wend - wbeg + 63u) >> 6) : 0;
    // prefetch the wave's whole slice into regs
    unsigned d_[KBMAX];
    #pragma unroll
    for (int k = 0; k < KBMAX; ++k) {
        unsigned i = wbeg + (unsigned)(k * 64 + lane);
        d_[k] = (i < wend) ? buf[start + i] : 0u;
    }
    // pass A: per-wave rl counts (ballots overlap the prefetch)
    #pragma unroll
    for (int k = 0; k < KBMAX; ++k) {
        if (k >= nbat) break;
        unsigned i = wbeg + (unsigned)(k * 64 + lane);
        bool act = (i < wend);
        unsigned v = act ? (d_[k] >> RLSHIFT) : 255u;
        unsigned long long m = match_key<8>(v);
        unsigned before = (unsigned)__popcll(m & lmask);
        unsigned total  = (unsigned)__popcll(m);
        if (act && before == 0u) h2[w * BROWS + v] += total;
    }
    for (int k = KBMAX; k < nbat; ++k) {     // dynamic tail (giant-bucket fallback)
        unsigned i = wbeg + (unsigned)(k * 64 + lane);
        bool act = (i < wend);
        unsigned v = act ? (buf[start + i] >> RLSHIFT) : 255u;
        unsigned long long m = match_key<8>(v);
        unsigned before = (unsigned)__popcll(m & lmask);
        unsigned total  = (unsigned)__popcll(m);
        if (act && before == 0u) h2[w * BROWS + v] += total;
    }
    __syncthreads();
    // per-row totals -> offs (inclusive scan via wave-0 shfl; 2 barriers not 16)
    unsigned hv = 0;
    if (t < BROWS) {
        #pragma unroll
        for (int w2 = 0; w2 < MSDW; ++w2) hv += h2[w2 * BROWS + t];
        offs[t] = hv;
    }
    __syncthreads();
    if (t < 64) {
        unsigned a = offs[t], b2 = offs[t + 64];
        #pragma unroll
        for (int o = 1; o < 64; o <<= 1) {
            unsigned ua = __shfl_up(a, o, 64);
            unsigned ub = __shfl_up(b2, o, 64);
            if (t >= o) { a += ua; b2 += ub; }
        }
        unsigned tot = __shfl(a, 63, 64);
        offs[t] = a;                     // inclusive over first 64 rows
        offs[t + 64] = b2 + tot;         // inclusive over all 128
    }
    __syncthreads();
    if (t < BROWS) {
        unsigned excl = offs[t] - hv;
        int row = bb * BROWS + t;
        if (row < N) rs_g[row] = start + excl;
        unsigned g = lds_ok ? excl : (start + excl);   // bucket-relative if LDS-staged
        #pragma unroll
        for (int w2 = 0; w2 < MSDW; ++w2) {
            unsigned cnt = h2[w2 * BROWS + t];
            h2[w2 * BROWS + t] = g;
            g += cnt;
        }
    }
    __syncthreads();
    // pass B: stable scatter cols (from regs) into LDS staging / csr fallback
    #pragma unroll
    for (int k = 0; k < KBMAX; ++k) {
        if (k >= nbat) break;
        unsigned i = wbeg + (unsigned)(k * 64 + lane);
        bool act = (i < wend);
        unsigned p = d_[k];
        unsigned v = act ? (p >> RLSHIFT) : 255u;
        unsigned long long m = match_key<8>(v);
        unsigned before = (unsigned)__popcll(m & lmask);
        unsigned total  = (unsigned)__popcll(m);
        int leader = __ffsll(m) - 1;
        unsigned base0 = 0;
        if (act && before == 0u) { base0 = h2[w * BROWS + v]; h2[w * BROWS + v] = base0 + total; }
        base0 = __shfl(base0, leader, 64);
        if (act) {
            if (lds_ok) data2[base0 + before] = p & COLMASK;
            else        csr[base0 + before]   = p & COLMASK;
        }
    }
    for (int k = KBMAX; k < nbat; ++k) {     // dynamic tail
        unsigned i = wbeg + (unsigned)(k * 64 + lane);
        bool act = (i < wend);
        unsigned p = act ? buf[start + i] : 0u;
        unsigned v = act ? (p >> RLSHIFT) : 255u;
        unsigned long long m = match_key<8>(v);
        unsigned before = (unsigned)__popcll(m & lmask);
        unsigned total  = (unsigned)__popcll(m);
        int leader = __ffsll(m) - 1;
        unsigned base0 = 0;
        if (act && before == 0u) { base0 = h2[w * BROWS + v]; h2[w * BROWS + v] = base0 + total; }
        base0 = __shfl(base0, leader, 64);
        if (act) {
            if (lds_ok) data2[base0 + before] = p & COLMASK;
            else        csr[base0 + before]   = p & COLMASK;
        }
    }
    __syncthreads();
    // stream sorted bucket out FIRST: the stores drain underneath the fused prop
    if (lds_ok) for (unsigned i = t; i < len; i += BT) csr[start + i] = data2[i];
    // FUSED first prop: lab1 for this bucket's rows, 8 lanes/row, cols from LDS.
    const unsigned H1 = HP8, H2 = HP8 * HP8, H3 = H2 * HP8, H4 = H3 * HP8;
    const unsigned* srcp = lds_ok ? (const unsigned*)data2 : (csr + start);
    int l = t & 7;
    for (int r0 = t >> 3; r0 < BROWS; r0 += BT / 8) {
        unsigned beg = r0 ? offs[r0 - 1] : 0u;
        unsigned d   = offs[r0] - beg;
        unsigned h = 0u;
        unsigned M = (d > (unsigned)l) ? ((d - (unsigned)l + 7u) >> 3) : 0u;
        unsigned bidx = beg + (unsigned)l;
        unsigned m = 0;
        for (; m + 4u <= M; m += 4u) {
            unsigned c0 = srcp[bidx + 8u * m];
            unsigned c1 = srcp[bidx + 8u * m + 8u];
            unsigned c2 = srcp[bidx + 8u * m + 16u];
            unsigned c3 = srcp[bidx + 8u * m + 24u];
            unsigned l0 = lab0[c0], l1 = lab0[c1], l2 = lab0[c2], l3 = lab0[c3];
            h = h * H4 + l0 * H3 + l1 * H2 + l2 * H1 + l3;
        }
        for (; m + 2u <= M; m += 2u) {
            unsigned c0 = srcp[bidx + 8u * m];
            unsigned c1 = srcp[bidx + 8u * m + 8u];
            h = h * H2 + lab0[c0] * H1 + lab0[c1];
        }
        for (; m < M; ++m) h = h * H1 + lab0[srcp[bidx + 8u * m]];
        if (M) {
            unsigned T = d - 1u - (unsigned)l - 8u * (M - 1u);   // in [0,7]
            unsigned p = ((T & 1u) ? 31u : 1u) * ((T & 2u) ? 961u : 1u)
                       * ((T & 4u) ? 923521u : 1u);
            h *= p;
        }
        h += __shfl_xor(h, 1, 64);
        h += __shfl_xor(h, 2, 64);
        h += __shfl_xor(h, 4, 64);
        int row = bb * BROWS + r0;
        if (l == 0 && row < N) lab1[row] = h;
    }
}

// ---- prop: 8 lanes per row, 4/2-wide reassociated base-31^8 Horner ----
__device__ inline unsigned horner8(const unsigned* __restrict__ csr,
                                   const unsigned* __restrict__ rs,
                                   const unsigned* __restrict__ lin,
                                   int g, int l, int N, int E) {
    const unsigned H1 = HP8, H2 = HP8 * HP8, H3 = H2 * HP8, H4 = H3 * HP8;
    unsigned s = rs[g];
    unsigned e = (g + 1 < N) ? rs[g + 1] : (unsigned)E;
    unsigned d = e - s;
    unsigned h = 0u;
    unsigned M = (d > (unsigned)l) ? ((d - (unsigned)l + 7u) >> 3) : 0u;
    unsigned bidx = s + (unsigned)l;
    unsigned m = 0;
    for (; m + 4u <= M; m += 4u) {
        unsigned c0 = csr[bidx + 8u * m];
        unsigned c1 = csr[bidx + 8u * m + 8u];
        unsigned c2 = csr[bidx + 8u * m + 16u];
        unsigned c3 = csr[bidx + 8u * m + 24u];
        unsigned l0 = lin[c0], l1 = lin[c1], l2 = lin[c2], l3 = lin[c3];
        h = h * H4 + l0 * H3 + l1 * H2 + l2 * H1 + l3;
    }
    for (; m + 2u <= M; m += 2u) {
        unsigned c0 = csr[bidx + 8u * m];
        unsigned c1 = csr[bidx + 8u * m + 8u];
        h = h * H2 + lin[c0] * H1 + lin[c1];
    }
    for (; m < M; ++m) h = h * H1 + lin[csr[bidx + 8u * m]];
    if (M) {
        unsigned T = d - 1u - (unsigned)l - 8u * (M - 1u);   // in [0,7]
        unsigned p = ((T & 1u) ? 31u : 1u) * ((T & 2u) ? 961u : 1u)
                   * ((T & 4u) ? 923521u : 1u);
        h *= p;
    }
    h += __shfl_xor(h, 1, 64);
    h += __shfl_xor(h, 2, 64);
    h += __shfl_xor(h, 4, 64);
    return h;
}

__global__ void __launch_bounds__(BT)
k_prop(const unsigned* __restrict__ csr, const unsigned* __restrict__ rs,
       const unsigned* __restrict__ lin, unsigned* __restrict__ lout,
       int N, int E) {
    int idx = blockIdx.x * BT + threadIdx.x;
    int g = idx >> 3, l = idx & 7;
    if (g >= N) return;
    unsigned h = horner8(csr, rs, lin, g, l, N, E);
    if (l == 0) lout[g] = h;
}

// final prop: writes lab3 straight into out[0..N) and out[4N..5N), plus copies
// lab0..2 into out[N..4N)
__global__ void __launch_bounds__(BT)
k_prop_final(const unsigned* __restrict__ csr, const unsigned* __restrict__ rs,
             const unsigned* __restrict__ lin, const unsigned* __restrict__ l0,
             const unsigned* __restrict__ l1, int* __restrict__ out,
             int N, int E, int pgrid) {
    int idx = blockIdx.x * BT + threadIdx.x;
    int g = idx >> 3, l = idx & 7;
    if (g < N) {
        unsigned h = horner8(csr, rs, lin, g, l, N, E);
        if (l == 0) { out[g] = (int)h; out[4 * N + g] = (int)h; }
    }
    for (int i = idx; i < N; i += pgrid * BT) {
        out[N + i]     = (int)l0[i];
        out[2 * N + i] = (int)l1[i];
        out[3 * N + i] = (int)lin[i];    // lin == lab2 on the final pass
    }
}

extern "C" void kernel_launch(void* const* d_in, const int* in_sizes, int n_in,
                              void* d_out, int out_size, void* d_ws, size_t ws_size,
                              hipStream_t stream) {
    const float* x  = (const float*)d_in[0];
    const int*   ei = (const int*)d_in[1];
    int* out = (int*)d_out;

    int N = in_sizes[0] / WL_D;
    int E = in_sizes[1] / 2;
    int chunk    = (E + NCH - 1) / NCH;        // 6250
    int nbuckets = (N + BROWS - 1) / BROWS;    // 782
    int L        = nbuckets * NCH;             // 400,384
    int ntiles   = (L + 1023) / 1024;          // 391 (<= 512: in-block scan ok)
    int vtiles   = (nbuckets + 63) / 64;       // 13
    int btiles   = NCH / 64;                   // 8
    int pgrid    = (8 * N + BT - 1) / BT;      // 1563 (8 lanes per row)

    // workspace layout (uint32 units) — everything written before read
    unsigned* ws    = (unsigned*)d_ws;
    unsigned* lab0  = ws;               // N
    unsigned* lab1  = lab0 + N;         // N
    unsigned* lab2  = lab1 + N;         // N
    unsigned* rs    = lab2 + N;         // N
    unsigned* bs    = rs + N;           // 1024
    unsigned* bstart= bs + 1024;        // 1024 (nbuckets+1 used)
    unsigned* hist  = bstart + 1024;    // L
    unsigned* buf   = hist + L;         // E
    unsigned* csr   = buf + E;          // E
    unsigned* histT = csr;              // transient: csr space is free until k_bucket

    k_hist_argmax<<<GRID_F, BT, 0, stream>>>(x, ei, lab0, hist, N, E, chunk, nbuckets);
    k_scan_tile<<<ntiles, BT, 0, stream>>>(hist, bs, L);
    k_transp<<<vtiles * btiles, BT, 0, stream>>>(hist, bs, histT, bstart, nbuckets, ntiles, E);
    k_scatter<<<NCH, BT, 0, stream>>>(ei, histT, buf, E, chunk, nbuckets);
    k_bucket<<<nbuckets, BT, 0, stream>>>(buf, bstart, csr, rs, lab0, lab1, N, E, nbuckets);
    k_prop<<<pgrid, BT, 0, stream>>>(csr, rs, lab1, lab2, N, E);
    k_prop_final<<<pgrid, BT, 0, stream>>>(csr, rs, lab2, lab0, lab1, out, N, E, pgrid);
}

// Round 11
// 195.736 us; speedup vs baseline: 1.3340x; 1.0101x over previous
//
#include <hip/hip_runtime.h>
#include <hip/hip_bf16.h>

// WeisfeilerLehman: labels0 = argmax(x, -1); 3x ordered polynomial hash over edges.
// All arithmetic mod 2^32 (uint32 wrap) == reference int64 truncated to int32.
// R21: hist/argmax role split; scatter no mask-cache + launch_bounds(BT,6);
//      bucket wave-shfl scan; 2-wide horner residual.
// R22: prefix-path restructure. k_scan_tile (full 400K scan, 20-barrier ladder,
//      hist rewritten in place) + k_transp replaced by two wave-per-bucket
//      kernels: k_btot (row totals) and k_prep (replicated bstart prefix +
//      in-wave shfl row scan + pad-9 LDS tile transposed histT write).
//      histT[b][v] = bstart[v] + sum_{b'<b} hist[v][b'] == old lex scan.
//      hist never rewritten; bs array dropped. Same launch count, ~1/4 work.
// R23: identical resubmit of R22 (R22 bench failed on GPU acquisition timeout,
//      never measured).

#define WL_D 128
#define NCH 512             // MSD chunk count (scatter grid)
#define GRID_F 2048         // fused hist/argmax grid
#define BT 512              // threads per block (8 waves)
#define MSDW 8
#define BBITS 7             // bucket = row >> 7
#define BROWS 128           // rows per bucket
#define NBK 1024            // max buckets (N <= 131072)
#define RLSHIFT 23          // buf pack: (rl << 23) | col   (col < 2^23)
#define COLMASK ((1u << RLSHIFT) - 1u)
#define CMAX 5120           // LDS-staged output cap (20 KB)
#define NBMAX 13            // unrolled batches per wave in k_scatter (chunk 6250)
#define KBMAX 10            // unrolled batches per wave in k_bucket (len <= CMAX)
#define HP8 2487512833u     // 31^8 mod 2^32

// XCD-chunked chunk assignment: blockIdx -> chunk such that each XCD (bid % 8
// under round-robin dispatch) owns NCH/8 consecutive chunks. Bijective on [0,NCH).
__device__ inline int xcd_chunk(int bid) { return ((bid & 7) << 6) | (bid >> 3); }

// mask of lanes whose low BITS bits of v match mine (inactive lanes use a
// sentinel outside the valid key range so they never match active lanes)
template <int BITS>
__device__ inline unsigned long long match_key(unsigned v) {
    unsigned long long m = ~0ull;
    #pragma unroll
    for (int b = 0; b < BITS; ++b) {
        unsigned long long s = __ballot((v >> b) & 1u);
        m &= ((v >> b) & 1u) ? s : ~s;
    }
    return m;
}

// ---- fused: chunk bucket-histogram (blocks < NCH) OR argmax (blocks >= NCH) ----
__global__ void __launch_bounds__(BT)
k_hist_argmax(const float* __restrict__ x, const int* __restrict__ ei,
              unsigned* __restrict__ lab0, unsigned* __restrict__ hist,
              int N, int E, int chunk, int nbuckets) {
    __shared__ unsigned h[NBK];
    int bid = blockIdx.x, t = threadIdx.x, lane = t & 63, w = t >> 6;
    if (bid < NCH) {                    // hist-only blocks (uniform condition)
        int b = xcd_chunk(bid);         // swizzled chunk id (bijective on [0,NCH))
        for (int i = t; i < nbuckets; i += BT) h[i] = 0u;
        __syncthreads();
        int base = b * chunk, lim = min(base + chunk, E);
        int vbeg = (base + 3) & ~3; if (vbeg > lim) vbeg = lim;
        int vend = lim & ~3;        if (vend < vbeg) vend = vbeg;
        for (int e = base + t; e < vbeg; e += BT)
            atomicAdd(&h[((unsigned)ei[e]) >> BBITS], 1u);
        for (int i = vbeg + 4 * t; i < vend; i += 4 * BT) {
            int4 v4 = *(const int4*)(ei + i);
            atomicAdd(&h[((unsigned)v4.x) >> BBITS], 1u);
            atomicAdd(&h[((unsigned)v4.y) >> BBITS], 1u);
            atomicAdd(&h[((unsigned)v4.z) >> BBITS], 1u);
            atomicAdd(&h[((unsigned)v4.w) >> BBITS], 1u);
        }
        for (int e = vend + t; e < lim; e += BT)
            atomicAdd(&h[((unsigned)ei[e]) >> BBITS], 1u);
        __syncthreads();
        for (int v = t; v < nbuckets; v += BT) hist[(size_t)v * NCH + b] = h[v];
    } else {
        // argmax blocks: 2 rows per wave (float4; half-waves of 32 lanes)
        int ab = bid - NCH;
        int half = lane >> 5, li = lane & 31;
        for (int pr = ab * MSDW + w; 2 * pr < N; pr += (GRID_F - NCH) * MSDW) {
            int r = 2 * pr + half;
            float bv = -3.4e38f; int bi = 0;
            if (r < N) {
                float4 v = ((const float4*)(x + (size_t)r * WL_D))[li];
                bv = v.x; bi = 4 * li;
                if (v.y > bv) { bv = v.y; bi = 4 * li + 1; }
                if (v.z > bv) { bv = v.z; bi = 4 * li + 2; }
                if (v.w > bv) { bv = v.w; bi = 4 * li + 3; }
            }
            #pragma unroll
            for (int off = 16; off > 0; off >>= 1) {
                float ov = __shfl_down(bv, off, 32);
                int   oi = __shfl_down(bi, off, 32);
                if (ov > bv || (ov == bv && oi < bi)) { bv = ov; bi = oi; }
            }
            if (li == 0 && r < N) lab0[r] = (unsigned)bi;
        }
    }
}

// ---- per-bucket totals: one wave per bucket, 8 coalesced loads + butterfly ----
__global__ void __launch_bounds__(BT)
k_btot(const unsigned* __restrict__ hist, unsigned* __restrict__ btot,
       int nbuckets) {
    int t = threadIdx.x, w = t >> 6, lane = t & 63;
    int v = blockIdx.x * MSDW + w;
    if (v >= nbuckets) return;          // whole wave exits; no barriers below
    unsigned s = 0;
    #pragma unroll
    for (int j = 0; j < NCH / 64; ++j) s += hist[(size_t)v * NCH + j * 64 + lane];
    #pragma unroll
    for (int o = 1; o < 64; o <<= 1) s += __shfl_xor(s, o, 64);
    if (lane == 0) btot[v] = s;
}

// ---- prep: bstart prefix (replicated) + in-wave chunk scan -> transposed histT ----
__global__ void __launch_bounds__(BT)
k_prep(const unsigned* __restrict__ hist, const unsigned* __restrict__ btot,
       unsigned* __restrict__ histT, unsigned* __restrict__ bstart,
       int nbuckets, int E) {
    __shared__ unsigned tile[NCH * 9];   // [512 chunks][8 waves], pad stride 9 (18 KB)
    __shared__ unsigned sS[MSDW];
    int t = threadIdx.x, w = t >> 6, lane = t & 63;
    int v = blockIdx.x * MSDW + w;
    bool act = (v < nbuckets);
    // bstart[v] = sum_{u<v} btot[u] (lane-parallel partial + butterfly)
    unsigned S = 0;
    if (act) for (int u = lane; u < v; u += 64) S += btot[u];
    #pragma unroll
    for (int o = 1; o < 64; o <<= 1) S += __shfl_xor(S, o, 64);
    if (lane == 0) { sS[w] = act ? S : 0u; if (act) bstart[v] = S; }
    if (blockIdx.x == 0 && t == 0) bstart[nbuckets] = (unsigned)E;
    // exclusive scan of the bucket's 512 chunk counts (in-wave, chunk order)
    unsigned carry = 0;
    #pragma unroll
    for (int j = 0; j < NCH / 64; ++j) {
        unsigned xv = act ? hist[(size_t)v * NCH + j * 64 + lane] : 0u;
        unsigned a = xv;
        #pragma unroll
        for (int o = 1; o < 64; o <<= 1) {
            unsigned u = __shfl_up(a, o, 64);
            if (lane >= o) a += u;
        }
        unsigned excl = a - xv + carry;
        carry += __shfl(a, 63, 64);
        tile[(j * 64 + lane) * 9 + w] = excl;
    }
    __syncthreads();
    // transposed write: histT[chunk][v] (consecutive threads -> contiguous v's)
    for (int i = t; i < NCH * MSDW; i += BT) {
        int c = i >> 3, w2 = i & 7;
        int v2 = blockIdx.x * MSDW + w2;
        if (v2 < nbuckets) histT[(size_t)c * nbuckets + v2] = tile[c * 9 + w2] + sS[w2];
    }
}

// ---- stable MSD scatter: prefetched batches, LDS cursors; 3 blocks/CU ----
__global__ void __launch_bounds__(BT, 6)
k_scatter(const int* __restrict__ ei, const unsigned* __restrict__ histT,
          unsigned* __restrict__ buf, int E, int chunk, int nbuckets) {
    __shared__ unsigned wbase[MSDW * NBK];   // 32 KB
    int b = xcd_chunk(blockIdx.x);           // swizzled chunk id
    int t = threadIdx.x, lane = t & 63, w = t >> 6;
    unsigned long long lmask = (1ull << lane) - 1ull;
    for (int i = t; i < MSDW * NBK; i += BT) wbase[i] = 0u;
    __syncthreads();
    int base = b * chunk, lim = min(base + chunk, E);
    int sub  = (chunk + MSDW - 1) / MSDW;
    int wbeg = base + w * sub;
    int wend = min(wbeg + sub, lim);
    int nbat = (wbeg < wend) ? ((wend - wbeg + 63) >> 6) : 0;
    // prefetch all row loads (static reg indices; issued before any ballot chain)
    unsigned r_[NBMAX];
    #pragma unroll
    for (int k = 0; k < NBMAX; ++k) {
        int e = wbeg + k * 64 + lane;
        r_[k] = (e < wend) ? (unsigned)ei[e] : 0u;
    }
    // pass A: per-wave bucket counts
    #pragma unroll
    for (int k = 0; k < NBMAX; ++k) {
        if (k >= nbat) break;
        int e = wbeg + k * 64 + lane;
        bool act = (e < wend);
        unsigned v = act ? (r_[k] >> BBITS) : (NBK - 1u);
        unsigned long long m = match_key<10>(v);
        unsigned before = (unsigned)__popcll(m & lmask);
        if (act && before == 0u) wbase[w * NBK + v] += (unsigned)__popcll(m);
    }
    for (int k = NBMAX; k < nbat; ++k) {     // dynamic tail (robustness)
        int e = wbeg + k * 64 + lane;
        bool act = (e < wend);
        unsigned v = act ? (((unsigned)ei[e]) >> BBITS) : (NBK - 1u);
        unsigned long long m = match_key<10>(v);
        unsigned before = (unsigned)__popcll(m & lmask);
        if (act && before == 0u) wbase[w * NBK + v] += (unsigned)__popcll(m);
    }
    __syncthreads();
    // seed per-wave cursors from transposed bases (coalesced)
    for (int v = t; v < nbuckets; v += BT) {
        unsigned g = histT[(size_t)b * nbuckets + v];
        #pragma unroll
        for (int w2 = 0; w2 < MSDW; ++w2) {
            unsigned cnt = wbase[w2 * NBK + v];
            wbase[w2 * NBK + v] = g;
            g += cnt;
        }
    }
    __syncthreads();
    // pass B: prefetch cols (rows still live in r_), recompute masks, stable scatter
    unsigned c_[NBMAX];
    #pragma unroll
    for (int k = 0; k < NBMAX; ++k) {
        int e = wbeg + k * 64 + lane;
        c_[k] = (e < wend) ? (unsigned)ei[(size_t)E + e] : 0u;
    }
    #pragma unroll
    for (int k = 0; k < NBMAX; ++k) {
        if (k >= nbat) break;
        int e = wbeg + k * 64 + lane;
        bool act = (e < wend);
        unsigned r = r_[k], col = c_[k];
        unsigned v = act ? (r >> BBITS) : (NBK - 1u);
        unsigned long long m = match_key<10>(v);
        unsigned before = (unsigned)__popcll(m & lmask);
        int leader = __ffsll(m) - 1;
        unsigned base0 = 0;
        if (act && before == 0u) {
            base0 = wbase[w * NBK + v];
            wbase[w * NBK + v] = base0 + (unsigned)__popcll(m);
        }
        base0 = __shfl(base0, leader, 64);
        if (act) buf[base0 + before] = ((r & (BROWS - 1u)) << RLSHIFT) | col;
    }
    for (int k = NBMAX; k < nbat; ++k) {     // dynamic tail
        int e = wbeg + k * 64 + lane;
        bool act = (e < wend);
        unsigned r   = act ? (unsigned)ei[e] : 0u;
        unsigned col = act ? (unsigned)ei[(size_t)E + e] : 0u;
        unsigned v = act ? (r >> BBITS) : (NBK - 1u);
        unsigned long long m = match_key<10>(v);
        unsigned before = (unsigned)__popcll(m & lmask);
        unsigned total  = (unsigned)__popcll(m);
        int leader = __ffsll(m) - 1;
        unsigned base0 = 0;
        if (act && before == 0u) { base0 = wbase[w * NBK + v]; wbase[w * NBK + v] = base0 + total; }
        base0 = __shfl(base0, leader, 64);
        if (act) buf[base0 + before] = ((r & (BROWS - 1u)) << RLSHIFT) | col;
    }
}

// ---- per-bucket stable counting sort by rl (reg-prefetched, LDS-staged out)
//      + FUSED first prop ----
__global__ void __launch_bounds__(BT)
k_bucket(const unsigned* __restrict__ buf, const unsigned* __restrict__ bstart,
         unsigned* __restrict__ csr, unsigned* __restrict__ rs_g,
         const unsigned* __restrict__ lab0, unsigned* __restrict__ lab1,
         int N, int E, int nbuckets) {
    __shared__ unsigned data2[CMAX];          // 20 KB (sorted output staging)
    __shared__ unsigned h2[MSDW * BROWS];     // 4 KB
    __shared__ unsigned offs[BROWS];          // 0.5 KB
    int bb = blockIdx.x, t = threadIdx.x, lane = t & 63, w = t >> 6;
    unsigned long long lmask = (1ull << lane) - 1ull;
    unsigned start = bstart[bb];
    unsigned end   = bstart[bb + 1];
    unsigned len = end - start;
    bool lds_ok = (len <= CMAX);
    for (int i = t; i < MSDW * BROWS; i += BT) h2[i] = 0u;
    __syncthreads();
    unsigned sub  = (len + MSDW - 1u) / MSDW;
    unsigned wbeg = w * sub;
    unsigned wend = min(wbeg + sub, len);
    int nbat = (wbeg < wend) ? (int)((wend - wbeg + 63u) >> 6) : 0;
    // prefetch the wave's whole slice into regs
    unsigned d_[KBMAX];
    #pragma unroll
    for (int k = 0; k < KBMAX; ++k) {
        unsigned i = wbeg + (unsigned)(k * 64 + lane);
        d_[k] = (i < wend) ? buf[start + i] : 0u;
    }
    // pass A: per-wave rl counts (ballots overlap the prefetch)
    #pragma unroll
    for (int k = 0; k < KBMAX; ++k) {
        if (k >= nbat) break;
        unsigned i = wbeg + (unsigned)(k * 64 + lane);
        bool act = (i < wend);
        unsigned v = act ? (d_[k] >> RLSHIFT) : 255u;
        unsigned long long m = match_key<8>(v);
        unsigned before = (unsigned)__popcll(m & lmask);
        unsigned total  = (unsigned)__popcll(m);
        if (act && before == 0u) h2[w * BROWS + v] += total;
    }
    for (int k = KBMAX; k < nbat; ++k) {     // dynamic tail (giant-bucket fallback)
        unsigned i = wbeg + (unsigned)(k * 64 + lane);
        bool act = (i < wend);
        unsigned v = act ? (buf[start + i] >> RLSHIFT) : 255u;
        unsigned long long m = match_key<8>(v);
        unsigned before = (unsigned)__popcll(m & lmask);
        unsigned total  = (unsigned)__popcll(m);
        if (act && before == 0u) h2[w * BROWS + v] += total;
    }
    __syncthreads();
    // per-row totals -> offs (inclusive scan via wave-0 shfl; 2 barriers not 16)
    unsigned hv = 0;
    if (t < BROWS) {
        #pragma unroll
        for (int w2 = 0; w2 < MSDW; ++w2) hv += h2[w2 * BROWS + t];
        offs[t] = hv;
    }
    __syncthreads();
    if (t < 64) {
        unsigned a = offs[t], b2 = offs[t + 64];
        #pragma unroll
        for (int o = 1; o < 64; o <<= 1) {
            unsigned ua = __shfl_up(a, o, 64);
            unsigned ub = __shfl_up(b2, o, 64);
            if (t >= o) { a += ua; b2 += ub; }
        }
        unsigned tot = __shfl(a, 63, 64);
        offs[t] = a;                     // inclusive over first 64 rows
        offs[t + 64] = b2 + tot;         // inclusive over all 128
    }
    __syncthreads();
    if (t < BROWS) {
        unsigned excl = offs[t] - hv;
        int row = bb * BROWS + t;
        if (row < N) rs_g[row] = start + excl;
        unsigned g = lds_ok ? excl : (start + excl);   // bucket-relative if LDS-staged
        #pragma unroll
        for (int w2 = 0; w2 < MSDW; ++w2) {
            unsigned cnt = h2[w2 * BROWS + t];
            h2[w2 * BROWS + t] = g;
            g += cnt;
        }
    }
    __syncthreads();
    // pass B: stable scatter cols (from regs) into LDS staging / csr fallback
    #pragma unroll
    for (int k = 0; k < KBMAX; ++k) {
        if (k >= nbat) break;
        unsigned i = wbeg + (unsigned)(k * 64 + lane);
        bool act = (i < wend);
        unsigned p = d_[k];
        unsigned v = act ? (p >> RLSHIFT) : 255u;
        unsigned long long m = match_key<8>(v);
        unsigned before = (unsigned)__popcll(m & lmask);
        unsigned total  = (unsigned)__popcll(m);
        int leader = __ffsll(m) - 1;
        unsigned base0 = 0;
        if (act && before == 0u) { base0 = h2[w * BROWS + v]; h2[w * BROWS + v] = base0 + total; }
        base0 = __shfl(base0, leader, 64);
        if (act) {
            if (lds_ok) data2[base0 + before] = p & COLMASK;
            else        csr[base0 + before]   = p & COLMASK;
        }
    }
    for (int k = KBMAX; k < nbat; ++k) {     // dynamic tail
        unsigned i = wbeg + (unsigned)(k * 64 + lane);
        bool act = (i < wend);
        unsigned p = act ? buf[start + i] : 0u;
        unsigned v = act ? (p >> RLSHIFT) : 255u;
        unsigned long long m = match_key<8>(v);
        unsigned before = (unsigned)__popcll(m & lmask);
        unsigned total  = (unsigned)__popcll(m);
        int leader = __ffsll(m) - 1;
        unsigned base0 = 0;
        if (act && before == 0u) { base0 = h2[w * BROWS + v]; h2[w * BROWS + v] = base0 + total; }
        base0 = __shfl(base0, leader, 64);
        if (act) {
            if (lds_ok) data2[base0 + before] = p & COLMASK;
            else        csr[base0 + before]   = p & COLMASK;
        }
    }
    __syncthreads();
    // stream sorted bucket out FIRST: the stores drain underneath the fused prop
    if (lds_ok) for (unsigned i = t; i < len; i += BT) csr[start + i] = data2[i];
    // FUSED first prop: lab1 for this bucket's rows, 8 lanes/row, cols from LDS.
    const unsigned H1 = HP8, H2 = HP8 * HP8, H3 = H2 * HP8, H4 = H3 * HP8;
    const unsigned* srcp = lds_ok ? (const unsigned*)data2 : (csr + start);
    int l = t & 7;
    for (int r0 = t >> 3; r0 < BROWS; r0 += BT / 8) {
        unsigned beg = r0 ? offs[r0 - 1] : 0u;
        unsigned d   = offs[r0] - beg;
        unsigned h = 0u;
        unsigned M = (d > (unsigned)l) ? ((d - (unsigned)l + 7u) >> 3) : 0u;
        unsigned bidx = beg + (unsigned)l;
        unsigned m = 0;
        for (; m + 4u <= M; m += 4u) {
            unsigned c0 = srcp[bidx + 8u * m];
            unsigned c1 = srcp[bidx + 8u * m + 8u];
            unsigned c2 = srcp[bidx + 8u * m + 16u];
            unsigned c3 = srcp[bidx + 8u * m + 24u];
            unsigned l0 = lab0[c0], l1 = lab0[c1], l2 = lab0[c2], l3 = lab0[c3];
            h = h * H4 + l0 * H3 + l1 * H2 + l2 * H1 + l3;
        }
        for (; m + 2u <= M; m += 2u) {
            unsigned c0 = srcp[bidx + 8u * m];
            unsigned c1 = srcp[bidx + 8u * m + 8u];
            h = h * H2 + lab0[c0] * H1 + lab0[c1];
        }
        for (; m < M; ++m) h = h * H1 + lab0[srcp[bidx + 8u * m]];
        if (M) {
            unsigned T = d - 1u - (unsigned)l - 8u * (M - 1u);   // in [0,7]
            unsigned p = ((T & 1u) ? 31u : 1u) * ((T & 2u) ? 961u : 1u)
                       * ((T & 4u) ? 923521u : 1u);
            h *= p;
        }
        h += __shfl_xor(h, 1, 64);
        h += __shfl_xor(h, 2, 64);
        h += __shfl_xor(h, 4, 64);
        int row = bb * BROWS + r0;
        if (l == 0 && row < N) lab1[row] = h;
    }
}

// ---- prop: 8 lanes per row, 4/2-wide reassociated base-31^8 Horner ----
__device__ inline unsigned horner8(const unsigned* __restrict__ csr,
                                   const unsigned* __restrict__ rs,
                                   const unsigned* __restrict__ lin,
                                   int g, int l, int N, int E) {
    const unsigned H1 = HP8, H2 = HP8 * HP8, H3 = H2 * HP8, H4 = H3 * HP8;
    unsigned s = rs[g];
    unsigned e = (g + 1 < N) ? rs[g + 1] : (unsigned)E;
    unsigned d = e - s;
    unsigned h = 0u;
    unsigned M = (d > (unsigned)l) ? ((d - (unsigned)l + 7u) >> 3) : 0u;
    unsigned bidx = s + (unsigned)l;
    unsigned m = 0;
    for (; m + 4u <= M; m += 4u) {
        unsigned c0 = csr[bidx + 8u * m];
        unsigned c1 = csr[bidx + 8u * m + 8u];
        unsigned c2 = csr[bidx + 8u * m + 16u];
        unsigned c3 = csr[bidx + 8u * m + 24u];
        unsigned l0 = lin[c0], l1 = lin[c1], l2 = lin[c2], l3 = lin[c3];
        h = h * H4 + l0 * H3 + l1 * H2 + l2 * H1 + l3;
    }
    for (; m + 2u <= M; m += 2u) {
        unsigned c0 = csr[bidx + 8u * m];
        unsigned c1 = csr[bidx + 8u * m + 8u];
        h = h * H2 + lin[c0] * H1 + lin[c1];
    }
    for (; m < M; ++m) h = h * H1 + lin[csr[bidx + 8u * m]];
    if (M) {
        unsigned T = d - 1u - (unsigned)l - 8u * (M - 1u);   // in [0,7]
        unsigned p = ((T & 1u) ? 31u : 1u) * ((T & 2u) ? 961u : 1u)
                   * ((T & 4u) ? 923521u : 1u);
        h *= p;
    }
    h += __shfl_xor(h, 1, 64);
    h += __shfl_xor(h, 2, 64);
    h += __shfl_xor(h, 4, 64);
    return h;
}

__global__ void __launch_bounds__(BT)
k_prop(const unsigned* __restrict__ csr, const unsigned* __restrict__ rs,
       const unsigned* __restrict__ lin, unsigned* __restrict__ lout,
       int N, int E) {
    int idx = blockIdx.x * BT + threadIdx.x;
    int g = idx >> 3, l = idx & 7;
    if (g >= N) return;
    unsigned h = horner8(csr, rs, lin, g, l, N, E);
    if (l == 0) lout[g] = h;
}

// final prop: writes lab3 straight into out[0..N) and out[4N..5N), plus copies
// lab0..2 into out[N..4N)
__global__ void __launch_bounds__(BT)
k_prop_final(const unsigned* __restrict__ csr, const unsigned* __restrict__ rs,
             const unsigned* __restrict__ lin, const unsigned* __restrict__ l0,
             const unsigned* __restrict__ l1, int* __restrict__ out,
             int N, int E, int pgrid) {
    int idx = blockIdx.x * BT + threadIdx.x;
    int g = idx >> 3, l = idx & 7;
    if (g < N) {
        unsigned h = horner8(csr, rs, lin, g, l, N, E);
        if (l == 0) { out[g] = (int)h; out[4 * N + g] = (int)h; }
    }
    for (int i = idx; i < N; i += pgrid * BT) {
        out[N + i]     = (int)l0[i];
        out[2 * N + i] = (int)l1[i];
        out[3 * N + i] = (int)lin[i];    // lin == lab2 on the final pass
    }
}

extern "C" void kernel_launch(void* const* d_in, const int* in_sizes, int n_in,
                              void* d_out, int out_size, void* d_ws, size_t ws_size,
                              hipStream_t stream) {
    const float* x  = (const float*)d_in[0];
    const int*   ei = (const int*)d_in[1];
    int* out = (int*)d_out;

    int N = in_sizes[0] / WL_D;
    int E = in_sizes[1] / 2;
    int chunk    = (E + NCH - 1) / NCH;        // 6250
    int nbuckets = (N + BROWS - 1) / BROWS;    // 782
    int L        = nbuckets * NCH;             // 400,384
    int pbk      = (nbuckets + MSDW - 1) / MSDW; // 98 (wave-per-bucket grids)
    int pgrid    = (8 * N + BT - 1) / BT;      // 1563 (8 lanes per row)

    // workspace layout (uint32 units) — everything written before read
    unsigned* ws    = (unsigned*)d_ws;
    unsigned* lab0  = ws;               // N
    unsigned* lab1  = lab0 + N;         // N
    unsigned* lab2  = lab1 + N;         // N
    unsigned* rs    = lab2 + N;         // N
    unsigned* btot  = rs + N;           // 1024 (nbuckets used)
    unsigned* bstart= btot + 1024;      // 1024 (nbuckets+1 used)
    unsigned* hist  = bstart + 1024;    // L (raw counts; never rewritten)
    unsigned* buf   = hist + L;         // E
    unsigned* csr   = buf + E;          // E
    unsigned* histT = csr;              // transient: csr space is free until k_bucket

    k_hist_argmax<<<GRID_F, BT, 0, stream>>>(x, ei, lab0, hist, N, E, chunk, nbuckets);
    k_btot<<<pbk, BT, 0, stream>>>(hist, btot, nbuckets);
    k_prep<<<pbk, BT, 0, stream>>>(hist, btot, histT, bstart, nbuckets, E);
    k_scatter<<<NCH, BT, 0, stream>>>(ei, histT, buf, E, chunk, nbuckets);
    k_bucket<<<nbuckets, BT, 0, stream>>>(buf, bstart, csr, rs, lab0, lab1, N, E, nbuckets);
    k_prop<<<pgrid, BT, 0, stream>>>(csr, rs, lab1, lab2, N, E);
    k_prop_final<<<pgrid, BT, 0, stream>>>(csr, rs, lab2, lab0, lab1, out, N, E, pgrid);
}